// Round 8
// baseline (237.465 us; speedup 1.0000x reference)
//
#include <hip/hip_runtime.h>

typedef unsigned short u16;
typedef __attribute__((ext_vector_type(8))) short s16x8;
typedef __attribute__((ext_vector_type(4))) float f32x4;
typedef __attribute__((ext_vector_type(4))) int   i32x4;
typedef __attribute__((ext_vector_type(2))) int   i32x2;
typedef __attribute__((ext_vector_type(4))) unsigned short u16x4;

// ---------------- workspace layout (bytes) ----------------
constexpr size_t OFF_XB   = 0;                     // bf16 x          [2048][1024]
constexpr size_t OFF_WQB  = OFF_XB   + 4194304;    // bf16 Wq         [1024][1024]
constexpr size_t OFF_WKB  = OFF_WQB  + 2097152;    // bf16 Wk         [512][1024]
constexpr size_t OFF_WVB  = OFF_WKB  + 1048576;    // bf16 Wv         [512][1024]
constexpr size_t OFF_WOB  = OFF_WVB  + 1048576;    // bf16 Wo         [1024][1024]
constexpr size_t OFF_W1T  = OFF_WOB  + 2097152;    // bf16 W1T [384][1024]; reused later as PL array
constexpr size_t OFF_W2T  = OFF_W1T  + 786432;     // bf16 w2T        [1024][64]
constexpr size_t OFF_A2T  = OFF_W2T  + 131072;     // bf16 a2T        [1024][64]
constexpr size_t OFF_V2T  = OFF_A2T  + 131072;     // bf16 v2T        [1024][32]
constexpr size_t OFF_G2T  = OFF_V2T  + 65536;      // bf16 g2T        [1024][160]
constexpr size_t OFF_KQF  = OFF_G2T  + 327680;     // f32 k-proj [2048][512]; reused as chunk records
constexpr size_t OFF_VQF  = OFF_KQF  + 4194304;    // f32 v-proj      [2048][512]
constexpr size_t OFF_URAW = OFF_VQF  + 4194304;    // (dead; kept for layout)
constexpr size_t OFF_UB   = OFF_URAW + 2621440;    // bf16 stage1 act [2048][384]
constexpr size_t OFF_S2A  = OFF_UB   + 1572864;    // f32 iclr        [2048][1024]
constexpr size_t OFF_S2V  = OFF_S2A  + 8388608;    // f32 vmix        [2048][1024]
constexpr size_t OFF_GBUF = OFF_S2V  + 8388608;    // f32 gate        [2048][1024]
constexpr size_t OFF_SEQ  = OFF_GBUF + 8388608;    // f32 SEQ [2][16][1024][6][64] (r,decay,k,v,a,b)
constexpr size_t OFF_YBUF = OFF_SEQ  + 50331648;   // f32 y   [2][16][1024][64]
constexpr size_t OFF_XGB  = OFF_YBUF + 8388608;    // bf16 xn*g       [2048][1024]

// chunk record overlay (dead KQF..S2V window, 2048 records x 14336B = exact fit)
// v3 layout: 0 P_f(2048) | 2048 G_f(2048) | 4096 barkar(4096, A-frag, c XOR (slice&3)<<2)
//            | 8192 + w*1536: { zloc_w(512) | Yloc_w(512) | V_w(512) }  (w = i-strip 0..3)
constexpr size_t OFF_REC  = OFF_KQF;
constexpr size_t OFF_PL   = OFF_W1T;   // f32 pL [2048][64]

__device__ __forceinline__ u16 f2bf(float f){
  unsigned int u = __builtin_bit_cast(unsigned int, f);
  u = u + 0x7fffu + ((u >> 16) & 1u);
  return (u16)(u >> 16);
}
__device__ __forceinline__ int pk2(float a, float b){
  return (int)((unsigned)f2bf(a) | ((unsigned)f2bf(b) << 16));
}
__device__ __forceinline__ float bf2f(u16 h){
  return __builtin_bit_cast(float, ((unsigned)h) << 16);
}
__device__ __forceinline__ f32x4 cvt4(i32x2 v){
  unsigned a=(unsigned)v[0], b=(unsigned)v[1];
  f32x4 r;
  r[0]=__builtin_bit_cast(float, a<<16);
  r[1]=__builtin_bit_cast(float, a&0xffff0000u);
  r[2]=__builtin_bit_cast(float, b<<16);
  r[3]=__builtin_bit_cast(float, b&0xffff0000u);
  return r;
}

__device__ __forceinline__ void gload_lds16(const float* g, float* l){
  __builtin_amdgcn_global_load_lds((const __attribute__((address_space(1))) void*)g,
                                   (__attribute__((address_space(3))) void*)l, 16, 0, 0);
}
__device__ __forceinline__ void gload_lds4(const float* g, float* l){
  __builtin_amdgcn_global_load_lds((const __attribute__((address_space(1))) void*)g,
                                   (__attribute__((address_space(3))) void*)l, 4, 0, 0);
}

// ---------------- prep: convert/transpose + v_first passthrough ----------------
constexpr size_t N_XB=2097152, N_WQ=1048576, N_WK=524288, N_WV=524288, N_WO=1048576,
  N_W1T=393216, N_W2T=65536, N_A2T=65536, N_V2T=32768, N_G2T=163840, N_VF=2097152;
constexpr size_t PREP_TOT = N_XB+N_WQ+N_WK+N_WV+N_WO+N_W1T+N_W2T+N_A2T+N_V2T+N_G2T+N_VF;

__global__ __launch_bounds__(256) void prep_kernel(char* ws, const float* x, const float* vfirst,
  const float* w1, const float* w2, const float* a1, const float* a2,
  const float* v1, const float* v2, const float* g1, const float* g2,
  const float* Wq, const float* Wk, const float* Wv, const float* Wo, float* dout)
{
  u16* XB=(u16*)(ws+OFF_XB); u16* WQB=(u16*)(ws+OFF_WQB); u16* WKB=(u16*)(ws+OFF_WKB);
  u16* WVB=(u16*)(ws+OFF_WVB); u16* WOB=(u16*)(ws+OFF_WOB); u16* W1T=(u16*)(ws+OFF_W1T);
  u16* W2T=(u16*)(ws+OFF_W2T); u16* A2T=(u16*)(ws+OFF_A2T); u16* V2T=(u16*)(ws+OFF_V2T);
  u16* G2T=(u16*)(ws+OFF_G2T);
  for (size_t idx=(size_t)blockIdx.x*256+threadIdx.x; idx<PREP_TOT; idx+=(size_t)gridDim.x*256){
    size_t r = idx;
    if (r < N_XB){ XB[r]=f2bf(x[r]); continue; } r-=N_XB;
    if (r < N_WQ){ WQB[r]=f2bf(Wq[r]); continue; } r-=N_WQ;
    if (r < N_WK){ WKB[r]=f2bf(Wk[r]); continue; } r-=N_WK;
    if (r < N_WV){ WVB[r]=f2bf(Wv[r]); continue; } r-=N_WV;
    if (r < N_WO){ WOB[r]=f2bf(Wo[r]); continue; } r-=N_WO;
    if (r < N_W1T){
      int n=(int)(r>>10), k=(int)(r&1023); float v=0.f;
      if (n<64) v=w1[(size_t)k*64+n];
      else if (n<128) v=a1[(size_t)k*64+(n-64)];
      else if (n<160) v=v1[(size_t)k*32+(n-128)];
      else if (n<320) v=g1[(size_t)k*160+(n-160)];
      W1T[r]=f2bf(v); continue; } r-=N_W1T;
    if (r < N_W2T){ int c=(int)(r>>6), d=(int)(r&63); W2T[r]=f2bf(w2[(size_t)d*1024+c]); continue; } r-=N_W2T;
    if (r < N_A2T){ int c=(int)(r>>6), d=(int)(r&63); A2T[r]=f2bf(a2[(size_t)d*1024+c]); continue; } r-=N_A2T;
    if (r < N_V2T){ int c=(int)(r>>5), d=(int)(r&31); V2T[r]=f2bf(v2[(size_t)d*1024+c]); continue; } r-=N_V2T;
    if (r < N_G2T){ int c=(int)(r/160), d=(int)(r%160); G2T[r]=f2bf(g2[(size_t)d*1024+c]); continue; } r-=N_G2T;
    dout[2228224 + r] = vfirst[r];   // v_first passthrough (offset 2097152+131072)
  }
}

// ---------------- unified NT bf16 MFMA GEMM: C[m][n] = sum_k A[m][k]*B[n][k] ----------------
__global__ __launch_bounds__(256) void gemm_kernel(int phase, char* ws,
  const float* w0b, const float* a0b, const float* v0b, float* dout)
{
  const u16* A; const u16* Bw;
  float* outF=nullptr; const float* bias=nullptr;
  float* SEQf=(float*)(ws+OFF_SEQ);
  u16* UBp=(u16*)(ws+OFF_UB);
  int lda=0, ldb=0, K=0, ldc=0, Nlim=1024, col0=0, outMode=0;
  int y = blockIdx.y;
  if (phase==0){
    A=(const u16*)(ws+OFF_XB); lda=1024; K=1024;
    if (y<8)      { Bw=(const u16*)(ws+OFF_WQB); ldb=1024; col0=y*128;       outMode=1; }
    else if (y<12){ Bw=(const u16*)(ws+OFF_WKB); ldb=1024; col0=(y-8)*128;   outF=(float*)(ws+OFF_KQF); ldc=512; Nlim=512; }
    else if (y<16){ Bw=(const u16*)(ws+OFF_WVB); ldb=1024; col0=(y-12)*128;  outF=(float*)(ws+OFF_VQF); ldc=512; Nlim=512; }
    else          { Bw=(const u16*)(ws+OFF_W1T); ldb=1024; col0=(y-16)*128;  outMode=4; Nlim=320; }
  } else if (phase==1){
    int seg=y>>3; col0=(y&7)*128;
    const int Ks[4]={64,64,32,160};
    const int Ao[4]={0,64,128,160};
    K=Ks[seg]; lda=384; ldb=K;
    A=(const u16*)(ws+OFF_UB) + Ao[seg];
    if (seg==0)     { Bw=(const u16*)(ws+OFF_W2T); outMode=2; bias=w0b; }
    else if (seg==1){ Bw=(const u16*)(ws+OFF_A2T); outMode=3; bias=a0b; outF=(float*)(ws+OFF_S2A); ldc=1024; }
    else if (seg==2){ Bw=(const u16*)(ws+OFF_V2T); outMode=3; bias=v0b; outF=(float*)(ws+OFF_S2V); ldc=1024; }
    else            { Bw=(const u16*)(ws+OFF_G2T); outF=(float*)(ws+OFF_GBUF); ldc=1024; }
  } else {
    A=(const u16*)(ws+OFF_XGB); lda=1024; K=1024;
    Bw=(const u16*)(ws+OFF_WOB); ldb=1024; col0=y*128; outF=dout; ldc=1024;
  }
  int m0 = blockIdx.x*128;
  __shared__ __align__(16) u16 As[128][40];
  __shared__ __align__(16) u16 Bs[128][40];
  int tid=threadIdx.x, l=tid&63, wv=tid>>6, wm=wv>>1, wn=wv&1;
  f32x4 acc[4][4];
  #pragma unroll
  for (int i=0;i<4;i++)
    #pragma unroll
    for (int j=0;j<4;j++) acc[i][j]=(f32x4){0.f,0.f,0.f,0.f};

  for (int k0=0;k0<K;k0+=32){
    #pragma unroll
    for (int c=tid;c<512;c+=256){
      int row=c>>2, seg=c&3;
      *(i32x4*)(&As[row][seg*8]) = *(const i32x4*)(A  + (size_t)(m0+row)*lda  + k0 + seg*8);
      *(i32x4*)(&Bs[row][seg*8]) = *(const i32x4*)(Bw + (size_t)(col0+row)*ldb + k0 + seg*8);
    }
    __syncthreads();
    int kseg=(l>>4)*8, rrow=l&15;
    s16x8 af[4], bf[4];
    #pragma unroll
    for (int mt=0;mt<4;mt++) af[mt]=*(const s16x8*)(&As[wm*64+mt*16+rrow][kseg]);
    #pragma unroll
    for (int nt=0;nt<4;nt++) bf[nt]=*(const s16x8*)(&Bs[wn*64+nt*16+rrow][kseg]);
    #pragma unroll
    for (int mt=0;mt<4;mt++)
      #pragma unroll
      for (int nt=0;nt<4;nt++)
        acc[mt][nt]=__builtin_amdgcn_mfma_f32_16x16x32_bf16(af[mt],bf[nt],acc[mt][nt],0,0,0);
    __syncthreads();
  }
  // epilogue
  #pragma unroll
  for (int mt=0;mt<4;mt++){
    #pragma unroll
    for (int nt=0;nt<4;nt++){
      int nglob = col0 + wn*64 + nt*16 + (l&15);
      if (nglob >= Nlim) continue;
      #pragma unroll
      for (int rg=0;rg<4;rg++){
        int mrow = m0 + wm*64 + mt*16 + ((l>>4)<<2) + rg;
        float val = acc[mt][nt][rg];
        if (outMode==0){
          outF[(size_t)mrow*ldc + nglob] = val;
        } else if (outMode==1){          // r -> SEQ slot 0
          int b=mrow>>10, t=mrow&1023, h=nglob>>6, i=nglob&63;
          SEQf[(((size_t)(b*16+h)*1024+t)*384) + i] = val;
        } else if (outMode==2){          // decay -> SEQ slot 1
          float w = bias[nglob] + val;
          float d = expf(-expf(w));
          int b=mrow>>10, t=mrow&1023, h=nglob>>6, i=nglob&63;
          SEQf[(((size_t)(b*16+h)*1024+t)*384) + 64 + i] = d;
        } else if (outMode==3){          // sigmoid(bias+acc)
          float s = 1.0f/(1.0f+__expf(-(bias[nglob]+val)));
          outF[(size_t)mrow*ldc + nglob] = s;
        } else {                          // fused stage-1 activation -> UB bf16
          float a = (nglob<64) ? tanhf(val)
                  : (nglob<160) ? val
                  : 1.0f/(1.0f+__expf(-val));
          UBp[(size_t)mrow*384 + nglob] = f2bf(a);
        }
      }
    }
  }
}

// ---------------- prep2: build SEQ slots k,v,a,b ----------------
__global__ __launch_bounds__(256) void prep2_kernel(char* ws, const float* vfirst,
  const float* kk_s, const float* ka_s)
{
  const float* KQF=(const float*)(ws+OFF_KQF);
  const float* VQF=(const float*)(ws+OFF_VQF);
  const float* ICLR=(const float*)(ws+OFF_S2A);
  const float* VMIX=(const float*)(ws+OFF_S2V);
  float* SEQf=(float*)(ws+OFF_SEQ);
  int m=blockIdx.x, b=m>>10, t=m&1023;
  int tid=threadIdx.x, c0=tid*4, h=c0>>6, i0=c0&63, hk=h>>1;
  f32x4 kq=*(const f32x4*)(KQF+(size_t)m*512+hk*64+i0);
  f32x4 vq=*(const f32x4*)(VQF+(size_t)m*512+hk*64+i0);
  f32x4 ic=*(const f32x4*)(ICLR+(size_t)m*1024+c0);
  f32x4 vm=*(const f32x4*)(VMIX+(size_t)m*1024+c0);
  f32x4 vf=*(const f32x4*)(vfirst+(size_t)m*1024+c0);
  f32x4 kkc=*(const f32x4*)(kk_s+c0);
  f32x4 kac=*(const f32x4*)(ka_s+c0);
  f32x4 kk=kq*kkc;
  float ssq=kk[0]*kk[0]+kk[1]*kk[1]+kk[2]*kk[2]+kk[3]*kk[3];
  #pragma unroll
  for (int mk=1;mk<16;mk<<=1) ssq += __shfl_xor(ssq,mk);
  float scale = 1.0f / fmaxf(sqrtf(ssq), 1e-12f);
  f32x4 kf,vv,av,bv;
  #pragma unroll
  for (int j=0;j<4;j++){
    float icc = 1.0f + (ic[j]-1.0f)*kac[j];
    float kkn = kk[j]*scale;
    kf[j]=kq[j]*icc;
    vv[j]=vq[j] + (vf[j]-vq[j])*vm[j];
    av[j]=-kkn;
    bv[j]=kkn*icc;
  }
  size_t sb = (((size_t)(b*16+h)*1024)+t)*384 + i0;
  *(f32x4*)(SEQf+sb+128)=kf;
  *(f32x4*)(SEQf+sb+192)=vv;
  *(f32x4*)(SEQf+sb+256)=av;
  *(f32x4*)(SEQf+sb+320)=bv;
}

#define MFMA32(a,b,c) __builtin_amdgcn_mfma_f32_16x16x32_bf16(a,b,c,0,0,0)

// ---------------- precompute: per-chunk S-independent quantities (2048-way parallel) ------
__global__ __launch_bounds__(64) void pre_kernel(char* ws){
  const float* SEQ=(const float*)(ws+OFF_SEQ);
  int bid=blockIdx.x, bh=bid>>6, ch=bid&63;
  int l=threadIdx.x, c16=l&15, g=l>>4;
  const float* seqb = SEQ + (size_t)bh*(1024*384) + (size_t)ch*6144;
  char* rec = ws + OFF_REC + (size_t)bid*14336;
  float* PLp = (float*)(ws + OFF_PL) + (size_t)bid*64;

  __shared__ __align__(16) float raw[16*396];
  __shared__ __align__(16) float pbuf[16*68];
  __shared__ __align__(16) u16 AT[16*72];
  __shared__ __align__(16) u16 RT[16*72];
  __shared__ __align__(16) u16 BT[16*72];
  __shared__ __align__(16) u16 KT[16*72];
  __shared__ __align__(16) u16 vbb[64*24+16];
  __shared__ __align__(16) u16 zbb[64*24+16];
  __shared__ __align__(16) u16 pbb[64*24+16];
  __shared__ __align__(16) float WN[16*17];
  __shared__ __align__(16) u16 WY[16*24+16];
  __shared__ __align__(16) u16 WB[16*24+16];
  __shared__ __align__(16) u16 WK[16*24+16];
  __shared__ __align__(16) float rhsb[16*68];
  __shared__ __align__(16) float ptmp[16*68];
  __shared__ __align__(16) float gtmp[16*68];
  const s16x8 zero8 = {0,0,0,0,0,0,0,0};

  #pragma unroll
  for (int t=0;t<16;t++){
    const float* src = seqb + (size_t)t*384;
    float* dst = &raw[t*396];
    gload_lds16(src + l*4, dst);
    gload_lds4 (src + 256 + l, dst + 256);
    gload_lds4 (src + 320 + l, dst + 320);
  }
  asm volatile("s_waitcnt vmcnt(0)" ::: "memory");
  __builtin_amdgcn_sched_barrier(0);

  // ---- P1a: lane = channel l. cumprod decay; vbb LDS; barkar/V/pL writes ----
  {
    float ptv[16]; float pp=1.f;
    #pragma unroll
    for (int t=0;t<16;t++){ pp *= raw[t*396+64+l]; ptv[t]=pp; pbuf[t*68+l]=pp; }
    float pL = ptv[15];
    PLp[l] = pL;
    float bs[16], ks[16], vs[16];
    #pragma unroll
    for (int t=0;t<16;t++){
      float sc = pL * __builtin_amdgcn_rcpf(ptv[t]);
      bs[t]=raw[t*396+320+l]*sc;
      ks[t]=raw[t*396+128+l]*sc;
      vs[t]=raw[t*396+192+l];
    }
    int it=l>>4, rc=l&15;
    size_t slice = 8192 + (size_t)it*1536;
    i32x4 o;
    o[0]=pk2(vs[0],vs[1]); o[1]=pk2(vs[2],vs[3]); o[2]=pk2(vs[4],vs[5]); o[3]=pk2(vs[6],vs[7]);
    *(i32x4*)(&vbb[l*24]) = o;
    *(i32x4*)(rec + slice + 1024 + (size_t)(0*16+rc)*16) = o;
    o[0]=pk2(vs[8],vs[9]); o[1]=pk2(vs[10],vs[11]); o[2]=pk2(vs[12],vs[13]); o[3]=pk2(vs[14],vs[15]);
    *(i32x4*)(&vbb[l*24+8]) = o;
    *(i32x4*)(rec + slice + 1024 + (size_t)(1*16+rc)*16) = o;
    // barkar A-frag section: slice s = it*4 + {0,1: bar halves, 2,3: kar halves}, c XOR (s&3)<<2
    o[0]=pk2(bs[0],bs[1]); o[1]=pk2(bs[2],bs[3]); o[2]=pk2(bs[4],bs[5]); o[3]=pk2(bs[6],bs[7]);
    *(i32x4*)(rec + 4096 + (size_t)((it*4+0)*16 + (rc^0 ))*16) = o;
    o[0]=pk2(bs[8],bs[9]); o[1]=pk2(bs[10],bs[11]); o[2]=pk2(bs[12],bs[13]); o[3]=pk2(bs[14],bs[15]);
    *(i32x4*)(rec + 4096 + (size_t)((it*4+1)*16 + (rc^4 ))*16) = o;
    o[0]=pk2(ks[0],ks[1]); o[1]=pk2(ks[2],ks[3]); o[2]=pk2(ks[4],ks[5]); o[3]=pk2(ks[6],ks[7]);
    *(i32x4*)(rec + 4096 + (size_t)((it*4+2)*16 + (rc^8 ))*16) = o;
    o[0]=pk2(ks[8],ks[9]); o[1]=pk2(ks[10],ks[11]); o[2]=pk2(ks[12],ks[13]); o[3]=pk2(ks[14],ks[15]);
    *(i32x4*)(rec + 4096 + (size_t)((it*4+3)*16 + (rc^12))*16) = o;
  }

  // ---- P1b: lane (t=c16, group g): write AT,RT,BT,KT ----
  {
    int tt=c16, gg=g;
    f32x4 pa[4], pp[4];
    int tp = (tt==0)?0:(tt-1);
    #pragma unroll
    for (int q=0;q<4;q++){
      pa[q] = *(const f32x4*)(&pbuf[tt*68 + 16*gg + 4*q]);
      pp[q] = *(const f32x4*)(&pbuf[tp*68 + 16*gg + 4*q]);
    }
    if (tt==0){
      #pragma unroll
      for (int q=0;q<4;q++) pp[q] = (f32x4){1.f,1.f,1.f,1.f};
    }
    f32x4 ra[4], rr[4], rb[4], rk[4];
    #pragma unroll
    for (int q=0;q<4;q++){
      ra[q]=*(const f32x4*)(&raw[tt*396+256+16*gg+4*q]);
      rr[q]=*(const f32x4*)(&raw[tt*396+    16*gg+4*q]);
      rb[q]=*(const f32x4*)(&raw[tt*396+320+16*gg+4*q]);
      rk[q]=*(const f32x4*)(&raw[tt*396+128+16*gg+4*q]);
    }
    float va[16], vr[16], vb2[16], vk2[16];
    #pragma unroll
    for (int q=0;q<4;q++)
      #pragma unroll
      for (int e=0;e<4;e++){
        float rp = __builtin_amdgcn_rcpf(pa[q][e]);
        va[q*4+e] = pp[q][e]*ra[q][e];
        vr[q*4+e] = pa[q][e]*rr[q][e];
        vb2[q*4+e] = rb[q][e]*rp;
        vk2[q*4+e] = rk[q][e]*rp;
      }
    i32x4 o;
    o[0]=pk2(va[0],va[1]); o[1]=pk2(va[2],va[3]); o[2]=pk2(va[4],va[5]); o[3]=pk2(va[6],va[7]);
    *(i32x4*)(&AT[tt*72+16*gg]) = o;
    o[0]=pk2(va[8],va[9]); o[1]=pk2(va[10],va[11]); o[2]=pk2(va[12],va[13]); o[3]=pk2(va[14],va[15]);
    *(i32x4*)(&AT[tt*72+16*gg+8]) = o;
    o[0]=pk2(vr[0],vr[1]); o[1]=pk2(vr[2],vr[3]); o[2]=pk2(vr[4],vr[5]); o[3]=pk2(vr[6],vr[7]);
    *(i32x4*)(&RT[tt*72+16*gg]) = o;
    o[0]=pk2(vr[8],vr[9]); o[1]=pk2(vr[10],vr[11]); o[2]=pk2(vr[12],vr[13]); o[3]=pk2(vr[14],vr[15]);
    *(i32x4*)(&RT[tt*72+16*gg+8]) = o;
    o[0]=pk2(vb2[0],vb2[1]); o[1]=pk2(vb2[2],vb2[3]); o[2]=pk2(vb2[4],vb2[5]); o[3]=pk2(vb2[6],vb2[7]);
    *(i32x4*)(&BT[tt*72+16*gg]) = o;
    o[0]=pk2(vb2[8],vb2[9]); o[1]=pk2(vb2[10],vb2[11]); o[2]=pk2(vb2[12],vb2[13]); o[3]=pk2(vb2[14],vb2[15]);
    *(i32x4*)(&BT[tt*72+16*gg+8]) = o;
    o[0]=pk2(vk2[0],vk2[1]); o[1]=pk2(vk2[2],vk2[3]); o[2]=pk2(vk2[4],vk2[5]); o[3]=pk2(vk2[6],vk2[7]);
    *(i32x4*)(&KT[tt*72+16*gg]) = o;
    o[0]=pk2(vk2[8],vk2[9]); o[1]=pk2(vk2[10],vk2[11]); o[2]=pk2(vk2[12],vk2[13]); o[3]=pk2(vk2[14],vk2[15]);
    *(i32x4*)(&KT[tt*72+16*gg+8]) = o;
  }

  // ---- W-block: N, Yhat, Tb, Tk ----
  {
    s16x8 afA[2], afR[2], bfB[2], bfK[2];
    #pragma unroll
    for (int Kt=0;Kt<2;Kt++){
      afA[Kt]=*(const s16x8*)(&AT[c16*72 + 32*Kt + 8*g]);
      afR[Kt]=*(const s16x8*)(&RT[c16*72 + 32*Kt + 8*g]);
      bfB[Kt]=*(const s16x8*)(&BT[c16*72 + 32*Kt + 8*g]);
      bfK[Kt]=*(const s16x8*)(&KT[c16*72 + 32*Kt + 8*g]);
    }
    f32x4 dNN={0.f,0.f,0.f,0.f}, dNY=dNN, dBB=dNN, dBK=dNN;
    #pragma unroll
    for (int Kt=0;Kt<2;Kt++){
      dNN=MFMA32(afA[Kt],bfB[Kt],dNN);
      dNY=MFMA32(afA[Kt],bfK[Kt],dNY);
      dBB=MFMA32(afR[Kt],bfB[Kt],dBB);
      dBK=MFMA32(afR[Kt],bfK[Kt],dBK);
    }
    #pragma unroll
    for (int e=0;e<4;e++){
      int tR=4*g+e, sC=c16;
      WN[tR*17+sC] = dNN[e];
      WY[tR*24+sC] = (sC<tR)? f2bf(dNY[e]) : (u16)0;
      WB[tR*24+sC] = (sC<=tR)? f2bf(dBB[e]) : (u16)0;
      WK[tR*24+sC] = (sC<=tR)? f2bf(dBK[e]) : (u16)0;
    }
  }

  // ---- YhatV -> rhsb ----
  s16x8 vf[4];
  #pragma unroll
  for (int J=0;J<4;J++){
    vf[J]=zero8;
    if (g<2) vf[J]=*(const s16x8*)(&vbb[(16*J+c16)*24 + 8*g]);
  }
  {
    s16x8 wyf=zero8;
    if (g<2) wyf=*(const s16x8*)(&WY[c16*24 + 8*g]);
    f32x4 dR[4];
    #pragma unroll
    for (int J=0;J<4;J++){
      dR[J]=(f32x4){0.f,0.f,0.f,0.f};
      dR[J]=MFMA32(wyf,vf[J],dR[J]);
      #pragma unroll
      for (int e=0;e<4;e++)
        rhsb[(4*g+e)*68 + 16*J + c16] = dR[J][e];
    }
  }

  // ---- P-solve: (I-N)P = Atil, lane = column j=l ----
  {
    float pv[16];
    #pragma unroll
    for (int t=0;t<16;t++) pv[t]=bf2f(AT[t*72+l]);
    #pragma unroll
    for (int t=1;t<16;t++)
      #pragma unroll
      for (int s=0;s<16;s++){
        if (s<t) pv[t] += WN[t*17+s]*pv[s];
      }
    i32x4 o;
    o[0]=pk2(pv[0],pv[1]); o[1]=pk2(pv[2],pv[3]); o[2]=pk2(pv[4],pv[5]); o[3]=pk2(pv[6],pv[7]);
    *(i32x4*)(&pbb[l*24]) = o;
    o[0]=pk2(pv[8],pv[9]); o[1]=pk2(pv[10],pv[11]); o[2]=pk2(pv[12],pv[13]); o[3]=pk2(pv[14],pv[15]);
    *(i32x4*)(&pbb[l*24+8]) = o;
    #pragma unroll
    for (int t=0;t<16;t++) ptmp[t*68+l]=pv[t];
  }

  // ---- z-solve: (I-N)zloc = YhatV, lane = column i=l ----
  {
    float zz[16];
    #pragma unroll
    for (int t=0;t<16;t++) zz[t]=rhsb[t*68+l];
    #pragma unroll
    for (int t=1;t<16;t++)
      #pragma unroll
      for (int s=0;s<16;s++){
        if (s<t) zz[t] += WN[t*17+s]*zz[s];
      }
    i32x4 o;
    o[0]=pk2(zz[0],zz[1]); o[1]=pk2(zz[2],zz[3]); o[2]=pk2(zz[4],zz[5]); o[3]=pk2(zz[6],zz[7]);
    *(i32x4*)(&zbb[l*24]) = o;
    o[0]=pk2(zz[8],zz[9]); o[1]=pk2(zz[10],zz[11]); o[2]=pk2(zz[12],zz[13]); o[3]=pk2(zz[14],zz[15]);
    *(i32x4*)(&zbb[l*24+8]) = o;
  }

  // ---- G = Rtil + Tb*P -> gtmp ; Yloc = Tb*zloc + Tk*V -> record slice ----
  {
    s16x8 wbf=zero8, wkf=zero8;
    if (g<2){
      wbf=*(const s16x8*)(&WB[c16*24 + 8*g]);
      wkf=*(const s16x8*)(&WK[c16*24 + 8*g]);
    }
    #pragma unroll
    for (int J=0;J<4;J++){
      s16x8 pfB=zero8, zfB=zero8;
      if (g<2){
        pfB=*(const s16x8*)(&pbb[(16*J+c16)*24 + 8*g]);
        zfB=*(const s16x8*)(&zbb[(16*J+c16)*24 + 8*g]);
      }
      f32x4 dG, dYl=(f32x4){0.f,0.f,0.f,0.f};
      #pragma unroll
      for (int e=0;e<4;e++) dG[e]=bf2f(RT[(4*g+e)*72 + 16*J + c16]);
      dG=MFMA32(wbf,pfB,dG);
      dYl=MFMA32(wbf,zfB,dYl);
      dYl=MFMA32(wkf,vf[J],dYl);
      #pragma unroll
      for (int e=0;e<4;e++) gtmp[(4*g+e)*68 + 16*J + c16]=dG[e];
      i32x2 o2; o2[0]=pk2(dYl[0],dYl[1]); o2[1]=pk2(dYl[2],dYl[3]);
      *(i32x2*)(rec + 8192 + (size_t)J*1536 + 512 + (size_t)l*8) = o2;
    }
  }

  // ---- zloc into record slices ----
  #pragma unroll
  for (int it=0;it<4;it++)
    *(i32x2*)(rec + 8192 + (size_t)it*1536 + (size_t)l*8) =
      *(const i32x2*)(&zbb[(16*it+c16)*24 + 4*g]);

  // ---- P_f / G_f rows from ptmp/gtmp ----
  #pragma unroll
  for (int kk=0;kk<2;kk++){
    f32x4 a0 = *(const f32x4*)(&ptmp[c16*68 + 32*kk + 8*g]);
    f32x4 a1 = *(const f32x4*)(&ptmp[c16*68 + 32*kk + 8*g + 4]);
    i32x4 o;
    o[0]=pk2(a0[0],a0[1]); o[1]=pk2(a0[2],a0[3]); o[2]=pk2(a1[0],a1[1]); o[3]=pk2(a1[2],a1[3]);
    *(i32x4*)(rec + (size_t)(kk*64+l)*16) = o;
    f32x4 b0 = *(const f32x4*)(&gtmp[c16*68 + 32*kk + 8*g]);
    f32x4 b1 = *(const f32x4*)(&gtmp[c16*68 + 32*kk + 8*g + 4]);
    o[0]=pk2(b0[0],b0[1]); o[1]=pk2(b0[2],b0[3]); o[2]=pk2(b1[0],b1[1]); o[3]=pk2(b1[2],b1[3]);
    *(i32x4*)(rec + 2048 + (size_t)(kk*64+l)*16) = o;
  }
}

// ---------------- serial scan v5: 1 wave per (bh, i-strip), depth-2 prefetch ring ----------
// Per chunk: 11 gload_lds (issued 2 chunks ahead, triple-buffered), counted vmcnt(15):
// steady-state outstanding = L(ch) 11 + S(ch-2) 4 + L(ch+1) 11 + S(ch-1) 4; vmcnt(15)
// drains exactly L(ch)+S(ch-2). Prologue stages ch0+ch1 then vmcnt(11).
__global__ __launch_bounds__(64) void scan2_kernel(char* ws, const float* S0, float* dout){
  float* YB=(float*)(ws+OFF_YBUF);
  const char* recb = ws + OFF_REC;
  const float* PLg = (const float*)(ws+OFF_PL);
  int bid=blockIdx.x, bh=bid>>2, w=bid&3;
  int l=threadIdx.x, c16=l&15, g=l>>4;

  __shared__ __align__(16) char buf[3][10240];
  __shared__ __align__(16) float plring[3][64];
  __shared__ __align__(16) u16 zT[16*24];
  __shared__ __align__(16) u16 ST[16*88];

  // Sreg[jt][e] = S^T[16jt+4g+e][i=16w+c16]
  f32x4 Sreg[4];
  #pragma unroll
  for (int jt=0;jt<4;jt++)
    Sreg[jt] = *(const f32x4*)(S0 + (size_t)bh*4096 + (size_t)(16*w+c16)*64 + 16*jt + 4*g);
  #pragma unroll
  for (int jt=0;jt<4;jt++){
    i32x2 p; p[0]=pk2(Sreg[jt][0],Sreg[jt][1]); p[1]=pk2(Sreg[jt][2],Sreg[jt][3]);
    *(i32x2*)(&ST[c16*88 + 16*jt + 4*g]) = p;
  }

  const char* rb = recb + (size_t)(bh*64)*14336;
  const float* plb = PLg + (size_t)(bh*64)*64;

  // prologue: stage chunks 0 and 1 (11 loads each), then ensure chunk 0 resident
  #pragma unroll
  for (int pc=0; pc<2; ++pc){
    const float* r0 = (const float*)(rb + (size_t)pc*14336);
    float* d = (float*)(&buf[pc][0]);
    #pragma unroll
    for (int q=0;q<8;q++) gload_lds16(r0 + q*256 + l*4, d + q*256);
    const float* rs = (const float*)(rb + (size_t)pc*14336 + 8192 + (size_t)w*1536);
    gload_lds16(rs + l*4, d + 2048);
    gload_lds16(rs + 256 + l*4, d + 2304);   // 512B valid + 512B overshoot pad
    gload_lds4(plb + pc*64 + l, &plring[pc][0]);
  }
  asm volatile("s_waitcnt vmcnt(11)" ::: "memory");
  __builtin_amdgcn_sched_barrier(0);

  float* yb0 = YB + (size_t)bh*65536;
  int cur=0;

  #pragma unroll 1
  for (int ch=0; ch<64; ++ch){
    asm volatile("s_waitcnt vmcnt(15)" ::: "memory");
    __builtin_amdgcn_sched_barrier(0);
    const char* bp = &buf[cur][0];
    const float* plv = &plring[cur][0];

    s16x8 pf[2], gf[2], sB[2], barkar[4];
    #pragma unroll
    for (int kk=0;kk<2;kk++){
      pf[kk]=*(const s16x8*)(bp + (size_t)(kk*64+l)*16);
      gf[kk]=*(const s16x8*)(bp + 2048 + (size_t)(kk*64+l)*16);
      sB[kk]=*(const s16x8*)(&ST[c16*88 + 32*kk + 8*g]);
    }
    #pragma unroll
    for (int jt=0;jt<4;jt++)
      barkar[jt]=*(const s16x8*)(bp + 4096 + (size_t)((jt*4+g)*16 + (c16 ^ (g<<2)))*16);
    i32x2 zlv=*(const i32x2*)(bp + 8192 + (size_t)l*8);
    i32x2 ylv=*(const i32x2*)(bp + 8704 + (size_t)l*8);

    // prefetch chunk ch+2 into slot cur+2 (mod 3)
    {
      int p2 = cur+2; if (p2>=3) p2-=3;
      int nc = ch+2; if (nc>63) nc=63;
      const float* r = (const float*)(rb + (size_t)nc*14336);
      float* d = (float*)(&buf[p2][0]);
      #pragma unroll
      for (int q=0;q<8;q++) gload_lds16(r + q*256 + l*4, d + q*256);
      const float* rs = (const float*)(rb + (size_t)nc*14336 + 8192 + (size_t)w*1536);
      gload_lds16(rs + l*4, d + 2048);
      gload_lds16(rs + 256 + l*4, d + 2304);
      gload_lds4(plb + nc*64 + l, &plring[p2][0]);
    }

    // z = P.S^T + zloc ; Y = G.S^T + Yloc   (own i-strip); dz via 2 independent MFMAs
    f32x4 dz1=cvt4(zlv), dz2=(f32x4){0.f,0.f,0.f,0.f};
    dz1=MFMA32(pf[0],sB[0],dz1);
    dz2=MFMA32(pf[1],sB[1],dz2);
    f32x4 dz = dz1+dz2;
    f32x4 dy=cvt4(ylv);
    dy=MFMA32(gf[0],sB[0],dy); dy=MFMA32(gf[1],sB[1],dy);

    // z -> B-frag via private LDS transpose; K-slots 16..31 come from record V
    {
      i32x2 zp; zp[0]=pk2(dz[0],dz[1]); zp[1]=pk2(dz[2],dz[3]);
      *(i32x2*)(&zT[c16*24 + 4*g]) = zp;
    }
    s16x8 zvf = (g<2) ? *(const s16x8*)(&zT[c16*24 + 8*g])
                      : *(const s16x8*)(bp + 9216 + (size_t)((g-2)*16 + c16)*16);

    // S' = diag(pL) S + [Bbar;Kbar]^T [z;V]   (one MFMA per j-tile)
    #pragma unroll
    for (int jt=0;jt<4;jt++){
      f32x4 pl4 = *(const f32x4*)(plv + 16*jt + 4*g);
      f32x4 acc = Sreg[jt]*pl4;
      acc=MFMA32(barkar[jt],zvf,acc);
      Sreg[jt]=acc;
    }
    #pragma unroll
    for (int jt=0;jt<4;jt++){
      i32x2 p; p[0]=pk2(Sreg[jt][0],Sreg[jt][1]); p[1]=pk2(Sreg[jt][2],Sreg[jt][3]);
      *(i32x2*)(&ST[c16*88 + 16*jt + 4*g]) = p;
    }
    // y stores (4 global stores, younger than all prefetch loads in vmcnt queue)
    {
      float* yb = yb0 + (size_t)ch*1024;
      #pragma unroll
      for (int e=0;e<4;e++)
        yb[(size_t)(4*g+e)*64 + 16*w + c16] = dy[e];
    }
    cur = (cur+1==3)?0:cur+1;
  }

  // final state
  #pragma unroll
  for (int jt=0;jt<4;jt++)
    *(f32x4*)(dout + 2097152 + (size_t)bh*4096 + (size_t)(16*w+c16)*64 + 16*jt + 4*g) = Sreg[jt];
}

// ---------------- epilogue: groupnorm + bonus + gate -> bf16 ----------------
__global__ __launch_bounds__(256) void epi_kernel(char* ws, const float* rk,
  const float* lnw, const float* lnb)
{
  const float* YB=(const float*)(ws+OFF_YBUF);
  const float* SEQf=(const float*)(ws+OFF_SEQ);
  const float* GB=(const float*)(ws+OFF_GBUF);
  u16* XGB=(u16*)(ws+OFF_XGB);
  int m=blockIdx.x, b=m>>10, t=m&1023;
  int tid=threadIdx.x, c0=tid*4, h=c0>>6, i0=c0&63;
  f32x4 y=*(const f32x4*)(YB + ((size_t)(b*16+h)*1024+t)*64 + i0);
  float s = y[0]+y[1]+y[2]+y[3];
  float ss= y[0]*y[0]+y[1]*y[1]+y[2]*y[2]+y[3]*y[3];
  #pragma unroll
  for (int mk=1;mk<16;mk<<=1){ s+=__shfl_xor(s,mk); ss+=__shfl_xor(ss,mk); }
  float mu=s*(1.0f/64.0f), var=ss*(1.0f/64.0f)-mu*mu;
  float inv=rsqrtf(var + 6.4e-4f);
  size_t sb=((size_t)(b*16+h)*1024+t)*384;
  f32x4 r=*(const f32x4*)(SEQf+sb+i0);
  f32x4 k=*(const f32x4*)(SEQf+sb+128+i0);
  f32x4 v=*(const f32x4*)(SEQf+sb+192+i0);
  f32x4 q=*(const f32x4*)(rk + h*64 + i0);
  float dp = r[0]*k[0]*q[0]+r[1]*k[1]*q[1]+r[2]*k[2]*q[2]+r[3]*k[3]*q[3];
  #pragma unroll
  for (int mk=1;mk<16;mk<<=1) dp+=__shfl_xor(dp,mk);
  f32x4 gg=*(const f32x4*)(GB+(size_t)m*1024+c0);
  u16x4 outv;
  #pragma unroll
  for (int j=0;j<4;j++){
    float xn = (y[j]-mu)*inv*lnw[c0+j] + lnb[c0+j] + dp*v[j];
    outv[j]=f2bf(xn*gg[j]);
  }
  *(u16x4*)(XGB+(size_t)m*1024+c0)=outv;
}

extern "C" void kernel_launch(void* const* d_in, const int* in_sizes, int n_in,
                              void* d_out, int out_size, void* d_ws, size_t ws_size,
                              hipStream_t stream) {
  const float* x      =(const float*)d_in[0];
  const float* S0     =(const float*)d_in[1];
  const float* vfirst =(const float*)d_in[2];
  const float* w0     =(const float*)d_in[3];
  const float* w1     =(const float*)d_in[4];
  const float* w2     =(const float*)d_in[5];
  const float* a0     =(const float*)d_in[6];
  const float* a1     =(const float*)d_in[7];
  const float* a2     =(const float*)d_in[8];
  const float* v0     =(const float*)d_in[9];
  const float* v1     =(const float*)d_in[10];
  const float* v2     =(const float*)d_in[11];
  const float* g1     =(const float*)d_in[12];
  const float* g2     =(const float*)d_in[13];
  const float* k_k    =(const float*)d_in[14];
  const float* k_a    =(const float*)d_in[15];
  const float* r_k    =(const float*)d_in[16];
  const float* Wq     =(const float*)d_in[17];
  const float* Wk     =(const float*)d_in[18];
  const float* Wv     =(const float*)d_in[19];
  const float* Wo     =(const float*)d_in[20];
  const float* ln_w   =(const float*)d_in[21];
  const float* ln_b   =(const float*)d_in[22];
  char* ws=(char*)d_ws;
  float* dout=(float*)d_out;

  prep_kernel<<<2048,256,0,stream>>>(ws,x,vfirst,w1,w2,a1,a2,v1,v2,g1,g2,Wq,Wk,Wv,Wo,dout);
  gemm_kernel<<<dim3(16,19),256,0,stream>>>(0,ws,w0,a0,v0,dout);
  gemm_kernel<<<dim3(16,32),256,0,stream>>>(1,ws,w0,a0,v0,dout);
  prep2_kernel<<<2048,256,0,stream>>>(ws,vfirst,k_k,k_a);
  pre_kernel<<<2048,64,0,stream>>>(ws);
  scan2_kernel<<<128,64,0,stream>>>(ws,S0,dout);
  epi_kernel<<<2048,256,0,stream>>>(ws,r_k,ln_w,ln_b);
  gemm_kernel<<<dim3(16,8),256,0,stream>>>(2,ws,w0,a0,v0,dout);
}

// Round 9
// 225.605 us; speedup vs baseline: 1.0526x; 1.0526x over previous
//
#include <hip/hip_runtime.h>

typedef unsigned short u16;
typedef __attribute__((ext_vector_type(8))) short s16x8;
typedef __attribute__((ext_vector_type(4))) float f32x4;
typedef __attribute__((ext_vector_type(4))) int   i32x4;
typedef __attribute__((ext_vector_type(2))) int   i32x2;
typedef __attribute__((ext_vector_type(4))) unsigned short u16x4;

// ---------------- workspace layout (bytes) ----------------
constexpr size_t OFF_XB   = 0;                     // bf16 x          [2048][1024]
constexpr size_t OFF_WQB  = OFF_XB   + 4194304;    // bf16 Wq         [1024][1024]
constexpr size_t OFF_WKB  = OFF_WQB  + 2097152;    // bf16 Wk         [512][1024]
constexpr size_t OFF_WVB  = OFF_WKB  + 1048576;    // bf16 Wv         [512][1024]
constexpr size_t OFF_WOB  = OFF_WVB  + 1048576;    // bf16 Wo         [1024][1024]
constexpr size_t OFF_W1T  = OFF_WOB  + 2097152;    // bf16 W1T        [384][1024]
constexpr size_t OFF_W2T  = OFF_W1T  + 786432;     // bf16 w2T        [1024][64]
constexpr size_t OFF_A2T  = OFF_W2T  + 131072;     // bf16 a2T        [1024][64]
constexpr size_t OFF_V2T  = OFF_A2T  + 131072;     // bf16 v2T        [1024][32]
constexpr size_t OFF_G2T  = OFF_V2T  + 65536;      // bf16 g2T        [1024][160]
constexpr size_t OFF_KQF  = OFF_G2T  + 327680;     // f32 k-proj [2048][512]; later VEPI/DP
constexpr size_t OFF_VQF  = OFF_KQF  + 4194304;    // f32 v-proj      [2048][512]
constexpr size_t OFF_URAW = OFF_VQF  + 4194304;    // (dead; kept for layout)
constexpr size_t OFF_UB   = OFF_URAW + 2621440;    // bf16 stage1 act [2048][384]
constexpr size_t OFF_S2A  = OFF_UB   + 1572864;    // f32 iclr        [2048][1024]
constexpr size_t OFF_S2V  = OFF_S2A  + 8388608;    // f32 vmix        [2048][1024]
constexpr size_t OFF_GBUF = OFF_S2V  + 8388608;    // f32 gate        [2048][1024]
constexpr size_t OFF_SEQ  = OFF_GBUF + 8388608;    // f32 SEQ [2048 chunks][24576B]; later records
constexpr size_t OFF_YBUF = OFF_SEQ  + 50331648;   // f32 y   [2][16][1024][64]
constexpr size_t OFF_XGB  = OFF_YBUF + 8388608;    // bf16 xn*g       [2048][1024]

// per-chunk record overlay in SEQ, stride 24576 (block overwrites its OWN chunk):
// 0: Q A-frags [kk2][jt4][lane]x16B (8192) | 8192: G A-frags [kk2][lane]x16B (2048)
// 10240: pL f32[64] (256) | 10496 + w*2560: { c[jt4][lane]x8B (2048) | Yloc[lane]x8B (512) }
constexpr size_t OFF_VEPI = OFF_KQF;               // bf16 v rows [32][1024][64]  (4MB)
constexpr size_t OFF_DP   = OFF_KQF + 4194304;     // f32 dp [32][1024]           (128KB)

__device__ __forceinline__ u16 f2bf(float f){
  unsigned int u = __builtin_bit_cast(unsigned int, f);
  u = u + 0x7fffu + ((u >> 16) & 1u);
  return (u16)(u >> 16);
}
__device__ __forceinline__ int pk2(float a, float b){
  return (int)((unsigned)f2bf(a) | ((unsigned)f2bf(b) << 16));
}
__device__ __forceinline__ int cvtpk(float a, float b){
  int r;
  asm("v_cvt_pk_bf16_f32 %0, %1, %2" : "=v"(r) : "v"(a), "v"(b));
  return r;
}
__device__ __forceinline__ float bf2f(u16 h){
  return __builtin_bit_cast(float, ((unsigned)h) << 16);
}
__device__ __forceinline__ f32x4 cvt4(i32x2 v){
  unsigned a=(unsigned)v[0], b=(unsigned)v[1];
  f32x4 r;
  r[0]=__builtin_bit_cast(float, a<<16);
  r[1]=__builtin_bit_cast(float, a&0xffff0000u);
  r[2]=__builtin_bit_cast(float, b<<16);
  r[3]=__builtin_bit_cast(float, b&0xffff0000u);
  return r;
}

__device__ __forceinline__ void gload_lds16(const float* g, float* l){
  __builtin_amdgcn_global_load_lds((const __attribute__((address_space(1))) void*)g,
                                   (__attribute__((address_space(3))) void*)l, 16, 0, 0);
}
__device__ __forceinline__ void gload_lds4(const float* g, float* l){
  __builtin_amdgcn_global_load_lds((const __attribute__((address_space(1))) void*)g,
                                   (__attribute__((address_space(3))) void*)l, 4, 0, 0);
}

// ---------------- prep: convert/transpose + v_first passthrough ----------------
constexpr size_t N_XB=2097152, N_WQ=1048576, N_WK=524288, N_WV=524288, N_WO=1048576,
  N_W1T=393216, N_W2T=65536, N_A2T=65536, N_V2T=32768, N_G2T=163840, N_VF=2097152;
constexpr size_t PREP_TOT = N_XB+N_WQ+N_WK+N_WV+N_WO+N_W1T+N_W2T+N_A2T+N_V2T+N_G2T+N_VF;

__global__ __launch_bounds__(256) void prep_kernel(char* ws, const float* x, const float* vfirst,
  const float* w1, const float* w2, const float* a1, const float* a2,
  const float* v1, const float* v2, const float* g1, const float* g2,
  const float* Wq, const float* Wk, const float* Wv, const float* Wo, float* dout)
{
  u16* XB=(u16*)(ws+OFF_XB); u16* WQB=(u16*)(ws+OFF_WQB); u16* WKB=(u16*)(ws+OFF_WKB);
  u16* WVB=(u16*)(ws+OFF_WVB); u16* WOB=(u16*)(ws+OFF_WOB); u16* W1T=(u16*)(ws+OFF_W1T);
  u16* W2T=(u16*)(ws+OFF_W2T); u16* A2T=(u16*)(ws+OFF_A2T); u16* V2T=(u16*)(ws+OFF_V2T);
  u16* G2T=(u16*)(ws+OFF_G2T);
  for (size_t idx=(size_t)blockIdx.x*256+threadIdx.x; idx<PREP_TOT; idx+=(size_t)gridDim.x*256){
    size_t r = idx;
    if (r < N_XB){ XB[r]=f2bf(x[r]); continue; } r-=N_XB;
    if (r < N_WQ){ WQB[r]=f2bf(Wq[r]); continue; } r-=N_WQ;
    if (r < N_WK){ WKB[r]=f2bf(Wk[r]); continue; } r-=N_WK;
    if (r < N_WV){ WVB[r]=f2bf(Wv[r]); continue; } r-=N_WV;
    if (r < N_WO){ WOB[r]=f2bf(Wo[r]); continue; } r-=N_WO;
    if (r < N_W1T){
      int n=(int)(r>>10), k=(int)(r&1023); float v=0.f;
      if (n<64) v=w1[(size_t)k*64+n];
      else if (n<128) v=a1[(size_t)k*64+(n-64)];
      else if (n<160) v=v1[(size_t)k*32+(n-128)];
      else if (n<320) v=g1[(size_t)k*160+(n-160)];
      W1T[r]=f2bf(v); continue; } r-=N_W1T;
    if (r < N_W2T){ int c=(int)(r>>6), d=(int)(r&63); W2T[r]=f2bf(w2[(size_t)d*1024+c]); continue; } r-=N_W2T;
    if (r < N_A2T){ int c=(int)(r>>6), d=(int)(r&63); A2T[r]=f2bf(a2[(size_t)d*1024+c]); continue; } r-=N_A2T;
    if (r < N_V2T){ int c=(int)(r>>5), d=(int)(r&31); V2T[r]=f2bf(v2[(size_t)d*1024+c]); continue; } r-=N_V2T;
    if (r < N_G2T){ int c=(int)(r/160), d=(int)(r%160); G2T[r]=f2bf(g2[(size_t)d*1024+c]); continue; } r-=N_G2T;
    dout[2228224 + r] = vfirst[r];   // v_first passthrough (offset 2097152+131072)
  }
}

// ---------------- unified NT bf16 MFMA GEMM: C[m][n] = sum_k A[m][k]*B[n][k] ----------------
__global__ __launch_bounds__(256) void gemm_kernel(int phase, char* ws,
  const float* w0b, const float* a0b, const float* v0b, float* dout)
{
  const u16* A; const u16* Bw;
  float* outF=nullptr; const float* bias=nullptr;
  float* SEQf=(float*)(ws+OFF_SEQ);
  u16* UBp=(u16*)(ws+OFF_UB);
  int lda=0, ldb=0, K=0, ldc=0, Nlim=1024, col0=0, outMode=0;
  int y = blockIdx.y;
  if (phase==0){
    A=(const u16*)(ws+OFF_XB); lda=1024; K=1024;
    if (y<8)      { Bw=(const u16*)(ws+OFF_WQB); ldb=1024; col0=y*128;       outMode=1; }
    else if (y<12){ Bw=(const u16*)(ws+OFF_WKB); ldb=1024; col0=(y-8)*128;   outF=(float*)(ws+OFF_KQF); ldc=512; Nlim=512; }
    else if (y<16){ Bw=(const u16*)(ws+OFF_WVB); ldb=1024; col0=(y-12)*128;  outF=(float*)(ws+OFF_VQF); ldc=512; Nlim=512; }
    else          { Bw=(const u16*)(ws+OFF_W1T); ldb=1024; col0=(y-16)*128;  outMode=4; Nlim=320; }
  } else if (phase==1){
    int seg=y>>3; col0=(y&7)*128;
    const int Ks[4]={64,64,32,160};
    const int Ao[4]={0,64,128,160};
    K=Ks[seg]; lda=384; ldb=K;
    A=(const u16*)(ws+OFF_UB) + Ao[seg];
    if (seg==0)     { Bw=(const u16*)(ws+OFF_W2T); outMode=2; bias=w0b; }
    else if (seg==1){ Bw=(const u16*)(ws+OFF_A2T); outMode=3; bias=a0b; outF=(float*)(ws+OFF_S2A); ldc=1024; }
    else if (seg==2){ Bw=(const u16*)(ws+OFF_V2T); outMode=3; bias=v0b; outF=(float*)(ws+OFF_S2V); ldc=1024; }
    else            { Bw=(const u16*)(ws+OFF_G2T); outF=(float*)(ws+OFF_GBUF); ldc=1024; }
  } else {
    A=(const u16*)(ws+OFF_XGB); lda=1024; K=1024;
    Bw=(const u16*)(ws+OFF_WOB); ldb=1024; col0=y*128; outF=dout; ldc=1024;
  }
  int m0 = blockIdx.x*128;
  __shared__ __align__(16) u16 As[128][40];
  __shared__ __align__(16) u16 Bs[128][40];
  int tid=threadIdx.x, l=tid&63, wv=tid>>6, wm=wv>>1, wn=wv&1;
  f32x4 acc[4][4];
  #pragma unroll
  for (int i=0;i<4;i++)
    #pragma unroll
    for (int j=0;j<4;j++) acc[i][j]=(f32x4){0.f,0.f,0.f,0.f};

  for (int k0=0;k0<K;k0+=32){
    #pragma unroll
    for (int c=tid;c<512;c+=256){
      int row=c>>2, seg=c&3;
      *(i32x4*)(&As[row][seg*8]) = *(const i32x4*)(A  + (size_t)(m0+row)*lda  + k0 + seg*8);
      *(i32x4*)(&Bs[row][seg*8]) = *(const i32x4*)(Bw + (size_t)(col0+row)*ldb + k0 + seg*8);
    }
    __syncthreads();
    int kseg=(l>>4)*8, rrow=l&15;
    s16x8 af[4], bf[4];
    #pragma unroll
    for (int mt=0;mt<4;mt++) af[mt]=*(const s16x8*)(&As[wm*64+mt*16+rrow][kseg]);
    #pragma unroll
    for (int nt=0;nt<4;nt++) bf[nt]=*(const s16x8*)(&Bs[wn*64+nt*16+rrow][kseg]);
    #pragma unroll
    for (int mt=0;mt<4;mt++)
      #pragma unroll
      for (int nt=0;nt<4;nt++)
        acc[mt][nt]=__builtin_amdgcn_mfma_f32_16x16x32_bf16(af[mt],bf[nt],acc[mt][nt],0,0,0);
    __syncthreads();
  }
  // epilogue
  #pragma unroll
  for (int mt=0;mt<4;mt++){
    #pragma unroll
    for (int nt=0;nt<4;nt++){
      int nglob = col0 + wn*64 + nt*16 + (l&15);
      if (nglob >= Nlim) continue;
      #pragma unroll
      for (int rg=0;rg<4;rg++){
        int mrow = m0 + wm*64 + mt*16 + ((l>>4)<<2) + rg;
        float val = acc[mt][nt][rg];
        if (outMode==0){
          outF[(size_t)mrow*ldc + nglob] = val;
        } else if (outMode==1){          // r -> SEQ slot 0
          int b=mrow>>10, t=mrow&1023, h=nglob>>6, i=nglob&63;
          SEQf[(((size_t)(b*16+h)*1024+t)*384) + i] = val;
        } else if (outMode==2){          // decay -> SEQ slot 1
          float w = bias[nglob] + val;
          float d = expf(-expf(w));
          int b=mrow>>10, t=mrow&1023, h=nglob>>6, i=nglob&63;
          SEQf[(((size_t)(b*16+h)*1024+t)*384) + 64 + i] = d;
        } else if (outMode==3){          // sigmoid(bias+acc)
          float s = 1.0f/(1.0f+__expf(-(bias[nglob]+val)));
          outF[(size_t)mrow*ldc + nglob] = s;
        } else {                          // fused stage-1 activation -> UB bf16
          float a = (nglob<64) ? tanhf(val)
                  : (nglob<160) ? val
                  : 1.0f/(1.0f+__expf(-val));
          UBp[(size_t)mrow*384 + nglob] = f2bf(a);
        }
      }
    }
  }
}

// ---------------- prep2: build SEQ slots k,v,a,b ----------------
__global__ __launch_bounds__(256) void prep2_kernel(char* ws, const float* vfirst,
  const float* kk_s, const float* ka_s)
{
  const float* KQF=(const float*)(ws+OFF_KQF);
  const float* VQF=(const float*)(ws+OFF_VQF);
  const float* ICLR=(const float*)(ws+OFF_S2A);
  const float* VMIX=(const float*)(ws+OFF_S2V);
  float* SEQf=(float*)(ws+OFF_SEQ);
  int m=blockIdx.x, b=m>>10, t=m&1023;
  int tid=threadIdx.x, c0=tid*4, h=c0>>6, i0=c0&63, hk=h>>1;
  f32x4 kq=*(const f32x4*)(KQF+(size_t)m*512+hk*64+i0);
  f32x4 vq=*(const f32x4*)(VQF+(size_t)m*512+hk*64+i0);
  f32x4 ic=*(const f32x4*)(ICLR+(size_t)m*1024+c0);
  f32x4 vm=*(const f32x4*)(VMIX+(size_t)m*1024+c0);
  f32x4 vf=*(const f32x4*)(vfirst+(size_t)m*1024+c0);
  f32x4 kkc=*(const f32x4*)(kk_s+c0);
  f32x4 kac=*(const f32x4*)(ka_s+c0);
  f32x4 kk=kq*kkc;
  float ssq=kk[0]*kk[0]+kk[1]*kk[1]+kk[2]*kk[2]+kk[3]*kk[3];
  #pragma unroll
  for (int mk=1;mk<16;mk<<=1) ssq += __shfl_xor(ssq,mk);
  float scale = 1.0f / fmaxf(sqrtf(ssq), 1e-12f);
  f32x4 kf,vv,av,bv;
  #pragma unroll
  for (int j=0;j<4;j++){
    float icc = 1.0f + (ic[j]-1.0f)*kac[j];
    float kkn = kk[j]*scale;
    kf[j]=kq[j]*icc;
    vv[j]=vq[j] + (vf[j]-vq[j])*vm[j];
    av[j]=-kkn;
    bv[j]=kkn*icc;
  }
  size_t sb = (((size_t)(b*16+h)*1024)+t)*384 + i0;
  *(f32x4*)(SEQf+sb+128)=kf;
  *(f32x4*)(SEQf+sb+192)=vv;
  *(f32x4*)(SEQf+sb+256)=av;
  *(f32x4*)(SEQf+sb+320)=bv;
}

#define MFMA32(a,b,c) __builtin_amdgcn_mfma_f32_16x16x32_bf16(a,b,c,0,0,0)

// ---------------- precompute: per-chunk S-independent record (2048-way parallel) ------
// Produces per-chunk: Q = Bbar^T P (A-frags), G (A-frags), pL, per-strip c = Bbar^T zloc
// + Kbar^T V (D-frags) and Yloc; plus epi inputs dp[t], v rows. Record overlays own SEQ chunk.
__global__ __launch_bounds__(64) void pre_kernel(char* ws, const float* rkw){
  const float* SEQ=(const float*)(ws+OFF_SEQ);
  int bid=blockIdx.x, bh=bid>>6, ch=bid&63;
  int l=threadIdx.x, c16=l&15, g=l>>4;
  const float* seqb = SEQ + (size_t)bh*(1024*384) + (size_t)ch*6144;
  char* rec = ws + OFF_SEQ + (size_t)bid*24576;
  u16* VEPI=(u16*)(ws+OFF_VEPI);
  float* DPp=(float*)(ws+OFF_DP);

  __shared__ __align__(16) float raw[16*396];
  __shared__ __align__(16) float pbuf[16*68];
  __shared__ __align__(16) u16 AT[16*72];
  __shared__ __align__(16) u16 RT[16*72];
  __shared__ __align__(16) u16 BT[16*72];
  __shared__ __align__(16) u16 KT[16*72];
  __shared__ __align__(16) u16 vbb[64*24+16];
  __shared__ __align__(16) u16 zbb[64*24+16];
  __shared__ __align__(16) u16 pbb[64*24+16];
  __shared__ __align__(16) u16 BKL[64*40];         // row=channel j: bs[0..15], ks[0..15]
  __shared__ __align__(16) float WN[16*17];
  __shared__ __align__(16) u16 WY[16*24+16];
  __shared__ __align__(16) u16 WB[16*24+16];
  __shared__ __align__(16) u16 WK[16*24+16];
  __shared__ __align__(16) float rhsb[16*68];
  __shared__ __align__(16) float gtmp[16*68];
  const s16x8 zero8 = {0,0,0,0,0,0,0,0};
  const f32x4 zf4 = {0.f,0.f,0.f,0.f};

  #pragma unroll
  for (int t=0;t<16;t++){
    const float* src = seqb + (size_t)t*384;
    float* dst = &raw[t*396];
    gload_lds16(src + l*4, dst);
    gload_lds4 (src + 256 + l, dst + 256);
    gload_lds4 (src + 320 + l, dst + 320);
  }
  asm volatile("s_waitcnt vmcnt(0)" ::: "memory");
  __builtin_amdgcn_sched_barrier(0);

  // ---- P1a: lane = channel l. cumprod decay; vbb/BKL LDS; pL + VEPI writes ----
  {
    float ptv[16]; float pp=1.f;
    #pragma unroll
    for (int t=0;t<16;t++){ pp *= raw[t*396+64+l]; ptv[t]=pp; pbuf[t*68+l]=pp; }
    float pL = ptv[15];
    *(float*)(rec + 10240 + (size_t)l*4) = pL;
    float bs[16], ks[16], vs[16];
    #pragma unroll
    for (int t=0;t<16;t++){
      float sc = pL * __builtin_amdgcn_rcpf(ptv[t]);
      bs[t]=raw[t*396+320+l]*sc;
      ks[t]=raw[t*396+128+l]*sc;
      vs[t]=raw[t*396+192+l];
    }
    i32x4 o;
    o[0]=pk2(vs[0],vs[1]); o[1]=pk2(vs[2],vs[3]); o[2]=pk2(vs[4],vs[5]); o[3]=pk2(vs[6],vs[7]);
    *(i32x4*)(&vbb[l*24]) = o;
    o[0]=pk2(vs[8],vs[9]); o[1]=pk2(vs[10],vs[11]); o[2]=pk2(vs[12],vs[13]); o[3]=pk2(vs[14],vs[15]);
    *(i32x4*)(&vbb[l*24+8]) = o;
    o[0]=pk2(bs[0],bs[1]); o[1]=pk2(bs[2],bs[3]); o[2]=pk2(bs[4],bs[5]); o[3]=pk2(bs[6],bs[7]);
    *(i32x4*)(&BKL[l*40]) = o;
    o[0]=pk2(bs[8],bs[9]); o[1]=pk2(bs[10],bs[11]); o[2]=pk2(bs[12],bs[13]); o[3]=pk2(bs[14],bs[15]);
    *(i32x4*)(&BKL[l*40+8]) = o;
    o[0]=pk2(ks[0],ks[1]); o[1]=pk2(ks[2],ks[3]); o[2]=pk2(ks[4],ks[5]); o[3]=pk2(ks[6],ks[7]);
    *(i32x4*)(&BKL[l*40+16]) = o;
    o[0]=pk2(ks[8],ks[9]); o[1]=pk2(ks[10],ks[11]); o[2]=pk2(ks[12],ks[13]); o[3]=pk2(ks[14],ks[15]);
    *(i32x4*)(&BKL[l*40+24]) = o;
    size_t vb = ((size_t)bh*1024 + (size_t)ch*16)*64 + l;
    #pragma unroll
    for (int t=0;t<16;t++) VEPI[vb + (size_t)t*64] = f2bf(vs[t]);
  }

  // ---- P1b: lane (t=c16, group g): write AT,RT,BT,KT; dp for bonus ----
  {
    int tt=c16, gg=g;
    f32x4 pa[4], pp[4];
    int tp = (tt==0)?0:(tt-1);
    #pragma unroll
    for (int q=0;q<4;q++){
      pa[q] = *(const f32x4*)(&pbuf[tt*68 + 16*gg + 4*q]);
      pp[q] = *(const f32x4*)(&pbuf[tp*68 + 16*gg + 4*q]);
    }
    if (tt==0){
      #pragma unroll
      for (int q=0;q<4;q++) pp[q] = (f32x4){1.f,1.f,1.f,1.f};
    }
    f32x4 ra[4], rr[4], rb[4], kq2[4];
    #pragma unroll
    for (int q=0;q<4;q++){
      ra[q]=*(const f32x4*)(&raw[tt*396+256+16*gg+4*q]);
      rr[q]=*(const f32x4*)(&raw[tt*396+    16*gg+4*q]);
      rb[q]=*(const f32x4*)(&raw[tt*396+320+16*gg+4*q]);
      kq2[q]=*(const f32x4*)(&raw[tt*396+128+16*gg+4*q]);
    }
    // bonus dp[t] = sum_c r*k*r_k
    {
      float dp=0.f;
      #pragma unroll
      for (int q=0;q<4;q++){
        f32x4 rkv = *(const f32x4*)(rkw + (bh&15)*64 + 16*gg + 4*q);
        #pragma unroll
        for (int e=0;e<4;e++) dp += rr[q][e]*kq2[q][e]*rkv[e];
      }
      dp += __shfl_xor(dp,16); dp += __shfl_xor(dp,32);
      if (gg==0) DPp[(size_t)bh*1024 + ch*16 + tt] = dp;
    }
    float va[16], vr[16], vb2[16], vk2[16];
    #pragma unroll
    for (int q=0;q<4;q++)
      #pragma unroll
      for (int e=0;e<4;e++){
        float rp = __builtin_amdgcn_rcpf(pa[q][e]);
        va[q*4+e] = pp[q][e]*ra[q][e];
        vr[q*4+e] = pa[q][e]*rr[q][e];
        vb2[q*4+e] = rb[q][e]*rp;
        vk2[q*4+e] = kq2[q][e]*rp;
      }
    i32x4 o;
    o[0]=pk2(va[0],va[1]); o[1]=pk2(va[2],va[3]); o[2]=pk2(va[4],va[5]); o[3]=pk2(va[6],va[7]);
    *(i32x4*)(&AT[tt*72+16*gg]) = o;
    o[0]=pk2(va[8],va[9]); o[1]=pk2(va[10],va[11]); o[2]=pk2(va[12],va[13]); o[3]=pk2(va[14],va[15]);
    *(i32x4*)(&AT[tt*72+16*gg+8]) = o;
    o[0]=pk2(vr[0],vr[1]); o[1]=pk2(vr[2],vr[3]); o[2]=pk2(vr[4],vr[5]); o[3]=pk2(vr[6],vr[7]);
    *(i32x4*)(&RT[tt*72+16*gg]) = o;
    o[0]=pk2(vr[8],vr[9]); o[1]=pk2(vr[10],vr[11]); o[2]=pk2(vr[12],vr[13]); o[3]=pk2(vr[14],vr[15]);
    *(i32x4*)(&RT[tt*72+16*gg+8]) = o;
    o[0]=pk2(vb2[0],vb2[1]); o[1]=pk2(vb2[2],vb2[3]); o[2]=pk2(vb2[4],vb2[5]); o[3]=pk2(vb2[6],vb2[7]);
    *(i32x4*)(&BT[tt*72+16*gg]) = o;
    o[0]=pk2(vb2[8],vb2[9]); o[1]=pk2(vb2[10],vb2[11]); o[2]=pk2(vb2[12],vb2[13]); o[3]=pk2(vb2[14],vb2[15]);
    *(i32x4*)(&BT[tt*72+16*gg+8]) = o;
    o[0]=pk2(vk2[0],vk2[1]); o[1]=pk2(vk2[2],vk2[3]); o[2]=pk2(vk2[4],vk2[5]); o[3]=pk2(vk2[6],vk2[7]);
    *(i32x4*)(&KT[tt*72+16*gg]) = o;
    o[0]=pk2(vk2[8],vk2[9]); o[1]=pk2(vk2[10],vk2[11]); o[2]=pk2(vk2[12],vk2[13]); o[3]=pk2(vk2[14],vk2[15]);
    *(i32x4*)(&KT[tt*72+16*gg+8]) = o;
  }

  // ---- W-block: N, Yhat, Tb, Tk ----
  {
    s16x8 afA[2], afR[2], bfB[2], bfK[2];
    #pragma unroll
    for (int Kt=0;Kt<2;Kt++){
      afA[Kt]=*(const s16x8*)(&AT[c16*72 + 32*Kt + 8*g]);
      afR[Kt]=*(const s16x8*)(&RT[c16*72 + 32*Kt + 8*g]);
      bfB[Kt]=*(const s16x8*)(&BT[c16*72 + 32*Kt + 8*g]);
      bfK[Kt]=*(const s16x8*)(&KT[c16*72 + 32*Kt + 8*g]);
    }
    f32x4 dNN=zf4, dNY=zf4, dBB=zf4, dBK=zf4;
    #pragma unroll
    for (int Kt=0;Kt<2;Kt++){
      dNN=MFMA32(afA[Kt],bfB[Kt],dNN);
      dNY=MFMA32(afA[Kt],bfK[Kt],dNY);
      dBB=MFMA32(afR[Kt],bfB[Kt],dBB);
      dBK=MFMA32(afR[Kt],bfK[Kt],dBK);
    }
    #pragma unroll
    for (int e=0;e<4;e++){
      int tR=4*g+e, sC=c16;
      WN[tR*17+sC] = dNN[e];
      WY[tR*24+sC] = (sC<tR)? f2bf(dNY[e]) : (u16)0;
      WB[tR*24+sC] = (sC<=tR)? f2bf(dBB[e]) : (u16)0;
      WK[tR*24+sC] = (sC<=tR)? f2bf(dBK[e]) : (u16)0;
    }
  }

  // ---- YhatV -> rhsb ----
  s16x8 vf[4];
  #pragma unroll
  for (int J=0;J<4;J++){
    vf[J]=zero8;
    if (g<2) vf[J]=*(const s16x8*)(&vbb[(16*J+c16)*24 + 8*g]);
  }
  {
    s16x8 wyf=zero8;
    if (g<2) wyf=*(const s16x8*)(&WY[c16*24 + 8*g]);
    f32x4 dR[4];
    #pragma unroll
    for (int J=0;J<4;J++){
      dR[J]=zf4;
      dR[J]=MFMA32(wyf,vf[J],dR[J]);
      #pragma unroll
      for (int e=0;e<4;e++)
        rhsb[(4*g+e)*68 + 16*J + c16] = dR[J][e];
    }
  }

  // ---- P-solve: (I-N)P = Atil, lane = column j=l ----
  {
    float pv[16];
    #pragma unroll
    for (int t=0;t<16;t++) pv[t]=bf2f(AT[t*72+l]);
    #pragma unroll
    for (int t=1;t<16;t++)
      #pragma unroll
      for (int s=0;s<16;s++){
        if (s<t) pv[t] += WN[t*17+s]*pv[s];
      }
    i32x4 o;
    o[0]=pk2(pv[0],pv[1]); o[1]=pk2(pv[2],pv[3]); o[2]=pk2(pv[4],pv[5]); o[3]=pk2(pv[6],pv[7]);
    *(i32x4*)(&pbb[l*24]) = o;
    o[0]=pk2(pv[8],pv[9]); o[1]=pk2(pv[10],pv[11]); o[2]=pk2(pv[12],pv[13]); o[3]=pk2(pv[14],pv[15]);
    *(i32x4*)(&pbb[l*24+8]) = o;
  }

  // ---- z-solve: (I-N)zloc = YhatV, lane = column i=l ----
  {
    float zz[16];
    #pragma unroll
    for (int t=0;t<16;t++) zz[t]=rhsb[t*68+l];
    #pragma unroll
    for (int t=1;t<16;t++)
      #pragma unroll
      for (int s=0;s<16;s++){
        if (s<t) zz[t] += WN[t*17+s]*zz[s];
      }
    i32x4 o;
    o[0]=pk2(zz[0],zz[1]); o[1]=pk2(zz[2],zz[3]); o[2]=pk2(zz[4],zz[5]); o[3]=pk2(zz[6],zz[7]);
    *(i32x4*)(&zbb[l*24]) = o;
    o[0]=pk2(zz[8],zz[9]); o[1]=pk2(zz[10],zz[11]); o[2]=pk2(zz[12],zz[13]); o[3]=pk2(zz[14],zz[15]);
    *(i32x4*)(&zbb[l*24+8]) = o;
  }

  // ---- G = Rtil + Tb*P -> gtmp ; Yloc = Tb*zloc + Tk*V -> record strips ----
  {
    s16x8 wbf=zero8, wkf=zero8;
    if (g<2){
      wbf=*(const s16x8*)(&WB[c16*24 + 8*g]);
      wkf=*(const s16x8*)(&WK[c16*24 + 8*g]);
    }
    #pragma unroll
    for (int J=0;J<4;J++){
      s16x8 pfB=zero8, zfB=zero8;
      if (g<2){
        pfB=*(const s16x8*)(&pbb[(16*J+c16)*24 + 8*g]);
        zfB=*(const s16x8*)(&zbb[(16*J+c16)*24 + 8*g]);
      }
      f32x4 dG, dYl=zf4;
      #pragma unroll
      for (int e=0;e<4;e++) dG[e]=bf2f(RT[(4*g+e)*72 + 16*J + c16]);
      dG=MFMA32(wbf,pfB,dG);
      dYl=MFMA32(wbf,zfB,dYl);
      dYl=MFMA32(wkf,vf[J],dYl);
      #pragma unroll
      for (int e=0;e<4;e++) gtmp[(4*g+e)*68 + 16*J + c16]=dG[e];
      i32x2 o2; o2[0]=pk2(dYl[0],dYl[1]); o2[1]=pk2(dYl[2],dYl[3]);
      *(i32x2*)(rec + 10496 + (size_t)J*2560 + 2048 + (size_t)l*8) = o2;
    }
  }

  // ---- Q^T = P^T Bbar tiles -> record Q A-frags; c = Bbar^T zloc + Kbar^T V -> strips ----
  {
    s16x8 bk[4], pfr[4], bzv[4];
    #pragma unroll
    for (int nt=0;nt<4;nt++) bk[nt]=*(const s16x8*)(&BKL[(16*nt+c16)*40 + 8*g]);
    #pragma unroll
    for (int mt=0;mt<4;mt++)
      pfr[mt]= (g<2) ? *(const s16x8*)(&pbb[(16*mt+c16)*24 + 8*g]) : zero8;
    #pragma unroll
    for (int it=0;it<4;it++)
      bzv[it]= (g<2) ? *(const s16x8*)(&zbb[(16*it+c16)*24 + 8*g])
                     : *(const s16x8*)(&vbb[(16*it+c16)*24 + 8*(g-2)]);
    // Q^T[j][j'] = sum_t P[t][j] Bbar[t][j']   (A=P zero-padded K, B=[Bbar;Kbar] upper x0)
    #pragma unroll
    for (int mt=0;mt<4;mt++){
      #pragma unroll
      for (int nt=0;nt<4;nt++){
        f32x4 dQ = MFMA32(pfr[mt], bk[nt], zf4);
        int kk = mt>>1, gq = ((mt&1)<<1) | (g>>1), jo = g&1;
        i32x2 o2; o2[0]=pk2(dQ[0],dQ[1]); o2[1]=pk2(dQ[2],dQ[3]);
        *(i32x2*)(rec + ((size_t)(kk*4+nt)*64 + (size_t)(c16 + 16*gq))*16 + 8*jo) = o2;
      }
    }
    // c[j'][i]: A = [Bbar;Kbar] (K=32), B = [zloc;V]
    #pragma unroll
    for (int jtp=0;jtp<4;jtp++){
      #pragma unroll
      for (int it=0;it<4;it++){
        f32x4 dc = MFMA32(bk[jtp], bzv[it], zf4);
        i32x2 o2; o2[0]=pk2(dc[0],dc[1]); o2[1]=pk2(dc[2],dc[3]);
        *(i32x2*)(rec + 10496 + (size_t)it*2560 + ((size_t)jtp*64 + l)*8) = o2;
      }
    }
  }

  // ---- G A-frags -> record ----
  #pragma unroll
  for (int kk=0;kk<2;kk++){
    f32x4 b0 = *(const f32x4*)(&gtmp[c16*68 + 32*kk + 8*g]);
    f32x4 b1 = *(const f32x4*)(&gtmp[c16*68 + 32*kk + 8*g + 4]);
    i32x4 o;
    o[0]=pk2(b0[0],b0[1]); o[1]=pk2(b0[2],b0[3]); o[2]=pk2(b1[0],b1[1]); o[3]=pk2(b1[2],b1[3]);
    *(i32x4*)(rec + 8192 + (size_t)(kk*64+l)*16) = o;
  }
}

// ---------------- serial scan v6: S' = pL.S + Q.S^T + c ; y = G.S^T + Yloc ----------------
// 1 wave per (bh, i-strip), depth-2 triple-buffer ring, 14 loads/iter, vmcnt(18).
__global__ __launch_bounds__(64) void scan2_kernel(char* ws, const float* S0, float* dout){
  float* YB=(float*)(ws+OFF_YBUF);
  const char* recb = ws + OFF_SEQ;
  int bid=blockIdx.x, bh=bid>>2, w=bid&3;
  int l=threadIdx.x, c16=l&15, g=l>>4;

  __shared__ __align__(16) char buf[3][13824];
  __shared__ __align__(16) u16 ST[16*88];

  // Sreg[jt][e] = S^T[16jt+4g+e][i=16w+c16]
  f32x4 Sreg[4];
  #pragma unroll
  for (int jt=0;jt<4;jt++)
    Sreg[jt] = *(const f32x4*)(S0 + (size_t)bh*4096 + (size_t)(16*w+c16)*64 + 16*jt + 4*g);
  #pragma unroll
  for (int jt=0;jt<4;jt++){
    i32x2 p; p[0]=pk2(Sreg[jt][0],Sreg[jt][1]); p[1]=pk2(Sreg[jt][2],Sreg[jt][3]);
    *(i32x2*)(&ST[c16*88 + 16*jt + 4*g]) = p;
  }

  const char* rb = recb + (size_t)(bh*64)*24576;

  // prologue: stage chunks 0 and 1 (14 loads each)
  #pragma unroll
  for (int pc=0; pc<2; ++pc){
    const float* r = (const float*)(rb + (size_t)pc*24576);
    float* d = (float*)(&buf[pc][0]);
    #pragma unroll
    for (int q=0;q<10;q++) gload_lds16(r + q*256 + l*4, d + q*256);
    gload_lds4((const float*)(rb + (size_t)pc*24576 + 10240) + l, d + 2560);
    const float* rs = (const float*)(rb + (size_t)pc*24576 + 10496 + (size_t)w*2560);
    #pragma unroll
    for (int q=0;q<3;q++) gload_lds16(rs + q*256 + l*4, d + 2624 + q*256);
  }
  asm volatile("s_waitcnt vmcnt(14)" ::: "memory");
  __builtin_amdgcn_sched_barrier(0);

  float* yb0 = YB + (size_t)bh*65536;
  int cur=0;

  #pragma unroll 1
  for (int ch=0; ch<64; ++ch){
    asm volatile("s_waitcnt vmcnt(18)" ::: "memory");
    __builtin_amdgcn_sched_barrier(0);
    const char* bp = &buf[cur][0];

    s16x8 qf[4][2], gf[2], sB[2];
    #pragma unroll
    for (int kk=0;kk<2;kk++){
      #pragma unroll
      for (int jt=0;jt<4;jt++)
        qf[jt][kk]=*(const s16x8*)(bp + (size_t)((kk*4+jt)*64 + l)*16);
      gf[kk]=*(const s16x8*)(bp + 8192 + (size_t)(kk*64+l)*16);
      sB[kk]=*(const s16x8*)(&ST[c16*88 + 32*kk + 8*g]);
    }
    f32x4 pl4[4];
    #pragma unroll
    for (int jt=0;jt<4;jt++)
      pl4[jt]=*(const f32x4*)(bp + 10240 + (size_t)(16*jt+4*g)*4);
    i32x2 cfr[4];
    #pragma unroll
    for (int jt=0;jt<4;jt++)
      cfr[jt]=*(const i32x2*)(bp + 10496 + (size_t)(jt*64+l)*8);
    i32x2 ylv=*(const i32x2*)(bp + 12544 + (size_t)l*8);

    // prefetch chunk ch+2 into slot cur+2 (mod 3) — 14 loads, before any stores
    {
      int p2 = cur+2; if (p2>=3) p2-=3;
      int nc = ch+2; if (nc>63) nc=63;
      const float* r = (const float*)(rb + (size_t)nc*24576);
      float* d = (float*)(&buf[p2][0]);
      #pragma unroll
      for (int q=0;q<10;q++) gload_lds16(r + q*256 + l*4, d + q*256);
      gload_lds4((const float*)(rb + (size_t)nc*24576 + 10240) + l, d + 2560);
      const float* rs = (const float*)(rb + (size_t)nc*24576 + 10496 + (size_t)w*2560);
      #pragma unroll
      for (int q=0;q<3;q++) gload_lds16(rs + q*256 + l*4, d + 2624 + q*256);
    }
    __builtin_amdgcn_sched_barrier(0);

    // y = G.S^T + Yloc
    f32x4 dy=cvt4(ylv);
    dy=MFMA32(gf[0],sB[0],dy); dy=MFMA32(gf[1],sB[1],dy);
    // S' = pL.S (f32) + Q.S^T + c
    #pragma unroll
    for (int jt=0;jt<4;jt++){
      f32x4 acc = cvt4(cfr[jt]);
      acc = MFMA32(qf[jt][0], sB[0], acc);
      acc = MFMA32(qf[jt][1], sB[1], acc);
      #pragma unroll
      for (int e=0;e<4;e++) acc[e] = fmaf(pl4[jt][e], Sreg[jt][e], acc[e]);
      Sreg[jt]=acc;
    }
    #pragma unroll
    for (int jt=0;jt<4;jt++){
      i32x2 p; p[0]=cvtpk(Sreg[jt][0],Sreg[jt][1]); p[1]=cvtpk(Sreg[jt][2],Sreg[jt][3]);
      *(i32x2*)(&ST[c16*88 + 16*jt + 4*g]) = p;
    }
    // y stores (4, younger than all prefetch loads)
    {
      float* yb = yb0 + (size_t)ch*1024;
      #pragma unroll
      for (int e=0;e<4;e++)
        yb[(size_t)(4*g+e)*64 + 16*w + c16] = dy[e];
    }
    cur = (cur+1==3)?0:cur+1;
  }

  // final state
  #pragma unroll
  for (int jt=0;jt<4;jt++)
    *(f32x4*)(dout + 2097152 + (size_t)bh*4096 + (size_t)(16*w+c16)*64 + 16*jt + 4*g) = Sreg[jt];
}

// ---------------- epilogue: groupnorm + bonus + gate -> bf16 ----------------
__global__ __launch_bounds__(256) void epi_kernel(char* ws, const float* lnw, const float* lnb)
{
  const float* YB=(const float*)(ws+OFF_YBUF);
  const u16* VEPI=(const u16*)(ws+OFF_VEPI);
  const float* DPp=(const float*)(ws+OFF_DP);
  const float* GB=(const float*)(ws+OFF_GBUF);
  u16* XGB=(u16*)(ws+OFF_XGB);
  int m=blockIdx.x, b=m>>10, t=m&1023;
  int tid=threadIdx.x, c0=tid*4, h=c0>>6, i0=c0&63;
  f32x4 y=*(const f32x4*)(YB + ((size_t)(b*16+h)*1024+t)*64 + i0);
  float s = y[0]+y[1]+y[2]+y[3];
  float ss= y[0]*y[0]+y[1]*y[1]+y[2]*y[2]+y[3]*y[3];
  #pragma unroll
  for (int mk=1;mk<16;mk<<=1){ s+=__shfl_xor(s,mk); ss+=__shfl_xor(ss,mk); }
  float mu=s*(1.0f/64.0f), var=ss*(1.0f/64.0f)-mu*mu;
  float inv=rsqrtf(var + 6.4e-4f);
  u16x4 v16=*(const u16x4*)(VEPI + ((size_t)(b*16+h)*1024+t)*64 + i0);
  float dp = DPp[(size_t)(b*16+h)*1024 + t];
  f32x4 gg=*(const f32x4*)(GB+(size_t)m*1024+c0);
  u16x4 outv;
  #pragma unroll
  for (int j=0;j<4;j++){
    float xn = (y[j]-mu)*inv*lnw[c0+j] + lnb[c0+j] + dp*bf2f(v16[j]);
    outv[j]=f2bf(xn*gg[j]);
  }
  *(u16x4*)(XGB+(size_t)m*1024+c0)=outv;
}

extern "C" void kernel_launch(void* const* d_in, const int* in_sizes, int n_in,
                              void* d_out, int out_size, void* d_ws, size_t ws_size,
                              hipStream_t stream) {
  const float* x      =(const float*)d_in[0];
  const float* S0     =(const float*)d_in[1];
  const float* vfirst =(const float*)d_in[2];
  const float* w0     =(const float*)d_in[3];
  const float* w1     =(const float*)d_in[4];
  const float* w2     =(const float*)d_in[5];
  const float* a0     =(const float*)d_in[6];
  const float* a1     =(const float*)d_in[7];
  const float* a2     =(const float*)d_in[8];
  const float* v0     =(const float*)d_in[9];
  const float* v1     =(const float*)d_in[10];
  const float* v2     =(const float*)d_in[11];
  const float* g1     =(const float*)d_in[12];
  const float* g2     =(const float*)d_in[13];
  const float* k_k    =(const float*)d_in[14];
  const float* k_a    =(const float*)d_in[15];
  const float* r_k    =(const float*)d_in[16];
  const float* Wq     =(const float*)d_in[17];
  const float* Wk     =(const float*)d_in[18];
  const float* Wv     =(const float*)d_in[19];
  const float* Wo     =(const float*)d_in[20];
  const float* ln_w   =(const float*)d_in[21];
  const float* ln_b   =(const float*)d_in[22];
  char* ws=(char*)d_ws;
  float* dout=(float*)d_out;

  prep_kernel<<<2048,256,0,stream>>>(ws,x,vfirst,w1,w2,a1,a2,v1,v2,g1,g2,Wq,Wk,Wv,Wo,dout);
  gemm_kernel<<<dim3(16,19),256,0,stream>>>(0,ws,w0,a0,v0,dout);
  gemm_kernel<<<dim3(16,32),256,0,stream>>>(1,ws,w0,a0,v0,dout);
  prep2_kernel<<<2048,256,0,stream>>>(ws,vfirst,k_k,k_a);
  pre_kernel<<<2048,64,0,stream>>>(ws,r_k);
  scan2_kernel<<<128,64,0,stream>>>(ws,S0,dout);
  epi_kernel<<<2048,256,0,stream>>>(ws,ln_w,ln_b);
  gemm_kernel<<<dim3(16,8),256,0,stream>>>(2,ws,w0,a0,v0,dout);
}

// Round 10
// 212.182 us; speedup vs baseline: 1.1192x; 1.0633x over previous
//
#include <hip/hip_runtime.h>

typedef unsigned short u16;
typedef __attribute__((ext_vector_type(8))) short s16x8;
typedef __attribute__((ext_vector_type(4))) float f32x4;
typedef __attribute__((ext_vector_type(4))) int   i32x4;
typedef __attribute__((ext_vector_type(2))) int   i32x2;
typedef __attribute__((ext_vector_type(4))) unsigned short u16x4;

// ---------------- workspace layout (bytes) ----------------
constexpr size_t OFF_XB   = 0;                     // bf16 x          [2048][1024]
constexpr size_t OFF_WQB  = OFF_XB   + 4194304;    // bf16 Wq         [1024][1024]
constexpr size_t OFF_WKB  = OFF_WQB  + 2097152;    // bf16 Wk         [512][1024]
constexpr size_t OFF_WVB  = OFF_WKB  + 1048576;    // bf16 Wv         [512][1024]
constexpr size_t OFF_WOB  = OFF_WVB  + 1048576;    // bf16 Wo         [1024][1024]
constexpr size_t OFF_W1T  = OFF_WOB  + 2097152;    // bf16 W1T        [384][1024]
constexpr size_t OFF_W2T  = OFF_W1T  + 786432;     // bf16 w2T        [1024][64]
constexpr size_t OFF_A2T  = OFF_W2T  + 131072;     // bf16 a2T        [1024][64]
constexpr size_t OFF_V2T  = OFF_A2T  + 131072;     // bf16 v2T        [1024][32]
constexpr size_t OFF_G2T  = OFF_V2T  + 65536;      // bf16 g2T        [1024][160]
constexpr size_t OFF_KQF  = OFF_G2T  + 327680;     // f32 k-proj [2048][512]; later VEPI/DP
constexpr size_t OFF_VQF  = OFF_KQF  + 4194304;    // f32 v-proj      [2048][512]
constexpr size_t OFF_URAW = OFF_VQF  + 4194304;    // (dead; kept for layout)
constexpr size_t OFF_UB   = OFF_URAW + 2621440;    // bf16 stage1 act [2048][384]
constexpr size_t OFF_S2A  = OFF_UB   + 1572864;    // f32 iclr        [2048][1024]
constexpr size_t OFF_S2V  = OFF_S2A  + 8388608;    // f32 vmix        [2048][1024]
constexpr size_t OFF_GBUF = OFF_S2V  + 8388608;    // f32 gate        [2048][1024]
constexpr size_t OFF_SEQ  = OFF_GBUF + 8388608;    // f32 SEQ [2048 chunks][24576B]; later records
constexpr size_t OFF_YBUF = OFF_SEQ  + 50331648;   // f32 y   [2][16][1024][64]
constexpr size_t OFF_XGB  = OFF_YBUF + 8388608;    // bf16 xn*g       [2048][1024]

// per-chunk record overlay in SEQ, stride 24576 (block overwrites its OWN chunk):
// 0: Q A-frags [kk2][jt4][lane]x16B (8192) | 8192: G A-frags [kk2][lane]x16B (2048)
// 10240: pL f32[64] (256) | 10496 + w*2560: { c[jt4][lane]x8B (2048) | Yloc[lane]x8B (512) }
constexpr size_t OFF_VEPI = OFF_KQF;               // bf16 v rows [32][1024][64]  (4MB)
constexpr size_t OFF_DP   = OFF_KQF + 4194304;     // f32 dp [32][1024]           (128KB)

__device__ __forceinline__ u16 f2bf(float f){
  unsigned int u = __builtin_bit_cast(unsigned int, f);
  u = u + 0x7fffu + ((u >> 16) & 1u);
  return (u16)(u >> 16);
}
__device__ __forceinline__ int pk2(float a, float b){
  return (int)((unsigned)f2bf(a) | ((unsigned)f2bf(b) << 16));
}
__device__ __forceinline__ int cvtpk(float a, float b){
  int r;
  asm("v_cvt_pk_bf16_f32 %0, %1, %2" : "=v"(r) : "v"(a), "v"(b));
  return r;
}
__device__ __forceinline__ float bf2f(u16 h){
  return __builtin_bit_cast(float, ((unsigned)h) << 16);
}
__device__ __forceinline__ f32x4 cvt4(i32x2 v){
  unsigned a=(unsigned)v[0], b=(unsigned)v[1];
  f32x4 r;
  r[0]=__builtin_bit_cast(float, a<<16);
  r[1]=__builtin_bit_cast(float, a&0xffff0000u);
  r[2]=__builtin_bit_cast(float, b<<16);
  r[3]=__builtin_bit_cast(float, b&0xffff0000u);
  return r;
}

__device__ __forceinline__ void gload_lds16(const float* g, float* l){
  __builtin_amdgcn_global_load_lds((const __attribute__((address_space(1))) void*)g,
                                   (__attribute__((address_space(3))) void*)l, 16, 0, 0);
}
__device__ __forceinline__ void gload_lds16u(const u16* g, u16* l){
  __builtin_amdgcn_global_load_lds((const __attribute__((address_space(1))) void*)g,
                                   (__attribute__((address_space(3))) void*)l, 16, 0, 0);
}
__device__ __forceinline__ void gload_lds4(const float* g, float* l){
  __builtin_amdgcn_global_load_lds((const __attribute__((address_space(1))) void*)g,
                                   (__attribute__((address_space(3))) void*)l, 4, 0, 0);
}

// ---------------- prep: convert/transpose + v_first passthrough ----------------
constexpr size_t N_XB=2097152, N_WQ=1048576, N_WK=524288, N_WV=524288, N_WO=1048576,
  N_W1T=393216, N_W2T=65536, N_A2T=65536, N_V2T=32768, N_G2T=163840, N_VF=2097152;
constexpr size_t PREP_TOT = N_XB+N_WQ+N_WK+N_WV+N_WO+N_W1T+N_W2T+N_A2T+N_V2T+N_G2T+N_VF;

__global__ __launch_bounds__(256) void prep_kernel(char* ws, const float* x, const float* vfirst,
  const float* w1, const float* w2, const float* a1, const float* a2,
  const float* v1, const float* v2, const float* g1, const float* g2,
  const float* Wq, const float* Wk, const float* Wv, const float* Wo, float* dout)
{
  u16* XB=(u16*)(ws+OFF_XB); u16* WQB=(u16*)(ws+OFF_WQB); u16* WKB=(u16*)(ws+OFF_WKB);
  u16* WVB=(u16*)(ws+OFF_WVB); u16* WOB=(u16*)(ws+OFF_WOB); u16* W1T=(u16*)(ws+OFF_W1T);
  u16* W2T=(u16*)(ws+OFF_W2T); u16* A2T=(u16*)(ws+OFF_A2T); u16* V2T=(u16*)(ws+OFF_V2T);
  u16* G2T=(u16*)(ws+OFF_G2T);
  for (size_t idx=(size_t)blockIdx.x*256+threadIdx.x; idx<PREP_TOT; idx+=(size_t)gridDim.x*256){
    size_t r = idx;
    if (r < N_XB){ XB[r]=f2bf(x[r]); continue; } r-=N_XB;
    if (r < N_WQ){ WQB[r]=f2bf(Wq[r]); continue; } r-=N_WQ;
    if (r < N_WK){ WKB[r]=f2bf(Wk[r]); continue; } r-=N_WK;
    if (r < N_WV){ WVB[r]=f2bf(Wv[r]); continue; } r-=N_WV;
    if (r < N_WO){ WOB[r]=f2bf(Wo[r]); continue; } r-=N_WO;
    if (r < N_W1T){
      int n=(int)(r>>10), k=(int)(r&1023); float v=0.f;
      if (n<64) v=w1[(size_t)k*64+n];
      else if (n<128) v=a1[(size_t)k*64+(n-64)];
      else if (n<160) v=v1[(size_t)k*32+(n-128)];
      else if (n<320) v=g1[(size_t)k*160+(n-160)];
      W1T[r]=f2bf(v); continue; } r-=N_W1T;
    if (r < N_W2T){ int c=(int)(r>>6), d=(int)(r&63); W2T[r]=f2bf(w2[(size_t)d*1024+c]); continue; } r-=N_W2T;
    if (r < N_A2T){ int c=(int)(r>>6), d=(int)(r&63); A2T[r]=f2bf(a2[(size_t)d*1024+c]); continue; } r-=N_A2T;
    if (r < N_V2T){ int c=(int)(r>>5), d=(int)(r&31); V2T[r]=f2bf(v2[(size_t)d*1024+c]); continue; } r-=N_V2T;
    if (r < N_G2T){ int c=(int)(r/160), d=(int)(r%160); G2T[r]=f2bf(g2[(size_t)d*1024+c]); continue; } r-=N_G2T;
    dout[2228224 + r] = vfirst[r];   // v_first passthrough (offset 2097152+131072)
  }
}

// ---------------- unified NT bf16 MFMA GEMM: C[m][n] = sum_k A[m][k]*B[n][k] ----------------
// v2: global_load_lds width-16 staging, double-buffered linear [128][32] tiles with
// XOR chunk swizzle (chunk ^= (row>>1)&3) applied on the global SOURCE address and on
// the ds_read address (linear LDS dest required by global_load_lds).
__global__ __launch_bounds__(256) void gemm_kernel(int phase, char* ws,
  const float* w0b, const float* a0b, const float* v0b, float* dout)
{
  const u16* A; const u16* Bw;
  float* outF=nullptr; const float* bias=nullptr;
  float* SEQf=(float*)(ws+OFF_SEQ);
  u16* UBp=(u16*)(ws+OFF_UB);
  int lda=0, ldb=0, K=0, ldc=0, Nlim=1024, col0=0, outMode=0;
  int y = blockIdx.y;
  if (phase==0){
    A=(const u16*)(ws+OFF_XB); lda=1024; K=1024;
    if (y<8)      { Bw=(const u16*)(ws+OFF_WQB); ldb=1024; col0=y*128;       outMode=1; }
    else if (y<12){ Bw=(const u16*)(ws+OFF_WKB); ldb=1024; col0=(y-8)*128;   outF=(float*)(ws+OFF_KQF); ldc=512; Nlim=512; }
    else if (y<16){ Bw=(const u16*)(ws+OFF_WVB); ldb=1024; col0=(y-12)*128;  outF=(float*)(ws+OFF_VQF); ldc=512; Nlim=512; }
    else          { Bw=(const u16*)(ws+OFF_W1T); ldb=1024; col0=(y-16)*128;  outMode=4; Nlim=320; }
  } else if (phase==1){
    int seg=y>>3; col0=(y&7)*128;
    const int Ks[4]={64,64,32,160};
    const int Ao[4]={0,64,128,160};
    K=Ks[seg]; lda=384; ldb=K;
    A=(const u16*)(ws+OFF_UB) + Ao[seg];
    if (seg==0)     { Bw=(const u16*)(ws+OFF_W2T); outMode=2; bias=w0b; }
    else if (seg==1){ Bw=(const u16*)(ws+OFF_A2T); outMode=3; bias=a0b; outF=(float*)(ws+OFF_S2A); ldc=1024; }
    else if (seg==2){ Bw=(const u16*)(ws+OFF_V2T); outMode=3; bias=v0b; outF=(float*)(ws+OFF_S2V); ldc=1024; }
    else            { Bw=(const u16*)(ws+OFF_G2T); outF=(float*)(ws+OFF_GBUF); ldc=1024; }
  } else {
    A=(const u16*)(ws+OFF_XGB); lda=1024; K=1024;
    Bw=(const u16*)(ws+OFF_WOB); ldb=1024; col0=y*128; outF=dout; ldc=1024;
  }
  int m0 = blockIdx.x*128;
  __shared__ __align__(16) u16 As[2][4096];
  __shared__ __align__(16) u16 Bs[2][4096];
  int tid=threadIdx.x, l=tid&63, wv=tid>>6, wm=wv>>1, wn=wv&1;

  // staging geometry: wave wv stages rows [wv*32, wv*32+32); lane l covers row
  // srow=wv*32+(l>>2) (+16 for second half), chunk cidx=l&3; source chunk is
  // XOR-swizzled so the linear LDS dest holds the swizzled layout.
  int srow = wv*32 + (l>>2);
  int cswz = (l&3) ^ ((srow>>1)&3);          // invariant under srow+16
  const u16* aP0 = A  + (size_t)(m0+srow)*lda      + cswz*8;
  const u16* aP1 = A  + (size_t)(m0+srow+16)*lda   + cswz*8;
  const u16* bP0 = Bw + (size_t)(col0+srow)*ldb    + cswz*8;
  const u16* bP1 = Bw + (size_t)(col0+srow+16)*ldb + cswz*8;
  u16* adst0 = &As[0][wv*1024];

  f32x4 acc[4][4];
  #pragma unroll
  for (int i=0;i<4;i++)
    #pragma unroll
    for (int j=0;j<4;j++) acc[i][j]=(f32x4){0.f,0.f,0.f,0.f};

#define GSTAGE(b,k0) do{                                   \
    gload_lds16u(aP0 + (k0), &As[b][wv*1024]);             \
    gload_lds16u(aP1 + (k0), &As[b][wv*1024+512]);         \
    gload_lds16u(bP0 + (k0), &Bs[b][wv*1024]);             \
    gload_lds16u(bP1 + (k0), &Bs[b][wv*1024+512]);         \
  }while(0)

  GSTAGE(0,0);
  asm volatile("s_waitcnt vmcnt(0)" ::: "memory");
  __syncthreads();

  int rrow=l&15, ck=l>>4;
  for (int k0=0;k0<K;k0+=32){
    int cb=(k0>>5)&1;
    if (k0+32<K) GSTAGE(cb^1, k0+32);
    s16x8 af[4], bf[4];
    #pragma unroll
    for (int mt=0;mt<4;mt++){
      int ra = wm*64+mt*16+rrow;
      af[mt]=*(const s16x8*)(&As[cb][ra*32 + ((ck ^ ((ra>>1)&3))<<3)]);
    }
    #pragma unroll
    for (int nt=0;nt<4;nt++){
      int rb = wn*64+nt*16+rrow;
      bf[nt]=*(const s16x8*)(&Bs[cb][rb*32 + ((ck ^ ((rb>>1)&3))<<3)]);
    }
    #pragma unroll
    for (int mt=0;mt<4;mt++)
      #pragma unroll
      for (int nt=0;nt<4;nt++)
        acc[mt][nt]=__builtin_amdgcn_mfma_f32_16x16x32_bf16(af[mt],bf[nt],acc[mt][nt],0,0,0);
    __syncthreads();   // drains vmcnt (prefetch landed) + lgkm; protects dbuf reuse
  }
#undef GSTAGE
  (void)adst0;
  // epilogue
  #pragma unroll
  for (int mt=0;mt<4;mt++){
    #pragma unroll
    for (int nt=0;nt<4;nt++){
      int nglob = col0 + wn*64 + nt*16 + (l&15);
      if (nglob >= Nlim) continue;
      #pragma unroll
      for (int rg=0;rg<4;rg++){
        int mrow = m0 + wm*64 + mt*16 + ((l>>4)<<2) + rg;
        float val = acc[mt][nt][rg];
        if (outMode==0){
          outF[(size_t)mrow*ldc + nglob] = val;
        } else if (outMode==1){          // r -> SEQ slot 0
          int b=mrow>>10, t=mrow&1023, h=nglob>>6, i=nglob&63;
          SEQf[(((size_t)(b*16+h)*1024+t)*384) + i] = val;
        } else if (outMode==2){          // decay -> SEQ slot 1
          float w = bias[nglob] + val;
          float d = expf(-expf(w));
          int b=mrow>>10, t=mrow&1023, h=nglob>>6, i=nglob&63;
          SEQf[(((size_t)(b*16+h)*1024+t)*384) + 64 + i] = d;
        } else if (outMode==3){          // sigmoid(bias+acc)
          float s = 1.0f/(1.0f+__expf(-(bias[nglob]+val)));
          outF[(size_t)mrow*ldc + nglob] = s;
        } else {                          // fused stage-1 activation -> UB bf16
          float a = (nglob<64) ? tanhf(val)
                  : (nglob<160) ? val
                  : 1.0f/(1.0f+__expf(-val));
          UBp[(size_t)mrow*384 + nglob] = f2bf(a);
        }
      }
    }
  }
}

// ---------------- prep2: build SEQ slots k,v,a,b ----------------
__global__ __launch_bounds__(256) void prep2_kernel(char* ws, const float* vfirst,
  const float* kk_s, const float* ka_s)
{
  const float* KQF=(const float*)(ws+OFF_KQF);
  const float* VQF=(const float*)(ws+OFF_VQF);
  const float* ICLR=(const float*)(ws+OFF_S2A);
  const float* VMIX=(const float*)(ws+OFF_S2V);
  float* SEQf=(float*)(ws+OFF_SEQ);
  int m=blockIdx.x, b=m>>10, t=m&1023;
  int tid=threadIdx.x, c0=tid*4, h=c0>>6, i0=c0&63, hk=h>>1;
  f32x4 kq=*(const f32x4*)(KQF+(size_t)m*512+hk*64+i0);
  f32x4 vq=*(const f32x4*)(VQF+(size_t)m*512+hk*64+i0);
  f32x4 ic=*(const f32x4*)(ICLR+(size_t)m*1024+c0);
  f32x4 vm=*(const f32x4*)(VMIX+(size_t)m*1024+c0);
  f32x4 vf=*(const f32x4*)(vfirst+(size_t)m*1024+c0);
  f32x4 kkc=*(const f32x4*)(kk_s+c0);
  f32x4 kac=*(const f32x4*)(ka_s+c0);
  f32x4 kk=kq*kkc;
  float ssq=kk[0]*kk[0]+kk[1]*kk[1]+kk[2]*kk[2]+kk[3]*kk[3];
  #pragma unroll
  for (int mk=1;mk<16;mk<<=1) ssq += __shfl_xor(ssq,mk);
  float scale = 1.0f / fmaxf(sqrtf(ssq), 1e-12f);
  f32x4 kf,vv,av,bv;
  #pragma unroll
  for (int j=0;j<4;j++){
    float icc = 1.0f + (ic[j]-1.0f)*kac[j];
    float kkn = kk[j]*scale;
    kf[j]=kq[j]*icc;
    vv[j]=vq[j] + (vf[j]-vq[j])*vm[j];
    av[j]=-kkn;
    bv[j]=kkn*icc;
  }
  size_t sb = (((size_t)(b*16+h)*1024)+t)*384 + i0;
  *(f32x4*)(SEQf+sb+128)=kf;
  *(f32x4*)(SEQf+sb+192)=vv;
  *(f32x4*)(SEQf+sb+256)=av;
  *(f32x4*)(SEQf+sb+320)=bv;
}

#define MFMA32(a,b,c) __builtin_amdgcn_mfma_f32_16x16x32_bf16(a,b,c,0,0,0)

// ---------------- precompute: per-chunk S-independent record (2048-way parallel) ------
// Produces per-chunk: Q = Bbar^T P (A-frags), G (A-frags), pL, per-strip c = Bbar^T zloc
// + Kbar^T V (D-frags) and Yloc; plus epi inputs dp[t], v rows. Record overlays own SEQ chunk.
__global__ __launch_bounds__(64) void pre_kernel(char* ws, const float* rkw){
  const float* SEQ=(const float*)(ws+OFF_SEQ);
  int bid=blockIdx.x, bh=bid>>6, ch=bid&63;
  int l=threadIdx.x, c16=l&15, g=l>>4;
  const float* seqb = SEQ + (size_t)bh*(1024*384) + (size_t)ch*6144;
  char* rec = ws + OFF_SEQ + (size_t)bid*24576;
  u16* VEPI=(u16*)(ws+OFF_VEPI);
  float* DPp=(float*)(ws+OFF_DP);

  __shared__ __align__(16) float raw[16*396];
  __shared__ __align__(16) float pbuf[16*68];
  __shared__ __align__(16) u16 AT[16*72];
  __shared__ __align__(16) u16 RT[16*72];
  __shared__ __align__(16) u16 BT[16*72];
  __shared__ __align__(16) u16 KT[16*72];
  __shared__ __align__(16) u16 vbb[64*24+16];
  __shared__ __align__(16) u16 zbb[64*24+16];
  __shared__ __align__(16) u16 pbb[64*24+16];
  __shared__ __align__(16) u16 BKL[64*40];         // row=channel j: bs[0..15], ks[0..15]
  __shared__ __align__(16) float WN[16*17];
  __shared__ __align__(16) u16 WY[16*24+16];
  __shared__ __align__(16) u16 WB[16*24+16];
  __shared__ __align__(16) u16 WK[16*24+16];
  __shared__ __align__(16) float rhsb[16*68];
  __shared__ __align__(16) float gtmp[16*68];
  const s16x8 zero8 = {0,0,0,0,0,0,0,0};
  const f32x4 zf4 = {0.f,0.f,0.f,0.f};

  #pragma unroll
  for (int t=0;t<16;t++){
    const float* src = seqb + (size_t)t*384;
    float* dst = &raw[t*396];
    gload_lds16(src + l*4, dst);
    gload_lds4 (src + 256 + l, dst + 256);
    gload_lds4 (src + 320 + l, dst + 320);
  }
  asm volatile("s_waitcnt vmcnt(0)" ::: "memory");
  __builtin_amdgcn_sched_barrier(0);

  // ---- P1a: lane = channel l. cumprod decay; vbb/BKL LDS; pL + VEPI writes ----
  {
    float ptv[16]; float pp=1.f;
    #pragma unroll
    for (int t=0;t<16;t++){ pp *= raw[t*396+64+l]; ptv[t]=pp; pbuf[t*68+l]=pp; }
    float pL = ptv[15];
    *(float*)(rec + 10240 + (size_t)l*4) = pL;
    float bs[16], ks[16], vs[16];
    #pragma unroll
    for (int t=0;t<16;t++){
      float sc = pL * __builtin_amdgcn_rcpf(ptv[t]);
      bs[t]=raw[t*396+320+l]*sc;
      ks[t]=raw[t*396+128+l]*sc;
      vs[t]=raw[t*396+192+l];
    }
    i32x4 o;
    o[0]=pk2(vs[0],vs[1]); o[1]=pk2(vs[2],vs[3]); o[2]=pk2(vs[4],vs[5]); o[3]=pk2(vs[6],vs[7]);
    *(i32x4*)(&vbb[l*24]) = o;
    o[0]=pk2(vs[8],vs[9]); o[1]=pk2(vs[10],vs[11]); o[2]=pk2(vs[12],vs[13]); o[3]=pk2(vs[14],vs[15]);
    *(i32x4*)(&vbb[l*24+8]) = o;
    o[0]=pk2(bs[0],bs[1]); o[1]=pk2(bs[2],bs[3]); o[2]=pk2(bs[4],bs[5]); o[3]=pk2(bs[6],bs[7]);
    *(i32x4*)(&BKL[l*40]) = o;
    o[0]=pk2(bs[8],bs[9]); o[1]=pk2(bs[10],bs[11]); o[2]=pk2(bs[12],bs[13]); o[3]=pk2(bs[14],bs[15]);
    *(i32x4*)(&BKL[l*40+8]) = o;
    o[0]=pk2(ks[0],ks[1]); o[1]=pk2(ks[2],ks[3]); o[2]=pk2(ks[4],ks[5]); o[3]=pk2(ks[6],ks[7]);
    *(i32x4*)(&BKL[l*40+16]) = o;
    o[0]=pk2(ks[8],ks[9]); o[1]=pk2(ks[10],ks[11]); o[2]=pk2(ks[12],ks[13]); o[3]=pk2(ks[14],ks[15]);
    *(i32x4*)(&BKL[l*40+24]) = o;
    size_t vb = ((size_t)bh*1024 + (size_t)ch*16)*64 + l;
    #pragma unroll
    for (int t=0;t<16;t++) VEPI[vb + (size_t)t*64] = f2bf(vs[t]);
  }

  // ---- P1b: lane (t=c16, group g): write AT,RT,BT,KT; dp for bonus ----
  {
    int tt=c16, gg=g;
    f32x4 pa[4], pp[4];
    int tp = (tt==0)?0:(tt-1);
    #pragma unroll
    for (int q=0;q<4;q++){
      pa[q] = *(const f32x4*)(&pbuf[tt*68 + 16*gg + 4*q]);
      pp[q] = *(const f32x4*)(&pbuf[tp*68 + 16*gg + 4*q]);
    }
    if (tt==0){
      #pragma unroll
      for (int q=0;q<4;q++) pp[q] = (f32x4){1.f,1.f,1.f,1.f};
    }
    f32x4 ra[4], rr[4], rb[4], kq2[4];
    #pragma unroll
    for (int q=0;q<4;q++){
      ra[q]=*(const f32x4*)(&raw[tt*396+256+16*gg+4*q]);
      rr[q]=*(const f32x4*)(&raw[tt*396+    16*gg+4*q]);
      rb[q]=*(const f32x4*)(&raw[tt*396+320+16*gg+4*q]);
      kq2[q]=*(const f32x4*)(&raw[tt*396+128+16*gg+4*q]);
    }
    // bonus dp[t] = sum_c r*k*r_k
    {
      float dp=0.f;
      #pragma unroll
      for (int q=0;q<4;q++){
        f32x4 rkv = *(const f32x4*)(rkw + (bh&15)*64 + 16*gg + 4*q);
        #pragma unroll
        for (int e=0;e<4;e++) dp += rr[q][e]*kq2[q][e]*rkv[e];
      }
      dp += __shfl_xor(dp,16); dp += __shfl_xor(dp,32);
      if (gg==0) DPp[(size_t)bh*1024 + ch*16 + tt] = dp;
    }
    float va[16], vr[16], vb2[16], vk2[16];
    #pragma unroll
    for (int q=0;q<4;q++)
      #pragma unroll
      for (int e=0;e<4;e++){
        float rp = __builtin_amdgcn_rcpf(pa[q][e]);
        va[q*4+e] = pp[q][e]*ra[q][e];
        vr[q*4+e] = pa[q][e]*rr[q][e];
        vb2[q*4+e] = rb[q][e]*rp;
        vk2[q*4+e] = kq2[q][e]*rp;
      }
    i32x4 o;
    o[0]=pk2(va[0],va[1]); o[1]=pk2(va[2],va[3]); o[2]=pk2(va[4],va[5]); o[3]=pk2(va[6],va[7]);
    *(i32x4*)(&AT[tt*72+16*gg]) = o;
    o[0]=pk2(va[8],va[9]); o[1]=pk2(va[10],va[11]); o[2]=pk2(va[12],va[13]); o[3]=pk2(va[14],va[15]);
    *(i32x4*)(&AT[tt*72+16*gg+8]) = o;
    o[0]=pk2(vr[0],vr[1]); o[1]=pk2(vr[2],vr[3]); o[2]=pk2(vr[4],vr[5]); o[3]=pk2(vr[6],vr[7]);
    *(i32x4*)(&RT[tt*72+16*gg]) = o;
    o[0]=pk2(vr[8],vr[9]); o[1]=pk2(vr[10],vr[11]); o[2]=pk2(vr[12],vr[13]); o[3]=pk2(vr[14],vr[15]);
    *(i32x4*)(&RT[tt*72+16*gg+8]) = o;
    o[0]=pk2(vb2[0],vb2[1]); o[1]=pk2(vb2[2],vb2[3]); o[2]=pk2(vb2[4],vb2[5]); o[3]=pk2(vb2[6],vb2[7]);
    *(i32x4*)(&BT[tt*72+16*gg]) = o;
    o[0]=pk2(vb2[8],vb2[9]); o[1]=pk2(vb2[10],vb2[11]); o[2]=pk2(vb2[12],vb2[13]); o[3]=pk2(vb2[14],vb2[15]);
    *(i32x4*)(&BT[tt*72+16*gg+8]) = o;
    o[0]=pk2(vk2[0],vk2[1]); o[1]=pk2(vk2[2],vk2[3]); o[2]=pk2(vk2[4],vk2[5]); o[3]=pk2(vk2[6],vk2[7]);
    *(i32x4*)(&KT[tt*72+16*gg]) = o;
    o[0]=pk2(vk2[8],vk2[9]); o[1]=pk2(vk2[10],vk2[11]); o[2]=pk2(vk2[12],vk2[13]); o[3]=pk2(vk2[14],vk2[15]);
    *(i32x4*)(&KT[tt*72+16*gg+8]) = o;
  }

  // ---- W-block: N, Yhat, Tb, Tk ----
  {
    s16x8 afA[2], afR[2], bfB[2], bfK[2];
    #pragma unroll
    for (int Kt=0;Kt<2;Kt++){
      afA[Kt]=*(const s16x8*)(&AT[c16*72 + 32*Kt + 8*g]);
      afR[Kt]=*(const s16x8*)(&RT[c16*72 + 32*Kt + 8*g]);
      bfB[Kt]=*(const s16x8*)(&BT[c16*72 + 32*Kt + 8*g]);
      bfK[Kt]=*(const s16x8*)(&KT[c16*72 + 32*Kt + 8*g]);
    }
    f32x4 dNN=zf4, dNY=zf4, dBB=zf4, dBK=zf4;
    #pragma unroll
    for (int Kt=0;Kt<2;Kt++){
      dNN=MFMA32(afA[Kt],bfB[Kt],dNN);
      dNY=MFMA32(afA[Kt],bfK[Kt],dNY);
      dBB=MFMA32(afR[Kt],bfB[Kt],dBB);
      dBK=MFMA32(afR[Kt],bfK[Kt],dBK);
    }
    #pragma unroll
    for (int e=0;e<4;e++){
      int tR=4*g+e, sC=c16;
      WN[tR*17+sC] = dNN[e];
      WY[tR*24+sC] = (sC<tR)? f2bf(dNY[e]) : (u16)0;
      WB[tR*24+sC] = (sC<=tR)? f2bf(dBB[e]) : (u16)0;
      WK[tR*24+sC] = (sC<=tR)? f2bf(dBK[e]) : (u16)0;
    }
  }

  // ---- YhatV -> rhsb ----
  s16x8 vf[4];
  #pragma unroll
  for (int J=0;J<4;J++){
    vf[J]=zero8;
    if (g<2) vf[J]=*(const s16x8*)(&vbb[(16*J+c16)*24 + 8*g]);
  }
  {
    s16x8 wyf=zero8;
    if (g<2) wyf=*(const s16x8*)(&WY[c16*24 + 8*g]);
    f32x4 dR[4];
    #pragma unroll
    for (int J=0;J<4;J++){
      dR[J]=zf4;
      dR[J]=MFMA32(wyf,vf[J],dR[J]);
      #pragma unroll
      for (int e=0;e<4;e++)
        rhsb[(4*g+e)*68 + 16*J + c16] = dR[J][e];
    }
  }

  // ---- P-solve: (I-N)P = Atil, lane = column j=l ----
  {
    float pv[16];
    #pragma unroll
    for (int t=0;t<16;t++) pv[t]=bf2f(AT[t*72+l]);
    #pragma unroll
    for (int t=1;t<16;t++)
      #pragma unroll
      for (int s=0;s<16;s++){
        if (s<t) pv[t] += WN[t*17+s]*pv[s];
      }
    i32x4 o;
    o[0]=pk2(pv[0],pv[1]); o[1]=pk2(pv[2],pv[3]); o[2]=pk2(pv[4],pv[5]); o[3]=pk2(pv[6],pv[7]);
    *(i32x4*)(&pbb[l*24]) = o;
    o[0]=pk2(pv[8],pv[9]); o[1]=pk2(pv[10],pv[11]); o[2]=pk2(pv[12],pv[13]); o[3]=pk2(pv[14],pv[15]);
    *(i32x4*)(&pbb[l*24+8]) = o;
  }

  // ---- z-solve: (I-N)zloc = YhatV, lane = column i=l ----
  {
    float zz[16];
    #pragma unroll
    for (int t=0;t<16;t++) zz[t]=rhsb[t*68+l];
    #pragma unroll
    for (int t=1;t<16;t++)
      #pragma unroll
      for (int s=0;s<16;s++){
        if (s<t) zz[t] += WN[t*17+s]*zz[s];
      }
    i32x4 o;
    o[0]=pk2(zz[0],zz[1]); o[1]=pk2(zz[2],zz[3]); o[2]=pk2(zz[4],zz[5]); o[3]=pk2(zz[6],zz[7]);
    *(i32x4*)(&zbb[l*24]) = o;
    o[0]=pk2(zz[8],zz[9]); o[1]=pk2(zz[10],zz[11]); o[2]=pk2(zz[12],zz[13]); o[3]=pk2(zz[14],zz[15]);
    *(i32x4*)(&zbb[l*24+8]) = o;
  }

  // ---- G = Rtil + Tb*P -> gtmp ; Yloc = Tb*zloc + Tk*V -> record strips ----
  {
    s16x8 wbf=zero8, wkf=zero8;
    if (g<2){
      wbf=*(const s16x8*)(&WB[c16*24 + 8*g]);
      wkf=*(const s16x8*)(&WK[c16*24 + 8*g]);
    }
    #pragma unroll
    for (int J=0;J<4;J++){
      s16x8 pfB=zero8, zfB=zero8;
      if (g<2){
        pfB=*(const s16x8*)(&pbb[(16*J+c16)*24 + 8*g]);
        zfB=*(const s16x8*)(&zbb[(16*J+c16)*24 + 8*g]);
      }
      f32x4 dG, dYl=zf4;
      #pragma unroll
      for (int e=0;e<4;e++) dG[e]=bf2f(RT[(4*g+e)*72 + 16*J + c16]);
      dG=MFMA32(wbf,pfB,dG);
      dYl=MFMA32(wbf,zfB,dYl);
      dYl=MFMA32(wkf,vf[J],dYl);
      #pragma unroll
      for (int e=0;e<4;e++) gtmp[(4*g+e)*68 + 16*J + c16]=dG[e];
      i32x2 o2; o2[0]=pk2(dYl[0],dYl[1]); o2[1]=pk2(dYl[2],dYl[3]);
      *(i32x2*)(rec + 10496 + (size_t)J*2560 + 2048 + (size_t)l*8) = o2;
    }
  }

  // ---- Q^T = P^T Bbar tiles -> record Q A-frags; c = Bbar^T zloc + Kbar^T V -> strips ----
  {
    s16x8 bk[4], pfr[4], bzv[4];
    #pragma unroll
    for (int nt=0;nt<4;nt++) bk[nt]=*(const s16x8*)(&BKL[(16*nt+c16)*40 + 8*g]);
    #pragma unroll
    for (int mt=0;mt<4;mt++)
      pfr[mt]= (g<2) ? *(const s16x8*)(&pbb[(16*mt+c16)*24 + 8*g]) : zero8;
    #pragma unroll
    for (int it=0;it<4;it++)
      bzv[it]= (g<2) ? *(const s16x8*)(&zbb[(16*it+c16)*24 + 8*g])
                     : *(const s16x8*)(&vbb[(16*it+c16)*24 + 8*(g-2)]);
    // Q^T[j][j'] = sum_t P[t][j] Bbar[t][j']   (A=P zero-padded K, B=[Bbar;Kbar] upper x0)
    #pragma unroll
    for (int mt=0;mt<4;mt++){
      #pragma unroll
      for (int nt=0;nt<4;nt++){
        f32x4 dQ = MFMA32(pfr[mt], bk[nt], zf4);
        int kk = mt>>1, gq = ((mt&1)<<1) | (g>>1), jo = g&1;
        i32x2 o2; o2[0]=pk2(dQ[0],dQ[1]); o2[1]=pk2(dQ[2],dQ[3]);
        *(i32x2*)(rec + ((size_t)(kk*4+nt)*64 + (size_t)(c16 + 16*gq))*16 + 8*jo) = o2;
      }
    }
    // c[j'][i]: A = [Bbar;Kbar] (K=32), B = [zloc;V]
    #pragma unroll
    for (int jtp=0;jtp<4;jtp++){
      #pragma unroll
      for (int it=0;it<4;it++){
        f32x4 dc = MFMA32(bk[jtp], bzv[it], zf4);
        i32x2 o2; o2[0]=pk2(dc[0],dc[1]); o2[1]=pk2(dc[2],dc[3]);
        *(i32x2*)(rec + 10496 + (size_t)it*2560 + ((size_t)jtp*64 + l)*8) = o2;
      }
    }
  }

  // ---- G A-frags -> record ----
  #pragma unroll
  for (int kk=0;kk<2;kk++){
    f32x4 b0 = *(const f32x4*)(&gtmp[c16*68 + 32*kk + 8*g]);
    f32x4 b1 = *(const f32x4*)(&gtmp[c16*68 + 32*kk + 8*g + 4]);
    i32x4 o;
    o[0]=pk2(b0[0],b0[1]); o[1]=pk2(b0[2],b0[3]); o[2]=pk2(b1[0],b1[1]); o[3]=pk2(b1[2],b1[3]);
    *(i32x4*)(rec + 8192 + (size_t)(kk*64+l)*16) = o;
  }
}

// ---------------- serial scan v6: S' = pL.S + Q.S^T + c ; y = G.S^T + Yloc ----------------
// 1 wave per (bh, i-strip), depth-2 triple-buffer ring, 14 loads/iter, vmcnt(18).
__global__ __launch_bounds__(64) void scan2_kernel(char* ws, const float* S0, float* dout){
  float* YB=(float*)(ws+OFF_YBUF);
  const char* recb = ws + OFF_SEQ;
  int bid=blockIdx.x, bh=bid>>2, w=bid&3;
  int l=threadIdx.x, c16=l&15, g=l>>4;

  __shared__ __align__(16) char buf[3][13824];
  __shared__ __align__(16) u16 ST[16*88];

  // Sreg[jt][e] = S^T[16jt+4g+e][i=16w+c16]
  f32x4 Sreg[4];
  #pragma unroll
  for (int jt=0;jt<4;jt++)
    Sreg[jt] = *(const f32x4*)(S0 + (size_t)bh*4096 + (size_t)(16*w+c16)*64 + 16*jt + 4*g);
  #pragma unroll
  for (int jt=0;jt<4;jt++){
    i32x2 p; p[0]=pk2(Sreg[jt][0],Sreg[jt][1]); p[1]=pk2(Sreg[jt][2],Sreg[jt][3]);
    *(i32x2*)(&ST[c16*88 + 16*jt + 4*g]) = p;
  }

  const char* rb = recb + (size_t)(bh*64)*24576;

  // prologue: stage chunks 0 and 1 (14 loads each)
  #pragma unroll
  for (int pc=0; pc<2; ++pc){
    const float* r = (const float*)(rb + (size_t)pc*24576);
    float* d = (float*)(&buf[pc][0]);
    #pragma unroll
    for (int q=0;q<10;q++) gload_lds16(r + q*256 + l*4, d + q*256);
    gload_lds4((const float*)(rb + (size_t)pc*24576 + 10240) + l, d + 2560);
    const float* rs = (const float*)(rb + (size_t)pc*24576 + 10496 + (size_t)w*2560);
    #pragma unroll
    for (int q=0;q<3;q++) gload_lds16(rs + q*256 + l*4, d + 2624 + q*256);
  }
  asm volatile("s_waitcnt vmcnt(14)" ::: "memory");
  __builtin_amdgcn_sched_barrier(0);

  float* yb0 = YB + (size_t)bh*65536;
  int cur=0;

  #pragma unroll 1
  for (int ch=0; ch<64; ++ch){
    asm volatile("s_waitcnt vmcnt(18)" ::: "memory");
    __builtin_amdgcn_sched_barrier(0);
    const char* bp = &buf[cur][0];

    s16x8 qf[4][2], gf[2], sB[2];
    #pragma unroll
    for (int kk=0;kk<2;kk++){
      #pragma unroll
      for (int jt=0;jt<4;jt++)
        qf[jt][kk]=*(const s16x8*)(bp + (size_t)((kk*4+jt)*64 + l)*16);
      gf[kk]=*(const s16x8*)(bp + 8192 + (size_t)(kk*64+l)*16);
      sB[kk]=*(const s16x8*)(&ST[c16*88 + 32*kk + 8*g]);
    }
    f32x4 pl4[4];
    #pragma unroll
    for (int jt=0;jt<4;jt++)
      pl4[jt]=*(const f32x4*)(bp + 10240 + (size_t)(16*jt+4*g)*4);
    i32x2 cfr[4];
    #pragma unroll
    for (int jt=0;jt<4;jt++)
      cfr[jt]=*(const i32x2*)(bp + 10496 + (size_t)(jt*64+l)*8);
    i32x2 ylv=*(const i32x2*)(bp + 12544 + (size_t)l*8);

    // prefetch chunk ch+2 into slot cur+2 (mod 3) — 14 loads, before any stores
    {
      int p2 = cur+2; if (p2>=3) p2-=3;
      int nc = ch+2; if (nc>63) nc=63;
      const float* r = (const float*)(rb + (size_t)nc*24576);
      float* d = (float*)(&buf[p2][0]);
      #pragma unroll
      for (int q=0;q<10;q++) gload_lds16(r + q*256 + l*4, d + q*256);
      gload_lds4((const float*)(rb + (size_t)nc*24576 + 10240) + l, d + 2560);
      const float* rs = (const float*)(rb + (size_t)nc*24576 + 10496 + (size_t)w*2560);
      #pragma unroll
      for (int q=0;q<3;q++) gload_lds16(rs + q*256 + l*4, d + 2624 + q*256);
    }
    __builtin_amdgcn_sched_barrier(0);

    // y = G.S^T + Yloc
    f32x4 dy=cvt4(ylv);
    dy=MFMA32(gf[0],sB[0],dy); dy=MFMA32(gf[1],sB[1],dy);
    // S' = pL.S (f32) + Q.S^T + c
    #pragma unroll
    for (int jt=0;jt<4;jt++){
      f32x4 acc = cvt4(cfr[jt]);
      acc = MFMA32(qf[jt][0], sB[0], acc);
      acc = MFMA32(qf[jt][1], sB[1], acc);
      #pragma unroll
      for (int e=0;e<4;e++) acc[e] = fmaf(pl4[jt][e], Sreg[jt][e], acc[e]);
      Sreg[jt]=acc;
    }
    #pragma unroll
    for (int jt=0;jt<4;jt++){
      i32x2 p; p[0]=cvtpk(Sreg[jt][0],Sreg[jt][1]); p[1]=cvtpk(Sreg[jt][2],Sreg[jt][3]);
      *(i32x2*)(&ST[c16*88 + 16*jt + 4*g]) = p;
    }
    // y stores (4, younger than all prefetch loads)
    {
      float* yb = yb0 + (size_t)ch*1024;
      #pragma unroll
      for (int e=0;e<4;e++)
        yb[(size_t)(4*g+e)*64 + 16*w + c16] = dy[e];
    }
    cur = (cur+1==3)?0:cur+1;
  }

  // final state
  #pragma unroll
  for (int jt=0;jt<4;jt++)
    *(f32x4*)(dout + 2097152 + (size_t)bh*4096 + (size_t)(16*w+c16)*64 + 16*jt + 4*g) = Sreg[jt];
}

// ---------------- epilogue: groupnorm + bonus + gate -> bf16 ----------------
__global__ __launch_bounds__(256) void epi_kernel(char* ws, const float* lnw, const float* lnb)
{
  const float* YB=(const float*)(ws+OFF_YBUF);
  const u16* VEPI=(const u16*)(ws+OFF_VEPI);
  const float* DPp=(const float*)(ws+OFF_DP);
  const float* GB=(const float*)(ws+OFF_GBUF);
  u16* XGB=(u16*)(ws+OFF_XGB);
  int m=blockIdx.x, b=m>>10, t=m&1023;
  int tid=threadIdx.x, c0=tid*4, h=c0>>6, i0=c0&63;
  f32x4 y=*(const f32x4*)(YB + ((size_t)(b*16+h)*1024+t)*64 + i0);
  float s = y[0]+y[1]+y[2]+y[3];
  float ss= y[0]*y[0]+y[1]*y[1]+y[2]*y[2]+y[3]*y[3];
  #pragma unroll
  for (int mk=1;mk<16;mk<<=1){ s+=__shfl_xor(s,mk); ss+=__shfl_xor(ss,mk); }
  float mu=s*(1.0f/64.0f), var=ss*(1.0f/64.0f)-mu*mu;
  float inv=rsqrtf(var + 6.4e-4f);
  u16x4 v16=*(const u16x4*)(VEPI + ((size_t)(b*16+h)*1024+t)*64 + i0);
  float dp = DPp[(size_t)(b*16+h)*1024 + t];
  f32x4 gg=*(const f32x4*)(GB+(size_t)m*1024+c0);
  u16x4 outv;
  #pragma unroll
  for (int j=0;j<4;j++){
    float xn = (y[j]-mu)*inv*lnw[c0+j] + lnb[c0+j] + dp*bf2f(v16[j]);
    outv[j]=f2bf(xn*gg[j]);
  }
  *(u16x4*)(XGB+(size_t)m*1024+c0)=outv;
}

extern "C" void kernel_launch(void* const* d_in, const int* in_sizes, int n_in,
                              void* d_out, int out_size, void* d_ws, size_t ws_size,
                              hipStream_t stream) {
  const float* x      =(const float*)d_in[0];
  const float* S0     =(const float*)d_in[1];
  const float* vfirst =(const float*)d_in[2];
  const float* w0     =(const float*)d_in[3];
  const float* w1     =(const float*)d_in[4];
  const float* w2     =(const float*)d_in[5];
  const float* a0     =(const float*)d_in[6];
  const float* a1     =(const float*)d_in[7];
  const float* a2     =(const float*)d_in[8];
  const float* v0     =(const float*)d_in[9];
  const float* v1     =(const float*)d_in[10];
  const float* v2     =(const float*)d_in[11];
  const float* g1     =(const float*)d_in[12];
  const float* g2     =(const float*)d_in[13];
  const float* k_k    =(const float*)d_in[14];
  const float* k_a    =(const float*)d_in[15];
  const float* r_k    =(const float*)d_in[16];
  const float* Wq     =(const float*)d_in[17];
  const float* Wk     =(const float*)d_in[18];
  const float* Wv     =(const float*)d_in[19];
  const float* Wo     =(const float*)d_in[20];
  const float* ln_w   =(const float*)d_in[21];
  const float* ln_b   =(const float*)d_in[22];
  char* ws=(char*)d_ws;
  float* dout=(float*)d_out;

  prep_kernel<<<2048,256,0,stream>>>(ws,x,vfirst,w1,w2,a1,a2,v1,v2,g1,g2,Wq,Wk,Wv,Wo,dout);
  gemm_kernel<<<dim3(16,19),256,0,stream>>>(0,ws,w0,a0,v0,dout);
  gemm_kernel<<<dim3(16,32),256,0,stream>>>(1,ws,w0,a0,v0,dout);
  prep2_kernel<<<2048,256,0,stream>>>(ws,vfirst,k_k,k_a);
  pre_kernel<<<2048,64,0,stream>>>(ws,r_k);
  scan2_kernel<<<128,64,0,stream>>>(ws,S0,dout);
  epi_kernel<<<2048,256,0,stream>>>(ws,ln_w,ln_b);
  gemm_kernel<<<dim3(16,8),256,0,stream>>>(2,ws,w0,a0,v0,dout);
}

// Round 11
// 195.864 us; speedup vs baseline: 1.2124x; 1.0833x over previous
//
#include <hip/hip_runtime.h>

typedef unsigned short u16;
typedef __attribute__((ext_vector_type(8))) short s16x8;
typedef __attribute__((ext_vector_type(4))) float f32x4;
typedef __attribute__((ext_vector_type(4))) int   i32x4;
typedef __attribute__((ext_vector_type(2))) int   i32x2;
typedef __attribute__((ext_vector_type(4))) unsigned short u16x4;

// ---------------- workspace layout (bytes) ----------------
constexpr size_t OFF_XB   = 0;                     // bf16 x [2048][1024]; later VEPI
constexpr size_t OFF_WQB  = OFF_XB   + 4194304;    // bf16 Wq         [1024][1024]
constexpr size_t OFF_WKB  = OFF_WQB  + 2097152;    // bf16 Wk         [512][1024]
constexpr size_t OFF_WVB  = OFF_WKB  + 1048576;    // bf16 Wv         [512][1024]
constexpr size_t OFF_WOB  = OFF_WVB  + 1048576;    // bf16 Wo         [1024][1024]
constexpr size_t OFF_W1T  = OFF_WOB  + 2097152;    // bf16 W1T [384][1024]; later DP
constexpr size_t OFF_W2T  = OFF_W1T  + 786432;     // bf16 w2T        [1024][64]
constexpr size_t OFF_A2T  = OFF_W2T  + 131072;     // bf16 a2T        [1024][64]
constexpr size_t OFF_V2T  = OFF_A2T  + 131072;     // bf16 v2T        [1024][32]
constexpr size_t OFF_G2T  = OFF_V2T  + 65536;      // bf16 g2T        [1024][160]
constexpr size_t OFF_KQF  = OFF_G2T  + 327680;     // f32 k-proj      [2048][512]
constexpr size_t OFF_VQF  = OFF_KQF  + 4194304;    // f32 v-proj      [2048][512]
constexpr size_t OFF_URAW = OFF_VQF  + 4194304;    // (dead)
constexpr size_t OFF_UB   = OFF_URAW + 2621440;    // bf16 stage1 act [2048][384]
constexpr size_t OFF_S2A  = OFF_UB   + 1572864;    // f32 iclr        [2048][1024]
constexpr size_t OFF_S2V  = OFF_S2A  + 8388608;    // f32 vmix        [2048][1024]
constexpr size_t OFF_GBUF = OFF_S2V  + 8388608;    // f32 gate        [2048][1024]
constexpr size_t OFF_SEQ  = OFF_GBUF + 8388608;    // chunks [2048][24576B]; later records
constexpr size_t OFF_YBUF = OFF_SEQ  + 50331648;   // f32 y   [2][16][1024][64]
constexpr size_t OFF_XGB  = OFF_YBUF + 8388608;    // bf16 xn*g       [2048][1024]

// SEQ chunk payload (first 14336B of each 24576B slot), per t-row stride 896:
//  +0 r bf16[64] | +128 k | +256 v | +384 a | +512 b | +640 decay f32[64]
// record overlay (pre overwrites its OWN chunk): 0 Q(8192) | 8192 G(2048) |
//  10240 pL f32[64] | 10496 + w*2560 { c[jt4][lane]x8B (2048) | Yloc (512) }
constexpr size_t OFF_VEPI = OFF_XB;                // bf16 v rows (XB dead after gemm0)
constexpr size_t OFF_DP   = OFF_W1T;               // f32 dp (W1T dead after gemm0)

__device__ __forceinline__ u16 f2bf(float f){
  unsigned int u = __builtin_bit_cast(unsigned int, f);
  u = u + 0x7fffu + ((u >> 16) & 1u);
  return (u16)(u >> 16);
}
__device__ __forceinline__ int pk2(float a, float b){
  return (int)((unsigned)f2bf(a) | ((unsigned)f2bf(b) << 16));
}
__device__ __forceinline__ int cvtpk(float a, float b){
  int r;
  asm("v_cvt_pk_bf16_f32 %0, %1, %2" : "=v"(r) : "v"(a), "v"(b));
  return r;
}
__device__ __forceinline__ float bf2f(u16 h){
  return __builtin_bit_cast(float, ((unsigned)h) << 16);
}
__device__ __forceinline__ f32x4 cvt4(i32x2 v){
  unsigned a=(unsigned)v[0], b=(unsigned)v[1];
  f32x4 r;
  r[0]=__builtin_bit_cast(float, a<<16);
  r[1]=__builtin_bit_cast(float, a&0xffff0000u);
  r[2]=__builtin_bit_cast(float, b<<16);
  r[3]=__builtin_bit_cast(float, b&0xffff0000u);
  return r;
}

__device__ __forceinline__ void gload_lds16(const float* g, float* l){
  __builtin_amdgcn_global_load_lds((const __attribute__((address_space(1))) void*)g,
                                   (__attribute__((address_space(3))) void*)l, 16, 0, 0);
}
__device__ __forceinline__ void gload_lds16u(const u16* g, u16* l){
  __builtin_amdgcn_global_load_lds((const __attribute__((address_space(1))) void*)g,
                                   (__attribute__((address_space(3))) void*)l, 16, 0, 0);
}
__device__ __forceinline__ void gload_lds4(const float* g, float* l){
  __builtin_amdgcn_global_load_lds((const __attribute__((address_space(1))) void*)g,
                                   (__attribute__((address_space(3))) void*)l, 4, 0, 0);
}

// ---------------- prep: convert/transpose + v_first passthrough ----------------
constexpr size_t N_XB=2097152, N_WQ=1048576, N_WK=524288, N_WV=524288, N_WO=1048576,
  N_W1T=393216, N_W2T=65536, N_A2T=65536, N_V2T=32768, N_G2T=163840, N_VF=2097152;
constexpr size_t PREP_TOT = N_XB+N_WQ+N_WK+N_WV+N_WO+N_W1T+N_W2T+N_A2T+N_V2T+N_G2T+N_VF;

__global__ __launch_bounds__(256) void prep_kernel(char* ws, const float* x, const float* vfirst,
  const float* w1, const float* w2, const float* a1, const float* a2,
  const float* v1, const float* v2, const float* g1, const float* g2,
  const float* Wq, const float* Wk, const float* Wv, const float* Wo, float* dout)
{
  u16* XB=(u16*)(ws+OFF_XB); u16* WQB=(u16*)(ws+OFF_WQB); u16* WKB=(u16*)(ws+OFF_WKB);
  u16* WVB=(u16*)(ws+OFF_WVB); u16* WOB=(u16*)(ws+OFF_WOB); u16* W1T=(u16*)(ws+OFF_W1T);
  u16* W2T=(u16*)(ws+OFF_W2T); u16* A2T=(u16*)(ws+OFF_A2T); u16* V2T=(u16*)(ws+OFF_V2T);
  u16* G2T=(u16*)(ws+OFF_G2T);
  for (size_t idx=(size_t)blockIdx.x*256+threadIdx.x; idx<PREP_TOT; idx+=(size_t)gridDim.x*256){
    size_t r = idx;
    if (r < N_XB){ XB[r]=f2bf(x[r]); continue; } r-=N_XB;
    if (r < N_WQ){ WQB[r]=f2bf(Wq[r]); continue; } r-=N_WQ;
    if (r < N_WK){ WKB[r]=f2bf(Wk[r]); continue; } r-=N_WK;
    if (r < N_WV){ WVB[r]=f2bf(Wv[r]); continue; } r-=N_WV;
    if (r < N_WO){ WOB[r]=f2bf(Wo[r]); continue; } r-=N_WO;
    if (r < N_W1T){
      int n=(int)(r>>10), k=(int)(r&1023); float v=0.f;
      if (n<64) v=w1[(size_t)k*64+n];
      else if (n<128) v=a1[(size_t)k*64+(n-64)];
      else if (n<160) v=v1[(size_t)k*32+(n-128)];
      else if (n<320) v=g1[(size_t)k*160+(n-160)];
      W1T[r]=f2bf(v); continue; } r-=N_W1T;
    if (r < N_W2T){ int c=(int)(r>>6), d=(int)(r&63); W2T[r]=f2bf(w2[(size_t)d*1024+c]); continue; } r-=N_W2T;
    if (r < N_A2T){ int c=(int)(r>>6), d=(int)(r&63); A2T[r]=f2bf(a2[(size_t)d*1024+c]); continue; } r-=N_A2T;
    if (r < N_V2T){ int c=(int)(r>>5), d=(int)(r&31); V2T[r]=f2bf(v2[(size_t)d*1024+c]); continue; } r-=N_V2T;
    if (r < N_G2T){ int c=(int)(r/160), d=(int)(r%160); G2T[r]=f2bf(g2[(size_t)d*1024+c]); continue; } r-=N_G2T;
    dout[2228224 + r] = vfirst[r];   // v_first passthrough (offset 2097152+131072)
  }
}

// ---------------- unified NT bf16 MFMA GEMM: C[m][n] = sum_k A[m][k]*B[n][k] ----------------
__global__ __launch_bounds__(256) void gemm_kernel(int phase, char* ws,
  const float* w0b, const float* a0b, const float* v0b, float* dout)
{
  const u16* A; const u16* Bw;
  float* outF=nullptr; const float* bias=nullptr;
  char* SEQc=(char*)(ws+OFF_SEQ);
  u16* UBp=(u16*)(ws+OFF_UB);
  int lda=0, ldb=0, K=0, ldc=0, Nlim=1024, col0=0, outMode=0;
  int y = blockIdx.y;
  if (phase==0){
    A=(const u16*)(ws+OFF_XB); lda=1024; K=1024;
    if (y<8)      { Bw=(const u16*)(ws+OFF_WQB); ldb=1024; col0=y*128;       outMode=1; }
    else if (y<12){ Bw=(const u16*)(ws+OFF_WKB); ldb=1024; col0=(y-8)*128;   outF=(float*)(ws+OFF_KQF); ldc=512; Nlim=512; }
    else if (y<16){ Bw=(const u16*)(ws+OFF_WVB); ldb=1024; col0=(y-12)*128;  outF=(float*)(ws+OFF_VQF); ldc=512; Nlim=512; }
    else          { Bw=(const u16*)(ws+OFF_W1T); ldb=1024; col0=(y-16)*128;  outMode=4; Nlim=320; }
  } else if (phase==1){
    int seg=y>>3; col0=(y&7)*128;
    const int Ks[4]={64,64,32,160};
    const int Ao[4]={0,64,128,160};
    K=Ks[seg]; lda=384; ldb=K;
    A=(const u16*)(ws+OFF_UB) + Ao[seg];
    if (seg==0)     { Bw=(const u16*)(ws+OFF_W2T); outMode=2; bias=w0b; }
    else if (seg==1){ Bw=(const u16*)(ws+OFF_A2T); outMode=3; bias=a0b; outF=(float*)(ws+OFF_S2A); ldc=1024; }
    else if (seg==2){ Bw=(const u16*)(ws+OFF_V2T); outMode=3; bias=v0b; outF=(float*)(ws+OFF_S2V); ldc=1024; }
    else            { Bw=(const u16*)(ws+OFF_G2T); outF=(float*)(ws+OFF_GBUF); ldc=1024; }
  } else {
    A=(const u16*)(ws+OFF_XGB); lda=1024; K=1024;
    Bw=(const u16*)(ws+OFF_WOB); ldb=1024; col0=y*128; outF=dout; ldc=1024;
  }
  int m0 = blockIdx.x*128;
  __shared__ __align__(16) u16 As[2][4096];
  __shared__ __align__(16) u16 Bs[2][4096];
  int tid=threadIdx.x, l=tid&63, wv=tid>>6, wm=wv>>1, wn=wv&1;

  int srow = wv*32 + (l>>2);
  int cswz = (l&3) ^ ((srow>>1)&3);
  const u16* aP0 = A  + (size_t)(m0+srow)*lda      + cswz*8;
  const u16* aP1 = A  + (size_t)(m0+srow+16)*lda   + cswz*8;
  const u16* bP0 = Bw + (size_t)(col0+srow)*ldb    + cswz*8;
  const u16* bP1 = Bw + (size_t)(col0+srow+16)*ldb + cswz*8;

  f32x4 acc[4][4];
  #pragma unroll
  for (int i=0;i<4;i++)
    #pragma unroll
    for (int j=0;j<4;j++) acc[i][j]=(f32x4){0.f,0.f,0.f,0.f};

#define GSTAGE(b,k0) do{                                   \
    gload_lds16u(aP0 + (k0), &As[b][wv*1024]);             \
    gload_lds16u(aP1 + (k0), &As[b][wv*1024+512]);         \
    gload_lds16u(bP0 + (k0), &Bs[b][wv*1024]);             \
    gload_lds16u(bP1 + (k0), &Bs[b][wv*1024+512]);         \
  }while(0)

  GSTAGE(0,0);
  asm volatile("s_waitcnt vmcnt(0)" ::: "memory");
  __syncthreads();

  int rrow=l&15, ck=l>>4;
  for (int k0=0;k0<K;k0+=32){
    int cb=(k0>>5)&1;
    if (k0+32<K) GSTAGE(cb^1, k0+32);
    s16x8 af[4], bf[4];
    #pragma unroll
    for (int mt=0;mt<4;mt++){
      int ra = wm*64+mt*16+rrow;
      af[mt]=*(const s16x8*)(&As[cb][ra*32 + ((ck ^ ((ra>>1)&3))<<3)]);
    }
    #pragma unroll
    for (int nt=0;nt<4;nt++){
      int rb = wn*64+nt*16+rrow;
      bf[nt]=*(const s16x8*)(&Bs[cb][rb*32 + ((ck ^ ((rb>>1)&3))<<3)]);
    }
    #pragma unroll
    for (int mt=0;mt<4;mt++)
      #pragma unroll
      for (int nt=0;nt<4;nt++)
        acc[mt][nt]=__builtin_amdgcn_mfma_f32_16x16x32_bf16(af[mt],bf[nt],acc[mt][nt],0,0,0);
    __syncthreads();
  }
#undef GSTAGE
  // epilogue
  #pragma unroll
  for (int mt=0;mt<4;mt++){
    #pragma unroll
    for (int nt=0;nt<4;nt++){
      int nglob = col0 + wn*64 + nt*16 + (l&15);
      if (nglob >= Nlim) continue;
      #pragma unroll
      for (int rg=0;rg<4;rg++){
        int mrow = m0 + wm*64 + mt*16 + ((l>>4)<<2) + rg;
        float val = acc[mt][nt][rg];
        if (outMode==0){
          outF[(size_t)mrow*ldc + nglob] = val;
        } else if (outMode==1){          // r bf16 -> SEQ slot 0
          int b=mrow>>10, t=mrow&1023, h=nglob>>6, i=nglob&63;
          char* cbase = SEQc + (size_t)((b*16+h)*64 + (t>>4))*24576 + (size_t)(t&15)*896;
          *(u16*)(cbase + i*2) = f2bf(val);
        } else if (outMode==2){          // decay f32 -> SEQ slot 5
          float w = bias[nglob] + val;
          float d = expf(-expf(w));
          int b=mrow>>10, t=mrow&1023, h=nglob>>6, i=nglob&63;
          char* cbase = SEQc + (size_t)((b*16+h)*64 + (t>>4))*24576 + (size_t)(t&15)*896;
          *(float*)(cbase + 640 + i*4) = d;
        } else if (outMode==3){          // sigmoid(bias+acc)
          float s = 1.0f/(1.0f+__expf(-(bias[nglob]+val)));
          outF[(size_t)mrow*ldc + nglob] = s;
        } else {                          // fused stage-1 activation -> UB bf16
          float a = (nglob<64) ? tanhf(val)
                  : (nglob<160) ? val
                  : 1.0f/(1.0f+__expf(-val));
          UBp[(size_t)mrow*384 + nglob] = f2bf(a);
        }
      }
    }
  }
}

// ---------------- prep2: build SEQ slots k,v,a,b (bf16) + dp + VEPI ----------------
__global__ __launch_bounds__(256) void prep2_kernel(char* ws, const float* vfirst,
  const float* kk_s, const float* ka_s, const float* rkw)
{
  const float* KQF=(const float*)(ws+OFF_KQF);
  const float* VQF=(const float*)(ws+OFF_VQF);
  const float* ICLR=(const float*)(ws+OFF_S2A);
  const float* VMIX=(const float*)(ws+OFF_S2V);
  u16* VEPI=(u16*)(ws+OFF_VEPI);
  float* DPp=(float*)(ws+OFF_DP);
  int m=blockIdx.x, b=m>>10, t=m&1023;
  int tid=threadIdx.x, c0=tid*4, h=c0>>6, i0=c0&63, hk=h>>1;
  f32x4 kq=*(const f32x4*)(KQF+(size_t)m*512+hk*64+i0);
  f32x4 vq=*(const f32x4*)(VQF+(size_t)m*512+hk*64+i0);
  f32x4 ic=*(const f32x4*)(ICLR+(size_t)m*1024+c0);
  f32x4 vm=*(const f32x4*)(VMIX+(size_t)m*1024+c0);
  f32x4 vf=*(const f32x4*)(vfirst+(size_t)m*1024+c0);
  f32x4 kkc=*(const f32x4*)(kk_s+c0);
  f32x4 kac=*(const f32x4*)(ka_s+c0);
  f32x4 kk=kq*kkc;
  float ssq=kk[0]*kk[0]+kk[1]*kk[1]+kk[2]*kk[2]+kk[3]*kk[3];
  #pragma unroll
  for (int mk=1;mk<16;mk<<=1) ssq += __shfl_xor(ssq,mk);
  float scale = 1.0f / fmaxf(sqrtf(ssq), 1e-12f);
  int bh=b*16+h;
  char* cb = ws + OFF_SEQ + (size_t)(bh*64+(t>>4))*24576 + (size_t)(t&15)*896;
  u16x4 rv = *(const u16x4*)(cb + (size_t)i0*2);
  f32x4 rkv = *(const f32x4*)(rkw + h*64 + i0);
  f32x4 kf,vv,av,bv;
  float dpp=0.f;
  #pragma unroll
  for (int j=0;j<4;j++){
    float icc = 1.0f + (ic[j]-1.0f)*kac[j];
    float kkn = kk[j]*scale;
    kf[j]=kq[j]*icc;
    vv[j]=vq[j] + (vf[j]-vq[j])*vm[j];
    av[j]=-kkn;
    bv[j]=kkn*icc;
    dpp += bf2f(rv[j])*kf[j]*rkv[j];
  }
  #pragma unroll
  for (int mk=1;mk<16;mk<<=1) dpp += __shfl_xor(dpp,mk);
  if ((tid&15)==0) DPp[(size_t)bh*1024 + t] = dpp;
  i32x2 o;
  o[0]=pk2(kf[0],kf[1]); o[1]=pk2(kf[2],kf[3]);
  *(i32x2*)(cb + 128 + (size_t)i0*2) = o;
  o[0]=pk2(vv[0],vv[1]); o[1]=pk2(vv[2],vv[3]);
  *(i32x2*)(cb + 256 + (size_t)i0*2) = o;
  *(i32x2*)(VEPI + ((size_t)bh*1024+t)*64 + i0) = o;
  o[0]=pk2(av[0],av[1]); o[1]=pk2(av[2],av[3]);
  *(i32x2*)(cb + 384 + (size_t)i0*2) = o;
  o[0]=pk2(bv[0],bv[1]); o[1]=pk2(bv[2],bv[3]);
  *(i32x2*)(cb + 512 + (size_t)i0*2) = o;
}

#define MFMA32(a,b,c) __builtin_amdgcn_mfma_f32_16x16x32_bf16(a,b,c,0,0,0)

// ---------------- precompute: per-chunk S-independent record (2048-way parallel) ------
// 31776B LDS -> 5 blocks/CU. Column-parallel operand build (lane = channel),
// overlay of solve/W buffers onto the dead raw region.
__global__ __launch_bounds__(64) void pre_kernel(char* ws){
  int bid=blockIdx.x;
  int l=threadIdx.x, c16=l&15, g=l>>4;
  char* chunk = ws + OFF_SEQ + (size_t)bid*24576;
  char* rec = chunk;

  __shared__ __align__(16) char SH[31776];
  u16* AT =(u16*)(SH+14336);
  u16* RT =(u16*)(SH+16640);
  u16* BT =(u16*)(SH+18944);
  u16* KT =(u16*)(SH+21248);
  u16* vbb=(u16*)(SH+23552);
  u16* BKL=(u16*)(SH+26656);
  // overlay region (valid after column pass)
  float* WN  =(float*)(SH+0);
  u16* WY =(u16*)(SH+1088);
  u16* WB =(u16*)(SH+1888);
  u16* WK =(u16*)(SH+2688);
  u16* pbb=(u16*)(SH+3488);
  u16* zbb=(u16*)(SH+6592);
  float* rhsb=(float*)(SH+9696);
  float* gtmp=(float*)(SH+9696);   // overlays rhsb (disjoint lifetime)
  const s16x8 zero8 = {0,0,0,0,0,0,0,0};
  const f32x4 zf4 = {0.f,0.f,0.f,0.f};

  // ---- stage chunk payload (14336B, linear) ----
  #pragma unroll
  for (int q=0;q<14;q++)
    gload_lds16((const float*)(chunk + (size_t)q*1024) + l*4, (float*)(SH + q*1024));
  asm volatile("s_waitcnt vmcnt(0)" ::: "memory");
  __builtin_amdgcn_sched_barrier(0);

  // ---- column pass: lane = channel l ----
  float ptv[16]; float pp=1.f;
  #pragma unroll
  for (int t=0;t<16;t++){ pp *= *(const float*)(SH + t*896 + 640 + l*4); ptv[t]=pp; }
  float pL = ptv[15];
  *(float*)(rec + 10240 + (size_t)l*4) = pL;
  float rpL = __builtin_amdgcn_rcpf(pL);
  float bs[16], ks[16];
  u16 vcol[16];
  #pragma unroll
  for (int t=0;t<16;t++){
    float sc = pL * __builtin_amdgcn_rcpf(ptv[t]);
    bs[t] = bf2f(*(const u16*)(SH + t*896 + 512 + l*2)) * sc;
    ks[t] = bf2f(*(const u16*)(SH + t*896 + 128 + l*2)) * sc;
    vcol[t] = *(const u16*)(SH + t*896 + 256 + l*2);
  }
  {
    i32x4 o;
    o[0]=(int)((unsigned)vcol[0]|((unsigned)vcol[1]<<16));
    o[1]=(int)((unsigned)vcol[2]|((unsigned)vcol[3]<<16));
    o[2]=(int)((unsigned)vcol[4]|((unsigned)vcol[5]<<16));
    o[3]=(int)((unsigned)vcol[6]|((unsigned)vcol[7]<<16));
    *(i32x4*)(&vbb[l*24]) = o;
    o[0]=(int)((unsigned)vcol[8]|((unsigned)vcol[9]<<16));
    o[1]=(int)((unsigned)vcol[10]|((unsigned)vcol[11]<<16));
    o[2]=(int)((unsigned)vcol[12]|((unsigned)vcol[13]<<16));
    o[3]=(int)((unsigned)vcol[14]|((unsigned)vcol[15]<<16));
    *(i32x4*)(&vbb[l*24+8]) = o;
    o[0]=pk2(bs[0],bs[1]); o[1]=pk2(bs[2],bs[3]); o[2]=pk2(bs[4],bs[5]); o[3]=pk2(bs[6],bs[7]);
    *(i32x4*)(&BKL[l*40]) = o;
    o[0]=pk2(bs[8],bs[9]); o[1]=pk2(bs[10],bs[11]); o[2]=pk2(bs[12],bs[13]); o[3]=pk2(bs[14],bs[15]);
    *(i32x4*)(&BKL[l*40+8]) = o;
    o[0]=pk2(ks[0],ks[1]); o[1]=pk2(ks[2],ks[3]); o[2]=pk2(ks[4],ks[5]); o[3]=pk2(ks[6],ks[7]);
    *(i32x4*)(&BKL[l*40+16]) = o;
    o[0]=pk2(ks[8],ks[9]); o[1]=pk2(ks[10],ks[11]); o[2]=pk2(ks[12],ks[13]); o[3]=pk2(ks[14],ks[15]);
    *(i32x4*)(&BKL[l*40+24]) = o;
  }
  #pragma unroll
  for (int t=0;t<16;t++){
    float at = bf2f(*(const u16*)(SH + t*896 + 384 + l*2));
    float rt = bf2f(*(const u16*)(SH + t*896 +   0 + l*2));
    float pprev = (t==0) ? 1.f : ptv[t-1];
    AT[t*72+l] = f2bf(pprev*at);
    RT[t*72+l] = f2bf(ptv[t]*rt);
    BT[t*72+l] = f2bf(bs[t]*rpL);
    KT[t*72+l] = f2bf(ks[t]*rpL);
  }
  asm volatile("s_waitcnt lgkmcnt(0)" ::: "memory");
  __builtin_amdgcn_sched_barrier(0);

  // ---- W-block: N, Yhat, Tb, Tk ----
  {
    s16x8 afA[2], afR[2], bfB[2], bfK[2];
    #pragma unroll
    for (int Kt=0;Kt<2;Kt++){
      afA[Kt]=*(const s16x8*)(&AT[c16*72 + 32*Kt + 8*g]);
      afR[Kt]=*(const s16x8*)(&RT[c16*72 + 32*Kt + 8*g]);
      bfB[Kt]=*(const s16x8*)(&BT[c16*72 + 32*Kt + 8*g]);
      bfK[Kt]=*(const s16x8*)(&KT[c16*72 + 32*Kt + 8*g]);
    }
    f32x4 dNN=zf4, dNY=zf4, dBB=zf4, dBK=zf4;
    #pragma unroll
    for (int Kt=0;Kt<2;Kt++){
      dNN=MFMA32(afA[Kt],bfB[Kt],dNN);
      dNY=MFMA32(afA[Kt],bfK[Kt],dNY);
      dBB=MFMA32(afR[Kt],bfB[Kt],dBB);
      dBK=MFMA32(afR[Kt],bfK[Kt],dBK);
    }
    #pragma unroll
    for (int e=0;e<4;e++){
      int tR=4*g+e, sC=c16;
      WN[tR*17+sC] = dNN[e];
      WY[tR*24+sC] = (sC<tR)? f2bf(dNY[e]) : (u16)0;
      WB[tR*24+sC] = (sC<=tR)? f2bf(dBB[e]) : (u16)0;
      WK[tR*24+sC] = (sC<=tR)? f2bf(dBK[e]) : (u16)0;
    }
  }

  // ---- YhatV -> rhsb ----
  s16x8 vf[4];
  #pragma unroll
  for (int J=0;J<4;J++){
    vf[J]=zero8;
    if (g<2) vf[J]=*(const s16x8*)(&vbb[(16*J+c16)*24 + 8*g]);
  }
  {
    s16x8 wyf=zero8;
    if (g<2) wyf=*(const s16x8*)(&WY[c16*24 + 8*g]);
    f32x4 dR[4];
    #pragma unroll
    for (int J=0;J<4;J++){
      dR[J]=zf4;
      dR[J]=MFMA32(wyf,vf[J],dR[J]);
      #pragma unroll
      for (int e=0;e<4;e++)
        rhsb[(4*g+e)*68 + 16*J + c16] = dR[J][e];
    }
  }

  // ---- P-solve: (I-N)P = Atil, lane = column j=l ----
  {
    float pv[16];
    #pragma unroll
    for (int t=0;t<16;t++) pv[t]=bf2f(AT[t*72+l]);
    #pragma unroll
    for (int t=1;t<16;t++)
      #pragma unroll
      for (int s=0;s<16;s++){
        if (s<t) pv[t] += WN[t*17+s]*pv[s];
      }
    i32x4 o;
    o[0]=pk2(pv[0],pv[1]); o[1]=pk2(pv[2],pv[3]); o[2]=pk2(pv[4],pv[5]); o[3]=pk2(pv[6],pv[7]);
    *(i32x4*)(&pbb[l*24]) = o;
    o[0]=pk2(pv[8],pv[9]); o[1]=pk2(pv[10],pv[11]); o[2]=pk2(pv[12],pv[13]); o[3]=pk2(pv[14],pv[15]);
    *(i32x4*)(&pbb[l*24+8]) = o;
  }

  // ---- z-solve: (I-N)zloc = YhatV, lane = column i=l ----
  {
    float zz[16];
    #pragma unroll
    for (int t=0;t<16;t++) zz[t]=rhsb[t*68+l];
    #pragma unroll
    for (int t=1;t<16;t++)
      #pragma unroll
      for (int s=0;s<16;s++){
        if (s<t) zz[t] += WN[t*17+s]*zz[s];
      }
    i32x4 o;
    o[0]=pk2(zz[0],zz[1]); o[1]=pk2(zz[2],zz[3]); o[2]=pk2(zz[4],zz[5]); o[3]=pk2(zz[6],zz[7]);
    *(i32x4*)(&zbb[l*24]) = o;
    o[0]=pk2(zz[8],zz[9]); o[1]=pk2(zz[10],zz[11]); o[2]=pk2(zz[12],zz[13]); o[3]=pk2(zz[14],zz[15]);
    *(i32x4*)(&zbb[l*24+8]) = o;
  }
  asm volatile("s_waitcnt lgkmcnt(0)" ::: "memory");
  __builtin_amdgcn_sched_barrier(0);

  // ---- G = Rtil + Tb*P -> gtmp ; Yloc = Tb*zloc + Tk*V -> record strips ----
  {
    s16x8 wbf=zero8, wkf=zero8;
    if (g<2){
      wbf=*(const s16x8*)(&WB[c16*24 + 8*g]);
      wkf=*(const s16x8*)(&WK[c16*24 + 8*g]);
    }
    #pragma unroll
    for (int J=0;J<4;J++){
      s16x8 pfB=zero8, zfB=zero8;
      if (g<2){
        pfB=*(const s16x8*)(&pbb[(16*J+c16)*24 + 8*g]);
        zfB=*(const s16x8*)(&zbb[(16*J+c16)*24 + 8*g]);
      }
      f32x4 dG, dYl=zf4;
      #pragma unroll
      for (int e=0;e<4;e++) dG[e]=bf2f(RT[(4*g+e)*72 + 16*J + c16]);
      dG=MFMA32(wbf,pfB,dG);
      dYl=MFMA32(wbf,zfB,dYl);
      dYl=MFMA32(wkf,vf[J],dYl);
      #pragma unroll
      for (int e=0;e<4;e++) gtmp[(4*g+e)*68 + 16*J + c16]=dG[e];
      i32x2 o2; o2[0]=pk2(dYl[0],dYl[1]); o2[1]=pk2(dYl[2],dYl[3]);
      *(i32x2*)(rec + 10496 + (size_t)J*2560 + 2048 + (size_t)l*8) = o2;
    }
  }

  // ---- Q = P^T [Bbar;Kbar] tiles -> record Q A-frags; c = [Bbar;Kbar]^T [z;V] ----
  {
    s16x8 bk[4], pfr[4], bzv[4];
    #pragma unroll
    for (int nt=0;nt<4;nt++) bk[nt]=*(const s16x8*)(&BKL[(16*nt+c16)*40 + 8*g]);
    #pragma unroll
    for (int mt=0;mt<4;mt++)
      pfr[mt]= (g<2) ? *(const s16x8*)(&pbb[(16*mt+c16)*24 + 8*g]) : zero8;
    #pragma unroll
    for (int it=0;it<4;it++)
      bzv[it]= (g<2) ? *(const s16x8*)(&zbb[(16*it+c16)*24 + 8*g])
                     : *(const s16x8*)(&vbb[(16*it+c16)*24 + 8*(g-2)]);
    #pragma unroll
    for (int mt=0;mt<4;mt++){
      #pragma unroll
      for (int nt=0;nt<4;nt++){
        f32x4 dQ = MFMA32(pfr[mt], bk[nt], zf4);
        int kk = mt>>1, gq = ((mt&1)<<1) | (g>>1), jo = g&1;
        i32x2 o2; o2[0]=pk2(dQ[0],dQ[1]); o2[1]=pk2(dQ[2],dQ[3]);
        *(i32x2*)(rec + ((size_t)(kk*4+nt)*64 + (size_t)(c16 + 16*gq))*16 + 8*jo) = o2;
      }
    }
    #pragma unroll
    for (int jtp=0;jtp<4;jtp++){
      #pragma unroll
      for (int it=0;it<4;it++){
        f32x4 dc = MFMA32(bk[jtp], bzv[it], zf4);
        i32x2 o2; o2[0]=pk2(dc[0],dc[1]); o2[1]=pk2(dc[2],dc[3]);
        *(i32x2*)(rec + 10496 + (size_t)it*2560 + ((size_t)jtp*64 + l)*8) = o2;
      }
    }
  }

  // ---- G A-frags -> record ----
  #pragma unroll
  for (int kk=0;kk<2;kk++){
    f32x4 b0 = *(const f32x4*)(&gtmp[c16*68 + 32*kk + 8*g]);
    f32x4 b1 = *(const f32x4*)(&gtmp[c16*68 + 32*kk + 8*g + 4]);
    i32x4 o;
    o[0]=pk2(b0[0],b0[1]); o[1]=pk2(b0[2],b0[3]); o[2]=pk2(b1[0],b1[1]); o[3]=pk2(b1[2],b1[3]);
    *(i32x4*)(rec + 8192 + (size_t)(kk*64+l)*16) = o;
  }
}

// ---------------- serial scan: S' = pL.S + Q.S^T + c ; y = G.S^T + Yloc ----------------
__global__ __launch_bounds__(64) void scan2_kernel(char* ws, const float* S0, float* dout){
  float* YB=(float*)(ws+OFF_YBUF);
  const char* recb = ws + OFF_SEQ;
  int bid=blockIdx.x, bh=bid>>2, w=bid&3;
  int l=threadIdx.x, c16=l&15, g=l>>4;

  __shared__ __align__(16) char buf[3][13824];
  __shared__ __align__(16) u16 ST[16*88];

  f32x4 Sreg[4];
  #pragma unroll
  for (int jt=0;jt<4;jt++)
    Sreg[jt] = *(const f32x4*)(S0 + (size_t)bh*4096 + (size_t)(16*w+c16)*64 + 16*jt + 4*g);
  #pragma unroll
  for (int jt=0;jt<4;jt++){
    i32x2 p; p[0]=pk2(Sreg[jt][0],Sreg[jt][1]); p[1]=pk2(Sreg[jt][2],Sreg[jt][3]);
    *(i32x2*)(&ST[c16*88 + 16*jt + 4*g]) = p;
  }

  const char* rb = recb + (size_t)(bh*64)*24576;

  #pragma unroll
  for (int pc=0; pc<2; ++pc){
    const float* r = (const float*)(rb + (size_t)pc*24576);
    float* d = (float*)(&buf[pc][0]);
    #pragma unroll
    for (int q=0;q<10;q++) gload_lds16(r + q*256 + l*4, d + q*256);
    gload_lds4((const float*)(rb + (size_t)pc*24576 + 10240) + l, d + 2560);
    const float* rs = (const float*)(rb + (size_t)pc*24576 + 10496 + (size_t)w*2560);
    #pragma unroll
    for (int q=0;q<3;q++) gload_lds16(rs + q*256 + l*4, d + 2624 + q*256);
  }
  asm volatile("s_waitcnt vmcnt(14)" ::: "memory");
  __builtin_amdgcn_sched_barrier(0);

  float* yb0 = YB + (size_t)bh*65536;
  int cur=0;

  #pragma unroll 1
  for (int ch=0; ch<64; ++ch){
    asm volatile("s_waitcnt vmcnt(18)" ::: "memory");
    __builtin_amdgcn_sched_barrier(0);
    const char* bp = &buf[cur][0];

    s16x8 qf[4][2], gf[2], sB[2];
    #pragma unroll
    for (int kk=0;kk<2;kk++){
      #pragma unroll
      for (int jt=0;jt<4;jt++)
        qf[jt][kk]=*(const s16x8*)(bp + (size_t)((kk*4+jt)*64 + l)*16);
      gf[kk]=*(const s16x8*)(bp + 8192 + (size_t)(kk*64+l)*16);
      sB[kk]=*(const s16x8*)(&ST[c16*88 + 32*kk + 8*g]);
    }
    f32x4 pl4[4];
    #pragma unroll
    for (int jt=0;jt<4;jt++)
      pl4[jt]=*(const f32x4*)(bp + 10240 + (size_t)(16*jt+4*g)*4);
    i32x2 cfr[4];
    #pragma unroll
    for (int jt=0;jt<4;jt++)
      cfr[jt]=*(const i32x2*)(bp + 10496 + (size_t)(jt*64+l)*8);
    i32x2 ylv=*(const i32x2*)(bp + 12544 + (size_t)l*8);

    {
      int p2 = cur+2; if (p2>=3) p2-=3;
      int nc = ch+2; if (nc>63) nc=63;
      const float* r = (const float*)(rb + (size_t)nc*24576);
      float* d = (float*)(&buf[p2][0]);
      #pragma unroll
      for (int q=0;q<10;q++) gload_lds16(r + q*256 + l*4, d + q*256);
      gload_lds4((const float*)(rb + (size_t)nc*24576 + 10240) + l, d + 2560);
      const float* rs = (const float*)(rb + (size_t)nc*24576 + 10496 + (size_t)w*2560);
      #pragma unroll
      for (int q=0;q<3;q++) gload_lds16(rs + q*256 + l*4, d + 2624 + q*256);
    }
    __builtin_amdgcn_sched_barrier(0);

    f32x4 dy=cvt4(ylv);
    dy=MFMA32(gf[0],sB[0],dy); dy=MFMA32(gf[1],sB[1],dy);
    #pragma unroll
    for (int jt=0;jt<4;jt++){
      f32x4 acc = cvt4(cfr[jt]);
      acc = MFMA32(qf[jt][0], sB[0], acc);
      acc = MFMA32(qf[jt][1], sB[1], acc);
      #pragma unroll
      for (int e=0;e<4;e++) acc[e] = fmaf(pl4[jt][e], Sreg[jt][e], acc[e]);
      Sreg[jt]=acc;
    }
    #pragma unroll
    for (int jt=0;jt<4;jt++){
      i32x2 p; p[0]=cvtpk(Sreg[jt][0],Sreg[jt][1]); p[1]=cvtpk(Sreg[jt][2],Sreg[jt][3]);
      *(i32x2*)(&ST[c16*88 + 16*jt + 4*g]) = p;
    }
    {
      float* yb = yb0 + (size_t)ch*1024;
      #pragma unroll
      for (int e=0;e<4;e++)
        yb[(size_t)(4*g+e)*64 + 16*w + c16] = dy[e];
    }
    cur = (cur+1==3)?0:cur+1;
  }

  #pragma unroll
  for (int jt=0;jt<4;jt++)
    *(f32x4*)(dout + 2097152 + (size_t)bh*4096 + (size_t)(16*w+c16)*64 + 16*jt + 4*g) = Sreg[jt];
}

// ---------------- epilogue: groupnorm + bonus + gate -> bf16 ----------------
__global__ __launch_bounds__(256) void epi_kernel(char* ws, const float* lnw, const float* lnb)
{
  const float* YB=(const float*)(ws+OFF_YBUF);
  const u16* VEPI=(const u16*)(ws+OFF_VEPI);
  const float* DPp=(const float*)(ws+OFF_DP);
  const float* GB=(const float*)(ws+OFF_GBUF);
  u16* XGB=(u16*)(ws+OFF_XGB);
  int m=blockIdx.x, b=m>>10, t=m&1023;
  int tid=threadIdx.x, c0=tid*4, h=c0>>6, i0=c0&63;
  f32x4 y=*(const f32x4*)(YB + ((size_t)(b*16+h)*1024+t)*64 + i0);
  float s = y[0]+y[1]+y[2]+y[3];
  float ss= y[0]*y[0]+y[1]*y[1]+y[2]*y[2]+y[3]*y[3];
  #pragma unroll
  for (int mk=1;mk<16;mk<<=1){ s+=__shfl_xor(s,mk); ss+=__shfl_xor(ss,mk); }
  float mu=s*(1.0f/64.0f), var=ss*(1.0f/64.0f)-mu*mu;
  float inv=rsqrtf(var + 6.4e-4f);
  u16x4 v16=*(const u16x4*)(VEPI + ((size_t)(b*16+h)*1024+t)*64 + i0);
  float dp = DPp[(size_t)(b*16+h)*1024 + t];
  f32x4 gg=*(const f32x4*)(GB+(size_t)m*1024+c0);
  u16x4 outv;
  #pragma unroll
  for (int j=0;j<4;j++){
    float xn = (y[j]-mu)*inv*lnw[c0+j] + lnb[c0+j] + dp*bf2f(v16[j]);
    outv[j]=f2bf(xn*gg[j]);
  }
  *(u16x4*)(XGB+(size_t)m*1024+c0)=outv;
}

extern "C" void kernel_launch(void* const* d_in, const int* in_sizes, int n_in,
                              void* d_out, int out_size, void* d_ws, size_t ws_size,
                              hipStream_t stream) {
  const float* x      =(const float*)d_in[0];
  const float* S0     =(const float*)d_in[1];
  const float* vfirst =(const float*)d_in[2];
  const float* w0     =(const float*)d_in[3];
  const float* w1     =(const float*)d_in[4];
  const float* w2     =(const float*)d_in[5];
  const float* a0     =(const float*)d_in[6];
  const float* a1     =(const float*)d_in[7];
  const float* a2     =(const float*)d_in[8];
  const float* v0     =(const float*)d_in[9];
  const float* v1     =(const float*)d_in[10];
  const float* v2     =(const float*)d_in[11];
  const float* g1     =(const float*)d_in[12];
  const float* g2     =(const float*)d_in[13];
  const float* k_k    =(const float*)d_in[14];
  const float* k_a    =(const float*)d_in[15];
  const float* r_k    =(const float*)d_in[16];
  const float* Wq     =(const float*)d_in[17];
  const float* Wk     =(const float*)d_in[18];
  const float* Wv     =(const float*)d_in[19];
  const float* Wo     =(const float*)d_in[20];
  const float* ln_w   =(const float*)d_in[21];
  const float* ln_b   =(const float*)d_in[22];
  char* ws=(char*)d_ws;
  float* dout=(float*)d_out;

  prep_kernel<<<2048,256,0,stream>>>(ws,x,vfirst,w1,w2,a1,a2,v1,v2,g1,g2,Wq,Wk,Wv,Wo,dout);
  gemm_kernel<<<dim3(16,19),256,0,stream>>>(0,ws,w0,a0,v0,dout);
  gemm_kernel<<<dim3(16,32),256,0,stream>>>(1,ws,w0,a0,v0,dout);
  prep2_kernel<<<2048,256,0,stream>>>(ws,vfirst,k_k,k_a,r_k);
  pre_kernel<<<2048,64,0,stream>>>(ws);
  scan2_kernel<<<128,64,0,stream>>>(ws,S0,dout);
  epi_kernel<<<2048,256,0,stream>>>(ws,ln_w,ln_b);
  gemm_kernel<<<dim3(16,8),256,0,stream>>>(2,ws,w0,a0,v0,dout);
}

// Round 12
// 195.362 us; speedup vs baseline: 1.2155x; 1.0026x over previous
//
#include <hip/hip_runtime.h>

typedef unsigned short u16;
typedef __attribute__((ext_vector_type(8))) short s16x8;
typedef __attribute__((ext_vector_type(4))) float f32x4;
typedef __attribute__((ext_vector_type(4))) int   i32x4;
typedef __attribute__((ext_vector_type(2))) int   i32x2;
typedef __attribute__((ext_vector_type(4))) unsigned short u16x4;

// ---------------- workspace layout (bytes) ----------------
constexpr size_t OFF_XB   = 0;                     // bf16 x [2048][1024]; later VEPI
constexpr size_t OFF_WQB  = OFF_XB   + 4194304;    // bf16 Wq         [1024][1024]
constexpr size_t OFF_WKB  = OFF_WQB  + 2097152;    // bf16 Wk         [512][1024]
constexpr size_t OFF_WVB  = OFF_WKB  + 1048576;    // bf16 Wv         [512][1024]
constexpr size_t OFF_WOB  = OFF_WVB  + 1048576;    // bf16 Wo         [1024][1024]
constexpr size_t OFF_W1T  = OFF_WOB  + 2097152;    // bf16 W1T [384][1024]; later DP
constexpr size_t OFF_W2T  = OFF_W1T  + 786432;     // bf16 w2T        [1024][64]
constexpr size_t OFF_A2T  = OFF_W2T  + 131072;     // bf16 a2T        [1024][64]
constexpr size_t OFF_V2T  = OFF_A2T  + 131072;     // bf16 v2T        [1024][32]
constexpr size_t OFF_G2T  = OFF_V2T  + 65536;      // bf16 g2T        [1024][160]
constexpr size_t OFF_KQF  = OFF_G2T  + 327680;     // f32 k-proj      [2048][512]
constexpr size_t OFF_VQF  = OFF_KQF  + 4194304;    // f32 v-proj      [2048][512]
constexpr size_t OFF_URAW = OFF_VQF  + 4194304;    // (dead)
constexpr size_t OFF_UB   = OFF_URAW + 2621440;    // bf16 stage1 act [2048][384]
constexpr size_t OFF_S2A  = OFF_UB   + 1572864;    // f32 iclr        [2048][1024]
constexpr size_t OFF_S2V  = OFF_S2A  + 8388608;    // f32 vmix        [2048][1024]
constexpr size_t OFF_GBUF = OFF_S2V  + 8388608;    // f32 gate        [2048][1024]
constexpr size_t OFF_SEQ  = OFF_GBUF + 8388608;    // chunks [2048][24576B]; later records
constexpr size_t OFF_YBUF = OFF_SEQ  + 50331648;   // f32 y   [2][16][1024][64]
constexpr size_t OFF_XGB  = OFF_YBUF + 8388608;    // bf16 xn*g       [2048][1024]

// SEQ chunk payload (first 14336B of each 24576B slot), per t-row stride 896:
//  +0 r bf16[64] | +128 k | +256 v | +384 a | +512 b | +640 decay f32[64]
// record overlay (pre overwrites its OWN chunk): 0 Q(8192) | 8192 G(2048) |
//  10240 pL f32[64] | 10496 + w*2560 { c[jt4][lane]x8B (2048) | Yloc (512) }
constexpr size_t OFF_VEPI = OFF_XB;                // bf16 v rows (XB dead after gemm0)
constexpr size_t OFF_DP   = OFF_W1T;               // f32 dp (W1T dead after gemm0)

__device__ __forceinline__ u16 f2bf(float f){
  unsigned int u = __builtin_bit_cast(unsigned int, f);
  u = u + 0x7fffu + ((u >> 16) & 1u);
  return (u16)(u >> 16);
}
__device__ __forceinline__ int pk2(float a, float b){
  return (int)((unsigned)f2bf(a) | ((unsigned)f2bf(b) << 16));
}
__device__ __forceinline__ int cvtpk(float a, float b){
  int r;
  asm("v_cvt_pk_bf16_f32 %0, %1, %2" : "=v"(r) : "v"(a), "v"(b));
  return r;
}
__device__ __forceinline__ float bf2f(u16 h){
  return __builtin_bit_cast(float, ((unsigned)h) << 16);
}
__device__ __forceinline__ f32x4 cvt4(i32x2 v){
  unsigned a=(unsigned)v[0], b=(unsigned)v[1];
  f32x4 r;
  r[0]=__builtin_bit_cast(float, a<<16);
  r[1]=__builtin_bit_cast(float, a&0xffff0000u);
  r[2]=__builtin_bit_cast(float, b<<16);
  r[3]=__builtin_bit_cast(float, b&0xffff0000u);
  return r;
}

__device__ __forceinline__ void gload_lds16(const float* g, float* l){
  __builtin_amdgcn_global_load_lds((const __attribute__((address_space(1))) void*)g,
                                   (__attribute__((address_space(3))) void*)l, 16, 0, 0);
}
__device__ __forceinline__ void gload_lds16u(const u16* g, u16* l){
  __builtin_amdgcn_global_load_lds((const __attribute__((address_space(1))) void*)g,
                                   (__attribute__((address_space(3))) void*)l, 16, 0, 0);
}
__device__ __forceinline__ void gload_lds4(const float* g, float* l){
  __builtin_amdgcn_global_load_lds((const __attribute__((address_space(1))) void*)g,
                                   (__attribute__((address_space(3))) void*)l, 4, 0, 0);
}

// ---------------- prep: convert/transpose + v_first passthrough ----------------
constexpr size_t N_XB=2097152, N_WQ=1048576, N_WK=524288, N_WV=524288, N_WO=1048576,
  N_W1T=393216, N_W2T=65536, N_A2T=65536, N_V2T=32768, N_G2T=163840, N_VF=2097152;
constexpr size_t PREP_TOT = N_XB+N_WQ+N_WK+N_WV+N_WO+N_W1T+N_W2T+N_A2T+N_V2T+N_G2T+N_VF;

__global__ __launch_bounds__(256) void prep_kernel(char* ws, const float* x, const float* vfirst,
  const float* w1, const float* w2, const float* a1, const float* a2,
  const float* v1, const float* v2, const float* g1, const float* g2,
  const float* Wq, const float* Wk, const float* Wv, const float* Wo, float* dout)
{
  u16* XB=(u16*)(ws+OFF_XB); u16* WQB=(u16*)(ws+OFF_WQB); u16* WKB=(u16*)(ws+OFF_WKB);
  u16* WVB=(u16*)(ws+OFF_WVB); u16* WOB=(u16*)(ws+OFF_WOB); u16* W1T=(u16*)(ws+OFF_W1T);
  u16* W2T=(u16*)(ws+OFF_W2T); u16* A2T=(u16*)(ws+OFF_A2T); u16* V2T=(u16*)(ws+OFF_V2T);
  u16* G2T=(u16*)(ws+OFF_G2T);
  for (size_t idx=(size_t)blockIdx.x*256+threadIdx.x; idx<PREP_TOT; idx+=(size_t)gridDim.x*256){
    size_t r = idx;
    if (r < N_XB){ XB[r]=f2bf(x[r]); continue; } r-=N_XB;
    if (r < N_WQ){ WQB[r]=f2bf(Wq[r]); continue; } r-=N_WQ;
    if (r < N_WK){ WKB[r]=f2bf(Wk[r]); continue; } r-=N_WK;
    if (r < N_WV){ WVB[r]=f2bf(Wv[r]); continue; } r-=N_WV;
    if (r < N_WO){ WOB[r]=f2bf(Wo[r]); continue; } r-=N_WO;
    if (r < N_W1T){
      int n=(int)(r>>10), k=(int)(r&1023); float v=0.f;
      if (n<64) v=w1[(size_t)k*64+n];
      else if (n<128) v=a1[(size_t)k*64+(n-64)];
      else if (n<160) v=v1[(size_t)k*32+(n-128)];
      else if (n<320) v=g1[(size_t)k*160+(n-160)];
      W1T[r]=f2bf(v); continue; } r-=N_W1T;
    if (r < N_W2T){ int c=(int)(r>>6), d=(int)(r&63); W2T[r]=f2bf(w2[(size_t)d*1024+c]); continue; } r-=N_W2T;
    if (r < N_A2T){ int c=(int)(r>>6), d=(int)(r&63); A2T[r]=f2bf(a2[(size_t)d*1024+c]); continue; } r-=N_A2T;
    if (r < N_V2T){ int c=(int)(r>>5), d=(int)(r&31); V2T[r]=f2bf(v2[(size_t)d*1024+c]); continue; } r-=N_V2T;
    if (r < N_G2T){ int c=(int)(r/160), d=(int)(r%160); G2T[r]=f2bf(g2[(size_t)d*1024+c]); continue; } r-=N_G2T;
    dout[2228224 + r] = vfirst[r];   // v_first passthrough (offset 2097152+131072)
  }
}

// ---------------- unified NT bf16 MFMA GEMM: C[m][n] = sum_k A[m][k]*B[n][k] ----------------
__global__ __launch_bounds__(256) void gemm_kernel(int phase, char* ws,
  const float* w0b, const float* a0b, const float* v0b, float* dout)
{
  const u16* A; const u16* Bw;
  float* outF=nullptr; const float* bias=nullptr;
  char* SEQc=(char*)(ws+OFF_SEQ);
  u16* UBp=(u16*)(ws+OFF_UB);
  int lda=0, ldb=0, K=0, ldc=0, Nlim=1024, col0=0, outMode=0;
  int y = blockIdx.y;
  if (phase==0){
    A=(const u16*)(ws+OFF_XB); lda=1024; K=1024;
    if (y<8)      { Bw=(const u16*)(ws+OFF_WQB); ldb=1024; col0=y*128;       outMode=1; }
    else if (y<12){ Bw=(const u16*)(ws+OFF_WKB); ldb=1024; col0=(y-8)*128;   outF=(float*)(ws+OFF_KQF); ldc=512; Nlim=512; }
    else if (y<16){ Bw=(const u16*)(ws+OFF_WVB); ldb=1024; col0=(y-12)*128;  outF=(float*)(ws+OFF_VQF); ldc=512; Nlim=512; }
    else          { Bw=(const u16*)(ws+OFF_W1T); ldb=1024; col0=(y-16)*128;  outMode=4; Nlim=320; }
  } else if (phase==1){
    int seg=y>>3; col0=(y&7)*128;
    const int Ks[4]={64,64,32,160};
    const int Ao[4]={0,64,128,160};
    K=Ks[seg]; lda=384; ldb=K;
    A=(const u16*)(ws+OFF_UB) + Ao[seg];
    if (seg==0)     { Bw=(const u16*)(ws+OFF_W2T); outMode=2; bias=w0b; }
    else if (seg==1){ Bw=(const u16*)(ws+OFF_A2T); outMode=3; bias=a0b; outF=(float*)(ws+OFF_S2A); ldc=1024; }
    else if (seg==2){ Bw=(const u16*)(ws+OFF_V2T); outMode=3; bias=v0b; outF=(float*)(ws+OFF_S2V); ldc=1024; }
    else            { Bw=(const u16*)(ws+OFF_G2T); outF=(float*)(ws+OFF_GBUF); ldc=1024; }
  } else {
    A=(const u16*)(ws+OFF_XGB); lda=1024; K=1024;
    Bw=(const u16*)(ws+OFF_WOB); ldb=1024; col0=y*128; outF=dout; ldc=1024;
  }
  int m0 = blockIdx.x*128;
  __shared__ __align__(16) u16 As[2][4096];
  __shared__ __align__(16) u16 Bs[2][4096];
  int tid=threadIdx.x, l=tid&63, wv=tid>>6, wm=wv>>1, wn=wv&1;

  int srow = wv*32 + (l>>2);
  int cswz = (l&3) ^ ((srow>>1)&3);
  const u16* aP0 = A  + (size_t)(m0+srow)*lda      + cswz*8;
  const u16* aP1 = A  + (size_t)(m0+srow+16)*lda   + cswz*8;
  const u16* bP0 = Bw + (size_t)(col0+srow)*ldb    + cswz*8;
  const u16* bP1 = Bw + (size_t)(col0+srow+16)*ldb + cswz*8;

  f32x4 acc[4][4];
  #pragma unroll
  for (int i=0;i<4;i++)
    #pragma unroll
    for (int j=0;j<4;j++) acc[i][j]=(f32x4){0.f,0.f,0.f,0.f};

#define GSTAGE(b,k0) do{                                   \
    gload_lds16u(aP0 + (k0), &As[b][wv*1024]);             \
    gload_lds16u(aP1 + (k0), &As[b][wv*1024+512]);         \
    gload_lds16u(bP0 + (k0), &Bs[b][wv*1024]);             \
    gload_lds16u(bP1 + (k0), &Bs[b][wv*1024+512]);         \
  }while(0)

  GSTAGE(0,0);
  asm volatile("s_waitcnt vmcnt(0)" ::: "memory");
  __syncthreads();

  int rrow=l&15, ck=l>>4;
  for (int k0=0;k0<K;k0+=32){
    int cb=(k0>>5)&1;
    if (k0+32<K) GSTAGE(cb^1, k0+32);
    s16x8 af[4], bf[4];
    #pragma unroll
    for (int mt=0;mt<4;mt++){
      int ra = wm*64+mt*16+rrow;
      af[mt]=*(const s16x8*)(&As[cb][ra*32 + ((ck ^ ((ra>>1)&3))<<3)]);
    }
    #pragma unroll
    for (int nt=0;nt<4;nt++){
      int rb = wn*64+nt*16+rrow;
      bf[nt]=*(const s16x8*)(&Bs[cb][rb*32 + ((ck ^ ((rb>>1)&3))<<3)]);
    }
    #pragma unroll
    for (int mt=0;mt<4;mt++)
      #pragma unroll
      for (int nt=0;nt<4;nt++)
        acc[mt][nt]=__builtin_amdgcn_mfma_f32_16x16x32_bf16(af[mt],bf[nt],acc[mt][nt],0,0,0);
    __syncthreads();
  }
#undef GSTAGE
  // epilogue
  #pragma unroll
  for (int mt=0;mt<4;mt++){
    #pragma unroll
    for (int nt=0;nt<4;nt++){
      int nglob = col0 + wn*64 + nt*16 + (l&15);
      if (nglob >= Nlim) continue;
      #pragma unroll
      for (int rg=0;rg<4;rg++){
        int mrow = m0 + wm*64 + mt*16 + ((l>>4)<<2) + rg;
        float val = acc[mt][nt][rg];
        if (outMode==0){
          outF[(size_t)mrow*ldc + nglob] = val;
        } else if (outMode==1){          // r bf16 -> SEQ slot 0
          int b=mrow>>10, t=mrow&1023, h=nglob>>6, i=nglob&63;
          char* cbase = SEQc + (size_t)((b*16+h)*64 + (t>>4))*24576 + (size_t)(t&15)*896;
          *(u16*)(cbase + i*2) = f2bf(val);
        } else if (outMode==2){          // decay f32 -> SEQ slot 5
          float w = bias[nglob] + val;
          float d = expf(-expf(w));
          int b=mrow>>10, t=mrow&1023, h=nglob>>6, i=nglob&63;
          char* cbase = SEQc + (size_t)((b*16+h)*64 + (t>>4))*24576 + (size_t)(t&15)*896;
          *(float*)(cbase + 640 + i*4) = d;
        } else if (outMode==3){          // sigmoid(bias+acc)
          float s = 1.0f/(1.0f+__expf(-(bias[nglob]+val)));
          outF[(size_t)mrow*ldc + nglob] = s;
        } else {                          // fused stage-1 activation -> UB bf16
          float a = (nglob<64) ? tanhf(val)
                  : (nglob<160) ? val
                  : 1.0f/(1.0f+__expf(-val));
          UBp[(size_t)mrow*384 + nglob] = f2bf(a);
        }
      }
    }
  }
}

// ---------------- prep2: build SEQ slots k,v,a,b (bf16) + dp + VEPI ----------------
__global__ __launch_bounds__(256) void prep2_kernel(char* ws, const float* vfirst,
  const float* kk_s, const float* ka_s, const float* rkw)
{
  const float* KQF=(const float*)(ws+OFF_KQF);
  const float* VQF=(const float*)(ws+OFF_VQF);
  const float* ICLR=(const float*)(ws+OFF_S2A);
  const float* VMIX=(const float*)(ws+OFF_S2V);
  u16* VEPI=(u16*)(ws+OFF_VEPI);
  float* DPp=(float*)(ws+OFF_DP);
  int m=blockIdx.x, b=m>>10, t=m&1023;
  int tid=threadIdx.x, c0=tid*4, h=c0>>6, i0=c0&63, hk=h>>1;
  f32x4 kq=*(const f32x4*)(KQF+(size_t)m*512+hk*64+i0);
  f32x4 vq=*(const f32x4*)(VQF+(size_t)m*512+hk*64+i0);
  f32x4 ic=*(const f32x4*)(ICLR+(size_t)m*1024+c0);
  f32x4 vm=*(const f32x4*)(VMIX+(size_t)m*1024+c0);
  f32x4 vf=*(const f32x4*)(vfirst+(size_t)m*1024+c0);
  f32x4 kkc=*(const f32x4*)(kk_s+c0);
  f32x4 kac=*(const f32x4*)(ka_s+c0);
  f32x4 kk=kq*kkc;
  float ssq=kk[0]*kk[0]+kk[1]*kk[1]+kk[2]*kk[2]+kk[3]*kk[3];
  #pragma unroll
  for (int mk=1;mk<16;mk<<=1) ssq += __shfl_xor(ssq,mk);
  float scale = 1.0f / fmaxf(sqrtf(ssq), 1e-12f);
  int bh=b*16+h;
  char* cb = ws + OFF_SEQ + (size_t)(bh*64+(t>>4))*24576 + (size_t)(t&15)*896;
  u16x4 rv = *(const u16x4*)(cb + (size_t)i0*2);
  f32x4 rkv = *(const f32x4*)(rkw + h*64 + i0);
  f32x4 kf,vv,av,bv;
  float dpp=0.f;
  #pragma unroll
  for (int j=0;j<4;j++){
    float icc = 1.0f + (ic[j]-1.0f)*kac[j];
    float kkn = kk[j]*scale;
    kf[j]=kq[j]*icc;
    vv[j]=vq[j] + (vf[j]-vq[j])*vm[j];
    av[j]=-kkn;
    bv[j]=kkn*icc;
    dpp += bf2f(rv[j])*kf[j]*rkv[j];
  }
  #pragma unroll
  for (int mk=1;mk<16;mk<<=1) dpp += __shfl_xor(dpp,mk);
  if ((tid&15)==0) DPp[(size_t)bh*1024 + t] = dpp;
  i32x2 o;
  o[0]=pk2(kf[0],kf[1]); o[1]=pk2(kf[2],kf[3]);
  *(i32x2*)(cb + 128 + (size_t)i0*2) = o;
  o[0]=pk2(vv[0],vv[1]); o[1]=pk2(vv[2],vv[3]);
  *(i32x2*)(cb + 256 + (size_t)i0*2) = o;
  *(i32x2*)(VEPI + ((size_t)bh*1024+t)*64 + i0) = o;
  o[0]=pk2(av[0],av[1]); o[1]=pk2(av[2],av[3]);
  *(i32x2*)(cb + 384 + (size_t)i0*2) = o;
  o[0]=pk2(bv[0],bv[1]); o[1]=pk2(bv[2],bv[3]);
  *(i32x2*)(cb + 512 + (size_t)i0*2) = o;
}

#define MFMA32(a,b,c) __builtin_amdgcn_mfma_f32_16x16x32_bf16(a,b,c,0,0,0)

// ---------------- precompute: per-chunk S-independent record (2048-way parallel) ------
__global__ __launch_bounds__(64) void pre_kernel(char* ws){
  int bid=blockIdx.x;
  int l=threadIdx.x, c16=l&15, g=l>>4;
  char* chunk = ws + OFF_SEQ + (size_t)bid*24576;
  char* rec = chunk;

  __shared__ __align__(16) char SH[31776];
  u16* AT =(u16*)(SH+14336);
  u16* RT =(u16*)(SH+16640);
  u16* BT =(u16*)(SH+18944);
  u16* KT =(u16*)(SH+21248);
  u16* vbb=(u16*)(SH+23552);
  u16* BKL=(u16*)(SH+26656);
  // overlay region (valid after column pass)
  float* WN  =(float*)(SH+0);
  u16* WY =(u16*)(SH+1088);
  u16* WB =(u16*)(SH+1888);
  u16* WK =(u16*)(SH+2688);
  u16* pbb=(u16*)(SH+3488);
  u16* zbb=(u16*)(SH+6592);
  float* rhsb=(float*)(SH+9696);
  float* gtmp=(float*)(SH+9696);   // overlays rhsb (disjoint lifetime)
  const s16x8 zero8 = {0,0,0,0,0,0,0,0};
  const f32x4 zf4 = {0.f,0.f,0.f,0.f};

  // ---- stage chunk payload (14336B, linear) ----
  #pragma unroll
  for (int q=0;q<14;q++)
    gload_lds16((const float*)(chunk + (size_t)q*1024) + l*4, (float*)(SH + q*1024));
  asm volatile("s_waitcnt vmcnt(0)" ::: "memory");
  __builtin_amdgcn_sched_barrier(0);

  // ---- column pass: lane = channel l ----
  float ptv[16]; float pp=1.f;
  #pragma unroll
  for (int t=0;t<16;t++){ pp *= *(const float*)(SH + t*896 + 640 + l*4); ptv[t]=pp; }
  float pL = ptv[15];
  *(float*)(rec + 10240 + (size_t)l*4) = pL;
  float rpL = __builtin_amdgcn_rcpf(pL);
  float bs[16], ks[16];
  u16 vcol[16];
  #pragma unroll
  for (int t=0;t<16;t++){
    float sc = pL * __builtin_amdgcn_rcpf(ptv[t]);
    bs[t] = bf2f(*(const u16*)(SH + t*896 + 512 + l*2)) * sc;
    ks[t] = bf2f(*(const u16*)(SH + t*896 + 128 + l*2)) * sc;
    vcol[t] = *(const u16*)(SH + t*896 + 256 + l*2);
  }
  {
    i32x4 o;
    o[0]=(int)((unsigned)vcol[0]|((unsigned)vcol[1]<<16));
    o[1]=(int)((unsigned)vcol[2]|((unsigned)vcol[3]<<16));
    o[2]=(int)((unsigned)vcol[4]|((unsigned)vcol[5]<<16));
    o[3]=(int)((unsigned)vcol[6]|((unsigned)vcol[7]<<16));
    *(i32x4*)(&vbb[l*24]) = o;
    o[0]=(int)((unsigned)vcol[8]|((unsigned)vcol[9]<<16));
    o[1]=(int)((unsigned)vcol[10]|((unsigned)vcol[11]<<16));
    o[2]=(int)((unsigned)vcol[12]|((unsigned)vcol[13]<<16));
    o[3]=(int)((unsigned)vcol[14]|((unsigned)vcol[15]<<16));
    *(i32x4*)(&vbb[l*24+8]) = o;
    o[0]=pk2(bs[0],bs[1]); o[1]=pk2(bs[2],bs[3]); o[2]=pk2(bs[4],bs[5]); o[3]=pk2(bs[6],bs[7]);
    *(i32x4*)(&BKL[l*40]) = o;
    o[0]=pk2(bs[8],bs[9]); o[1]=pk2(bs[10],bs[11]); o[2]=pk2(bs[12],bs[13]); o[3]=pk2(bs[14],bs[15]);
    *(i32x4*)(&BKL[l*40+8]) = o;
    o[0]=pk2(ks[0],ks[1]); o[1]=pk2(ks[2],ks[3]); o[2]=pk2(ks[4],ks[5]); o[3]=pk2(ks[6],ks[7]);
    *(i32x4*)(&BKL[l*40+16]) = o;
    o[0]=pk2(ks[8],ks[9]); o[1]=pk2(ks[10],ks[11]); o[2]=pk2(ks[12],ks[13]); o[3]=pk2(ks[14],ks[15]);
    *(i32x4*)(&BKL[l*40+24]) = o;
  }
  #pragma unroll
  for (int t=0;t<16;t++){
    float at = bf2f(*(const u16*)(SH + t*896 + 384 + l*2));
    float rt = bf2f(*(const u16*)(SH + t*896 +   0 + l*2));
    float pprev = (t==0) ? 1.f : ptv[t-1];
    AT[t*72+l] = f2bf(pprev*at);
    RT[t*72+l] = f2bf(ptv[t]*rt);
    BT[t*72+l] = f2bf(bs[t]*rpL);
    KT[t*72+l] = f2bf(ks[t]*rpL);
  }
  asm volatile("s_waitcnt lgkmcnt(0)" ::: "memory");
  __builtin_amdgcn_sched_barrier(0);

  // ---- W-block: N, Yhat, Tb, Tk ----
  {
    s16x8 afA[2], afR[2], bfB[2], bfK[2];
    #pragma unroll
    for (int Kt=0;Kt<2;Kt++){
      afA[Kt]=*(const s16x8*)(&AT[c16*72 + 32*Kt + 8*g]);
      afR[Kt]=*(const s16x8*)(&RT[c16*72 + 32*Kt + 8*g]);
      bfB[Kt]=*(const s16x8*)(&BT[c16*72 + 32*Kt + 8*g]);
      bfK[Kt]=*(const s16x8*)(&KT[c16*72 + 32*Kt + 8*g]);
    }
    f32x4 dNN=zf4, dNY=zf4, dBB=zf4, dBK=zf4;
    #pragma unroll
    for (int Kt=0;Kt<2;Kt++){
      dNN=MFMA32(afA[Kt],bfB[Kt],dNN);
      dNY=MFMA32(afA[Kt],bfK[Kt],dNY);
      dBB=MFMA32(afR[Kt],bfB[Kt],dBB);
      dBK=MFMA32(afR[Kt],bfK[Kt],dBK);
    }
    #pragma unroll
    for (int e=0;e<4;e++){
      int tR=4*g+e, sC=c16;
      WN[tR*17+sC] = dNN[e];
      WY[tR*24+sC] = (sC<tR)? f2bf(dNY[e]) : (u16)0;
      WB[tR*24+sC] = (sC<=tR)? f2bf(dBB[e]) : (u16)0;
      WK[tR*24+sC] = (sC<=tR)? f2bf(dBK[e]) : (u16)0;
    }
  }

  // ---- YhatV -> rhsb ----
  s16x8 vf[4];
  #pragma unroll
  for (int J=0;J<4;J++){
    vf[J]=zero8;
    if (g<2) vf[J]=*(const s16x8*)(&vbb[(16*J+c16)*24 + 8*g]);
  }
  {
    s16x8 wyf=zero8;
    if (g<2) wyf=*(const s16x8*)(&WY[c16*24 + 8*g]);
    f32x4 dR[4];
    #pragma unroll
    for (int J=0;J<4;J++){
      dR[J]=zf4;
      dR[J]=MFMA32(wyf,vf[J],dR[J]);
      #pragma unroll
      for (int e=0;e<4;e++)
        rhsb[(4*g+e)*68 + 16*J + c16] = dR[J][e];
    }
  }

  // ---- P-solve: (I-N)P = Atil, lane = column j=l ----
  {
    float pv[16];
    #pragma unroll
    for (int t=0;t<16;t++) pv[t]=bf2f(AT[t*72+l]);
    #pragma unroll
    for (int t=1;t<16;t++)
      #pragma unroll
      for (int s=0;s<16;s++){
        if (s<t) pv[t] += WN[t*17+s]*pv[s];
      }
    i32x4 o;
    o[0]=pk2(pv[0],pv[1]); o[1]=pk2(pv[2],pv[3]); o[2]=pk2(pv[4],pv[5]); o[3]=pk2(pv[6],pv[7]);
    *(i32x4*)(&pbb[l*24]) = o;
    o[0]=pk2(pv[8],pv[9]); o[1]=pk2(pv[10],pv[11]); o[2]=pk2(pv[12],pv[13]); o[3]=pk2(pv[14],pv[15]);
    *(i32x4*)(&pbb[l*24+8]) = o;
  }

  // ---- z-solve: (I-N)zloc = YhatV, lane = column i=l ----
  {
    float zz[16];
    #pragma unroll
    for (int t=0;t<16;t++) zz[t]=rhsb[t*68+l];
    #pragma unroll
    for (int t=1;t<16;t++)
      #pragma unroll
      for (int s=0;s<16;s++){
        if (s<t) zz[t] += WN[t*17+s]*zz[s];
      }
    i32x4 o;
    o[0]=pk2(zz[0],zz[1]); o[1]=pk2(zz[2],zz[3]); o[2]=pk2(zz[4],zz[5]); o[3]=pk2(zz[6],zz[7]);
    *(i32x4*)(&zbb[l*24]) = o;
    o[0]=pk2(zz[8],zz[9]); o[1]=pk2(zz[10],zz[11]); o[2]=pk2(zz[12],zz[13]); o[3]=pk2(zz[14],zz[15]);
    *(i32x4*)(&zbb[l*24+8]) = o;
  }
  asm volatile("s_waitcnt lgkmcnt(0)" ::: "memory");
  __builtin_amdgcn_sched_barrier(0);

  // ---- G = Rtil + Tb*P -> gtmp ; Yloc = Tb*zloc + Tk*V -> record strips ----
  {
    s16x8 wbf=zero8, wkf=zero8;
    if (g<2){
      wbf=*(const s16x8*)(&WB[c16*24 + 8*g]);
      wkf=*(const s16x8*)(&WK[c16*24 + 8*g]);
    }
    #pragma unroll
    for (int J=0;J<4;J++){
      s16x8 pfB=zero8, zfB=zero8;
      if (g<2){
        pfB=*(const s16x8*)(&pbb[(16*J+c16)*24 + 8*g]);
        zfB=*(const s16x8*)(&zbb[(16*J+c16)*24 + 8*g]);
      }
      f32x4 dG, dYl=zf4;
      #pragma unroll
      for (int e=0;e<4;e++) dG[e]=bf2f(RT[(4*g+e)*72 + 16*J + c16]);
      dG=MFMA32(wbf,pfB,dG);
      dYl=MFMA32(wbf,zfB,dYl);
      dYl=MFMA32(wkf,vf[J],dYl);
      #pragma unroll
      for (int e=0;e<4;e++) gtmp[(4*g+e)*68 + 16*J + c16]=dG[e];
      i32x2 o2; o2[0]=pk2(dYl[0],dYl[1]); o2[1]=pk2(dYl[2],dYl[3]);
      *(i32x2*)(rec + 10496 + (size_t)J*2560 + 2048 + (size_t)l*8) = o2;
    }
  }

  // ---- Q = P^T [Bbar;Kbar] tiles -> record Q A-frags; c = [Bbar;Kbar]^T [z;V] ----
  {
    s16x8 bk[4], pfr[4], bzv[4];
    #pragma unroll
    for (int nt=0;nt<4;nt++) bk[nt]=*(const s16x8*)(&BKL[(16*nt+c16)*40 + 8*g]);
    #pragma unroll
    for (int mt=0;mt<4;mt++)
      pfr[mt]= (g<2) ? *(const s16x8*)(&pbb[(16*mt+c16)*24 + 8*g]) : zero8;
    #pragma unroll
    for (int it=0;it<4;it++)
      bzv[it]= (g<2) ? *(const s16x8*)(&zbb[(16*it+c16)*24 + 8*g])
                     : *(const s16x8*)(&vbb[(16*it+c16)*24 + 8*(g-2)]);
    #pragma unroll
    for (int mt=0;mt<4;mt++){
      #pragma unroll
      for (int nt=0;nt<4;nt++){
        f32x4 dQ = MFMA32(pfr[mt], bk[nt], zf4);
        int kk = mt>>1, gq = ((mt&1)<<1) | (g>>1), jo = g&1;
        i32x2 o2; o2[0]=pk2(dQ[0],dQ[1]); o2[1]=pk2(dQ[2],dQ[3]);
        *(i32x2*)(rec + ((size_t)(kk*4+nt)*64 + (size_t)(c16 + 16*gq))*16 + 8*jo) = o2;
      }
    }
    #pragma unroll
    for (int jtp=0;jtp<4;jtp++){
      #pragma unroll
      for (int it=0;it<4;it++){
        f32x4 dc = MFMA32(bk[jtp], bzv[it], zf4);
        i32x2 o2; o2[0]=pk2(dc[0],dc[1]); o2[1]=pk2(dc[2],dc[3]);
        *(i32x2*)(rec + 10496 + (size_t)it*2560 + ((size_t)jtp*64 + l)*8) = o2;
      }
    }
  }

  // ---- G A-frags -> record ----
  #pragma unroll
  for (int kk=0;kk<2;kk++){
    f32x4 b0 = *(const f32x4*)(&gtmp[c16*68 + 32*kk + 8*g]);
    f32x4 b1 = *(const f32x4*)(&gtmp[c16*68 + 32*kk + 8*g + 4]);
    i32x4 o;
    o[0]=pk2(b0[0],b0[1]); o[1]=pk2(b0[2],b0[3]); o[2]=pk2(b1[0],b1[1]); o[3]=pk2(b1[2],b1[3]);
    *(i32x4*)(rec + 8192 + (size_t)(kk*64+l)*16) = o;
  }
}

// ---------------- serial scan v7: register-direct record loads, unroll-2 ----------------
// 1 wave per (bh, i-strip). Record fragments are laid out per-lane, so load them
// straight into VGPRs (global_load_dwordx4) with a 2-deep named double buffer.
__global__ __launch_bounds__(64) void scan2_kernel(char* ws, const float* S0, float* dout){
  float* YB=(float*)(ws+OFF_YBUF);
  const char* recb = ws + OFF_SEQ;
  int bid=blockIdx.x, bh=bid>>2, w=bid&3;
  int l=threadIdx.x, c16=l&15, g=l>>4;

  __shared__ __align__(16) u16 ST[16*88];

  f32x4 Sreg[4];
  #pragma unroll
  for (int jt=0;jt<4;jt++)
    Sreg[jt] = *(const f32x4*)(S0 + (size_t)bh*4096 + (size_t)(16*w+c16)*64 + 16*jt + 4*g);
  #pragma unroll
  for (int jt=0;jt<4;jt++){
    i32x2 p; p[0]=pk2(Sreg[jt][0],Sreg[jt][1]); p[1]=pk2(Sreg[jt][2],Sreg[jt][3]);
    *(i32x2*)(&ST[c16*88 + 16*jt + 4*g]) = p;
  }

  const char* rb = recb + (size_t)(bh*64)*24576;
  float* yb0 = YB + (size_t)bh*65536;

#define DECLR(S) s16x8 qf##S[8]; s16x8 gf##S[2]; f32x4 pl##S[4]; i32x2 cf##S[4]; i32x2 yl##S;
#define LOADR(S, nc) do{ \
    const char* rp_ = rb + (size_t)(nc)*24576; \
    _Pragma("unroll") \
    for (int q_=0;q_<8;q_++) qf##S[q_] = *(const s16x8*)(rp_ + (size_t)q_*1024 + l*16); \
    gf##S[0] = *(const s16x8*)(rp_ + 8192 + (size_t)l*16); \
    gf##S[1] = *(const s16x8*)(rp_ + 9216 + (size_t)l*16); \
    _Pragma("unroll") \
    for (int jt_=0;jt_<4;jt_++) pl##S[jt_] = *(const f32x4*)(rp_ + 10240 + (size_t)(16*jt_+4*g)*4); \
    _Pragma("unroll") \
    for (int jt_=0;jt_<4;jt_++) cf##S[jt_] = *(const i32x2*)(rp_ + 10496 + (size_t)w*2560 + (size_t)(jt_*64+l)*8); \
    yl##S = *(const i32x2*)(rp_ + 10496 + (size_t)w*2560 + 2048 + (size_t)l*8); \
  }while(0)
#define STEP(S, ch) do{ \
    s16x8 sB0=*(const s16x8*)(&ST[c16*88 + 8*g]); \
    s16x8 sB1=*(const s16x8*)(&ST[c16*88 + 32 + 8*g]); \
    f32x4 dy=cvt4(yl##S); \
    dy=MFMA32(gf##S[0],sB0,dy); dy=MFMA32(gf##S[1],sB1,dy); \
    _Pragma("unroll") \
    for (int jt_=0;jt_<4;jt_++){ \
      f32x4 acc = cvt4(cf##S[jt_]); \
      acc = MFMA32(qf##S[jt_], sB0, acc); \
      acc = MFMA32(qf##S[4+jt_], sB1, acc); \
      _Pragma("unroll") \
      for (int e_=0;e_<4;e_++) acc[e_] = fmaf(pl##S[jt_][e_], Sreg[jt_][e_], acc[e_]); \
      Sreg[jt_]=acc; \
    } \
    _Pragma("unroll") \
    for (int jt_=0;jt_<4;jt_++){ \
      i32x2 p_; p_[0]=cvtpk(Sreg[jt_][0],Sreg[jt_][1]); p_[1]=cvtpk(Sreg[jt_][2],Sreg[jt_][3]); \
      *(i32x2*)(&ST[c16*88 + 16*jt_ + 4*g]) = p_; \
    } \
    { float* yb_ = yb0 + (size_t)(ch)*1024; \
      _Pragma("unroll") \
      for (int e_=0;e_<4;e_++) yb_[(size_t)(4*g+e_)*64 + 16*w + c16] = dy[e_]; } \
  }while(0)

  DECLR(A); DECLR(B);
  LOADR(A, 0);
  LOADR(B, 1);

  #pragma unroll 1
  for (int ch=0; ch<64; ch+=2){
    STEP(A, ch);
    { int nc = ch+2; if (nc>63) nc=63; LOADR(A, nc); }
    STEP(B, ch+1);
    { int nc = ch+3; if (nc>63) nc=63; LOADR(B, nc); }
  }
#undef DECLR
#undef LOADR
#undef STEP

  #pragma unroll
  for (int jt=0;jt<4;jt++)
    *(f32x4*)(dout + 2097152 + (size_t)bh*4096 + (size_t)(16*w+c16)*64 + 16*jt + 4*g) = Sreg[jt];
}

// ---------------- epilogue: groupnorm + bonus + gate -> bf16 ----------------
__global__ __launch_bounds__(256) void epi_kernel(char* ws, const float* lnw, const float* lnb)
{
  const float* YB=(const float*)(ws+OFF_YBUF);
  const u16* VEPI=(const u16*)(ws+OFF_VEPI);
  const float* DPp=(const float*)(ws+OFF_DP);
  const float* GB=(const float*)(ws+OFF_GBUF);
  u16* XGB=(u16*)(ws+OFF_XGB);
  int m=blockIdx.x, b=m>>10, t=m&1023;
  int tid=threadIdx.x, c0=tid*4, h=c0>>6, i0=c0&63;
  f32x4 y=*(const f32x4*)(YB + ((size_t)(b*16+h)*1024+t)*64 + i0);
  float s = y[0]+y[1]+y[2]+y[3];
  float ss= y[0]*y[0]+y[1]*y[1]+y[2]*y[2]+y[3]*y[3];
  #pragma unroll
  for (int mk=1;mk<16;mk<<=1){ s+=__shfl_xor(s,mk); ss+=__shfl_xor(ss,mk); }
  float mu=s*(1.0f/64.0f), var=ss*(1.0f/64.0f)-mu*mu;
  float inv=rsqrtf(var + 6.4e-4f);
  u16x4 v16=*(const u16x4*)(VEPI + ((size_t)(b*16+h)*1024+t)*64 + i0);
  float dp = DPp[(size_t)(b*16+h)*1024 + t];
  f32x4 gg=*(const f32x4*)(GB+(size_t)m*1024+c0);
  u16x4 outv;
  #pragma unroll
  for (int j=0;j<4;j++){
    float xn = (y[j]-mu)*inv*lnw[c0+j] + lnb[c0+j] + dp*bf2f(v16[j]);
    outv[j]=f2bf(xn*gg[j]);
  }
  *(u16x4*)(XGB+(size_t)m*1024+c0)=outv;
}

extern "C" void kernel_launch(void* const* d_in, const int* in_sizes, int n_in,
                              void* d_out, int out_size, void* d_ws, size_t ws_size,
                              hipStream_t stream) {
  const float* x      =(const float*)d_in[0];
  const float* S0     =(const float*)d_in[1];
  const float* vfirst =(const float*)d_in[2];
  const float* w0     =(const float*)d_in[3];
  const float* w1     =(const float*)d_in[4];
  const float* w2     =(const float*)d_in[5];
  const float* a0     =(const float*)d_in[6];
  const float* a1     =(const float*)d_in[7];
  const float* a2     =(const float*)d_in[8];
  const float* v0     =(const float*)d_in[9];
  const float* v1     =(const float*)d_in[10];
  const float* v2     =(const float*)d_in[11];
  const float* g1     =(const float*)d_in[12];
  const float* g2     =(const float*)d_in[13];
  const float* k_k    =(const float*)d_in[14];
  const float* k_a    =(const float*)d_in[15];
  const float* r_k    =(const float*)d_in[16];
  const float* Wq     =(const float*)d_in[17];
  const float* Wk     =(const float*)d_in[18];
  const float* Wv     =(const float*)d_in[19];
  const float* Wo     =(const float*)d_in[20];
  const float* ln_w   =(const float*)d_in[21];
  const float* ln_b   =(const float*)d_in[22];
  char* ws=(char*)d_ws;
  float* dout=(float*)d_out;

  prep_kernel<<<2048,256,0,stream>>>(ws,x,vfirst,w1,w2,a1,a2,v1,v2,g1,g2,Wq,Wk,Wv,Wo,dout);
  gemm_kernel<<<dim3(16,19),256,0,stream>>>(0,ws,w0,a0,v0,dout);
  gemm_kernel<<<dim3(16,32),256,0,stream>>>(1,ws,w0,a0,v0,dout);
  prep2_kernel<<<2048,256,0,stream>>>(ws,vfirst,k_k,k_a,r_k);
  pre_kernel<<<2048,64,0,stream>>>(ws);
  scan2_kernel<<<128,64,0,stream>>>(ws,S0,dout);
  epi_kernel<<<2048,256,0,stream>>>(ws,ln_w,ln_b);
  gemm_kernel<<<dim3(16,8),256,0,stream>>>(2,ws,w0,a0,v0,dout);
}

// Round 13
// 159.531 us; speedup vs baseline: 1.4885x; 1.2246x over previous
//
#include <hip/hip_runtime.h>

typedef unsigned short u16;
typedef __attribute__((ext_vector_type(8))) short s16x8;
typedef __attribute__((ext_vector_type(4))) float f32x4;
typedef __attribute__((ext_vector_type(4))) int   i32x4;
typedef __attribute__((ext_vector_type(2))) int   i32x2;
typedef __attribute__((ext_vector_type(4))) unsigned short u16x4;

// ---------------- workspace layout (bytes) ----------------
constexpr size_t OFF_XB   = 0;                     // bf16 x [2048][1024]; later VEPI
constexpr size_t OFF_WQB  = OFF_XB   + 4194304;    // bf16 Wq         [1024][1024]
constexpr size_t OFF_WKB  = OFF_WQB  + 2097152;    // bf16 Wk         [512][1024]
constexpr size_t OFF_WVB  = OFF_WKB  + 1048576;    // bf16 Wv         [512][1024]
constexpr size_t OFF_WOB  = OFF_WVB  + 1048576;    // bf16 Wo         [1024][1024]
constexpr size_t OFF_W1T  = OFF_WOB  + 2097152;    // bf16 W1T [384][1024]; later DP
constexpr size_t OFF_W2T  = OFF_W1T  + 786432;     // bf16 w2T        [1024][64]
constexpr size_t OFF_A2T  = OFF_W2T  + 131072;     // bf16 a2T        [1024][64]
constexpr size_t OFF_V2T  = OFF_A2T  + 131072;     // bf16 v2T        [1024][32]
constexpr size_t OFF_G2T  = OFF_V2T  + 65536;      // bf16 g2T        [1024][160]
constexpr size_t OFF_KQF  = OFF_G2T  + 327680;     // f32 k-proj      [2048][512]
constexpr size_t OFF_VQF  = OFF_KQF  + 4194304;    // f32 v-proj      [2048][512]
constexpr size_t OFF_URAW = OFF_VQF  + 4194304;    // (dead)
constexpr size_t OFF_UB   = OFF_URAW + 2621440;    // bf16 stage1 act [2048][384]
constexpr size_t OFF_S2A  = OFF_UB   + 1572864;    // f32 iclr        [2048][1024]
constexpr size_t OFF_S2V  = OFF_S2A  + 8388608;    // f32 vmix        [2048][1024]
constexpr size_t OFF_GBUF = OFF_S2V  + 8388608;    // f32 gate        [2048][1024]
constexpr size_t OFF_SEQ  = OFF_GBUF + 8388608;    // chunks [2048][24576B]; later records
constexpr size_t OFF_YBUF = OFF_SEQ  + 50331648;   // f32 y   [2][16][1024][64]
constexpr size_t OFF_XGB  = OFF_YBUF + 8388608;    // bf16 xn*g       [2048][1024]

// SEQ chunk payload (first 14336B of each 24576B slot), per t-row stride 896:
//  +0 r bf16[64] | +128 k | +256 v | +384 a | +512 b | +640 decay f32[64]
// record overlay (pre overwrites its OWN chunk): 0 Q(8192) | 8192 G(2048) |
//  10240 pL f32[64] | 10496 + w*2560 { c[jt4][lane]x8B (2048) | Yloc (512) }
constexpr size_t OFF_VEPI = OFF_XB;                // bf16 v rows (XB dead after gemm0)
constexpr size_t OFF_DP   = OFF_W1T;               // f32 dp (W1T dead after gemm0)

__device__ __forceinline__ u16 f2bf(float f){
  unsigned int u = __builtin_bit_cast(unsigned int, f);
  u = u + 0x7fffu + ((u >> 16) & 1u);
  return (u16)(u >> 16);
}
__device__ __forceinline__ int pk2(float a, float b){
  return (int)((unsigned)f2bf(a) | ((unsigned)f2bf(b) << 16));
}
__device__ __forceinline__ int cvtpk(float a, float b){
  int r;
  asm("v_cvt_pk_bf16_f32 %0, %1, %2" : "=v"(r) : "v"(a), "v"(b));
  return r;
}
__device__ __forceinline__ float bf2f(u16 h){
  return __builtin_bit_cast(float, ((unsigned)h) << 16);
}
__device__ __forceinline__ f32x4 cvt4(i32x2 v){
  unsigned a=(unsigned)v[0], b=(unsigned)v[1];
  f32x4 r;
  r[0]=__builtin_bit_cast(float, a<<16);
  r[1]=__builtin_bit_cast(float, a&0xffff0000u);
  r[2]=__builtin_bit_cast(float, b<<16);
  r[3]=__builtin_bit_cast(float, b&0xffff0000u);
  return r;
}

__device__ __forceinline__ void gload_lds16(const float* g, float* l){
  __builtin_amdgcn_global_load_lds((const __attribute__((address_space(1))) void*)g,
                                   (__attribute__((address_space(3))) void*)l, 16, 0, 0);
}
__device__ __forceinline__ void gload_lds16u(const u16* g, u16* l){
  __builtin_amdgcn_global_load_lds((const __attribute__((address_space(1))) void*)g,
                                   (__attribute__((address_space(3))) void*)l, 16, 0, 0);
}
__device__ __forceinline__ void gload_lds4(const float* g, float* l){
  __builtin_amdgcn_global_load_lds((const __attribute__((address_space(1))) void*)g,
                                   (__attribute__((address_space(3))) void*)l, 4, 0, 0);
}

// ---------------- prep: convert/transpose + v_first passthrough ----------------
constexpr size_t N_XB=2097152, N_WQ=1048576, N_WK=524288, N_WV=524288, N_WO=1048576,
  N_W1T=393216, N_W2T=65536, N_A2T=65536, N_V2T=32768, N_G2T=163840, N_VF=2097152;
constexpr size_t PREP_TOT = N_XB+N_WQ+N_WK+N_WV+N_WO+N_W1T+N_W2T+N_A2T+N_V2T+N_G2T+N_VF;

__global__ __launch_bounds__(256) void prep_kernel(char* ws, const float* x, const float* vfirst,
  const float* w1, const float* w2, const float* a1, const float* a2,
  const float* v1, const float* v2, const float* g1, const float* g2,
  const float* Wq, const float* Wk, const float* Wv, const float* Wo, float* dout)
{
  u16* XB=(u16*)(ws+OFF_XB); u16* WQB=(u16*)(ws+OFF_WQB); u16* WKB=(u16*)(ws+OFF_WKB);
  u16* WVB=(u16*)(ws+OFF_WVB); u16* WOB=(u16*)(ws+OFF_WOB); u16* W1T=(u16*)(ws+OFF_W1T);
  u16* W2T=(u16*)(ws+OFF_W2T); u16* A2T=(u16*)(ws+OFF_A2T); u16* V2T=(u16*)(ws+OFF_V2T);
  u16* G2T=(u16*)(ws+OFF_G2T);
  for (size_t idx=(size_t)blockIdx.x*256+threadIdx.x; idx<PREP_TOT; idx+=(size_t)gridDim.x*256){
    size_t r = idx;
    if (r < N_XB){ XB[r]=f2bf(x[r]); continue; } r-=N_XB;
    if (r < N_WQ){ WQB[r]=f2bf(Wq[r]); continue; } r-=N_WQ;
    if (r < N_WK){ WKB[r]=f2bf(Wk[r]); continue; } r-=N_WK;
    if (r < N_WV){ WVB[r]=f2bf(Wv[r]); continue; } r-=N_WV;
    if (r < N_WO){ WOB[r]=f2bf(Wo[r]); continue; } r-=N_WO;
    if (r < N_W1T){
      int n=(int)(r>>10), k=(int)(r&1023); float v=0.f;
      if (n<64) v=w1[(size_t)k*64+n];
      else if (n<128) v=a1[(size_t)k*64+(n-64)];
      else if (n<160) v=v1[(size_t)k*32+(n-128)];
      else if (n<320) v=g1[(size_t)k*160+(n-160)];
      W1T[r]=f2bf(v); continue; } r-=N_W1T;
    if (r < N_W2T){ int c=(int)(r>>6), d=(int)(r&63); W2T[r]=f2bf(w2[(size_t)d*1024+c]); continue; } r-=N_W2T;
    if (r < N_A2T){ int c=(int)(r>>6), d=(int)(r&63); A2T[r]=f2bf(a2[(size_t)d*1024+c]); continue; } r-=N_A2T;
    if (r < N_V2T){ int c=(int)(r>>5), d=(int)(r&31); V2T[r]=f2bf(v2[(size_t)d*1024+c]); continue; } r-=N_V2T;
    if (r < N_G2T){ int c=(int)(r/160), d=(int)(r%160); G2T[r]=f2bf(g2[(size_t)d*1024+c]); continue; } r-=N_G2T;
    dout[2228224 + r] = vfirst[r];   // v_first passthrough (offset 2097152+131072)
  }
}

// ---------------- unified NT bf16 MFMA GEMM: C[m][n] = sum_k A[m][k]*B[n][k] ----------------
// v3: 64x128 tile, 4 waves (2Mx2N, each 32x64, acc[2][4]), LDS 24KB -> up to 6 blocks/CU.
// global_load_lds width-16 staging with XOR chunk swizzle applied on SOURCE + ds_read.
__global__ __launch_bounds__(256) void gemm_kernel(int phase, char* ws,
  const float* w0b, const float* a0b, const float* v0b, float* dout)
{
  const u16* A; const u16* Bw;
  float* outF=nullptr; const float* bias=nullptr;
  char* SEQc=(char*)(ws+OFF_SEQ);
  u16* UBp=(u16*)(ws+OFF_UB);
  int lda=0, ldb=0, K=0, ldc=0, Nlim=1024, col0=0, outMode=0;
  int y = blockIdx.y;
  if (phase==0){
    A=(const u16*)(ws+OFF_XB); lda=1024; K=1024;
    if (y<8)      { Bw=(const u16*)(ws+OFF_WQB); ldb=1024; col0=y*128;       outMode=1; }
    else if (y<12){ Bw=(const u16*)(ws+OFF_WKB); ldb=1024; col0=(y-8)*128;   outF=(float*)(ws+OFF_KQF); ldc=512; Nlim=512; }
    else if (y<16){ Bw=(const u16*)(ws+OFF_WVB); ldb=1024; col0=(y-12)*128;  outF=(float*)(ws+OFF_VQF); ldc=512; Nlim=512; }
    else          { Bw=(const u16*)(ws+OFF_W1T); ldb=1024; col0=(y-16)*128;  outMode=4; Nlim=320; }
  } else if (phase==1){
    int seg=y>>3; col0=(y&7)*128;
    const int Ks[4]={64,64,32,160};
    const int Ao[4]={0,64,128,160};
    K=Ks[seg]; lda=384; ldb=K;
    A=(const u16*)(ws+OFF_UB) + Ao[seg];
    if (seg==0)     { Bw=(const u16*)(ws+OFF_W2T); outMode=2; bias=w0b; }
    else if (seg==1){ Bw=(const u16*)(ws+OFF_A2T); outMode=3; bias=a0b; outF=(float*)(ws+OFF_S2A); ldc=1024; }
    else if (seg==2){ Bw=(const u16*)(ws+OFF_V2T); outMode=3; bias=v0b; outF=(float*)(ws+OFF_S2V); ldc=1024; }
    else            { Bw=(const u16*)(ws+OFF_G2T); outF=(float*)(ws+OFF_GBUF); ldc=1024; }
  } else {
    A=(const u16*)(ws+OFF_XGB); lda=1024; K=1024;
    Bw=(const u16*)(ws+OFF_WOB); ldb=1024; col0=y*128; outF=dout; ldc=1024;
  }
  int m0 = blockIdx.x*64;
  __shared__ __align__(16) u16 As[2][2048];   // 64 x 32
  __shared__ __align__(16) u16 Bs[2][4096];   // 128 x 32
  int tid=threadIdx.x, l=tid&63, wv=tid>>6, wm=wv>>1, wn=wv&1;

  // staging: wave wv stages A rows [wv*16,wv*16+16) (1 load) and B rows [wv*32,wv*32+32) (2).
  int cswz = (l&3) ^ ((l>>3)&3);        // (row>>1)&3 reduces to ((l>>2)>>1)&3 for all waves
  int srA = wv*16 + (l>>2);
  int srB = wv*32 + (l>>2);
  const u16* aP0 = A  + (size_t)(m0+srA)*lda       + cswz*8;
  const u16* bP0 = Bw + (size_t)(col0+srB)*ldb     + cswz*8;
  const u16* bP1 = Bw + (size_t)(col0+srB+16)*ldb  + cswz*8;

  f32x4 acc[2][4];
  #pragma unroll
  for (int i=0;i<2;i++)
    #pragma unroll
    for (int j=0;j<4;j++) acc[i][j]=(f32x4){0.f,0.f,0.f,0.f};

#define GSTAGE(b,k0) do{                                   \
    gload_lds16u(aP0 + (k0), &As[b][wv*512]);              \
    gload_lds16u(bP0 + (k0), &Bs[b][wv*1024]);             \
    gload_lds16u(bP1 + (k0), &Bs[b][wv*1024+512]);         \
  }while(0)

  GSTAGE(0,0);
  asm volatile("s_waitcnt vmcnt(0)" ::: "memory");
  __syncthreads();

  int rrow=l&15, ck=l>>4;
  for (int k0=0;k0<K;k0+=32){
    int cb=(k0>>5)&1;
    if (k0+32<K) GSTAGE(cb^1, k0+32);
    s16x8 af[2], bf[4];
    #pragma unroll
    for (int mt=0;mt<2;mt++){
      int ra = wm*32+mt*16+rrow;
      af[mt]=*(const s16x8*)(&As[cb][ra*32 + ((ck ^ ((ra>>1)&3))<<3)]);
    }
    #pragma unroll
    for (int nt=0;nt<4;nt++){
      int rb = wn*64+nt*16+rrow;
      bf[nt]=*(const s16x8*)(&Bs[cb][rb*32 + ((ck ^ ((rb>>1)&3))<<3)]);
    }
    #pragma unroll
    for (int mt=0;mt<2;mt++)
      #pragma unroll
      for (int nt=0;nt<4;nt++)
        acc[mt][nt]=__builtin_amdgcn_mfma_f32_16x16x32_bf16(af[mt],bf[nt],acc[mt][nt],0,0,0);
    __syncthreads();
  }
#undef GSTAGE
  // epilogue
  #pragma unroll
  for (int mt=0;mt<2;mt++){
    #pragma unroll
    for (int nt=0;nt<4;nt++){
      int nglob = col0 + wn*64 + nt*16 + (l&15);
      if (nglob >= Nlim) continue;
      #pragma unroll
      for (int rg=0;rg<4;rg++){
        int mrow = m0 + wm*32 + mt*16 + ((l>>4)<<2) + rg;
        float val = acc[mt][nt][rg];
        if (outMode==0){
          outF[(size_t)mrow*ldc + nglob] = val;
        } else if (outMode==1){          // r bf16 -> SEQ slot 0
          int b=mrow>>10, t=mrow&1023, h=nglob>>6, i=nglob&63;
          char* cbase = SEQc + (size_t)((b*16+h)*64 + (t>>4))*24576 + (size_t)(t&15)*896;
          *(u16*)(cbase + i*2) = f2bf(val);
        } else if (outMode==2){          // decay f32 -> SEQ slot 5
          float w = bias[nglob] + val;
          float d = expf(-expf(w));
          int b=mrow>>10, t=mrow&1023, h=nglob>>6, i=nglob&63;
          char* cbase = SEQc + (size_t)((b*16+h)*64 + (t>>4))*24576 + (size_t)(t&15)*896;
          *(float*)(cbase + 640 + i*4) = d;
        } else if (outMode==3){          // sigmoid(bias+acc)
          float s = 1.0f/(1.0f+__expf(-(bias[nglob]+val)));
          outF[(size_t)mrow*ldc + nglob] = s;
        } else {                          // fused stage-1 activation -> UB bf16
          float a = (nglob<64) ? tanhf(val)
                  : (nglob<160) ? val
                  : 1.0f/(1.0f+__expf(-val));
          UBp[(size_t)mrow*384 + nglob] = f2bf(a);
        }
      }
    }
  }
}

// ---------------- prep2: build SEQ slots k,v,a,b (bf16) + dp + VEPI ----------------
__global__ __launch_bounds__(256) void prep2_kernel(char* ws, const float* vfirst,
  const float* kk_s, const float* ka_s, const float* rkw)
{
  const float* KQF=(const float*)(ws+OFF_KQF);
  const float* VQF=(const float*)(ws+OFF_VQF);
  const float* ICLR=(const float*)(ws+OFF_S2A);
  const float* VMIX=(const float*)(ws+OFF_S2V);
  u16* VEPI=(u16*)(ws+OFF_VEPI);
  float* DPp=(float*)(ws+OFF_DP);
  int m=blockIdx.x, b=m>>10, t=m&1023;
  int tid=threadIdx.x, c0=tid*4, h=c0>>6, i0=c0&63, hk=h>>1;
  f32x4 kq=*(const f32x4*)(KQF+(size_t)m*512+hk*64+i0);
  f32x4 vq=*(const f32x4*)(VQF+(size_t)m*512+hk*64+i0);
  f32x4 ic=*(const f32x4*)(ICLR+(size_t)m*1024+c0);
  f32x4 vm=*(const f32x4*)(VMIX+(size_t)m*1024+c0);
  f32x4 vf=*(const f32x4*)(vfirst+(size_t)m*1024+c0);
  f32x4 kkc=*(const f32x4*)(kk_s+c0);
  f32x4 kac=*(const f32x4*)(ka_s+c0);
  f32x4 kk=kq*kkc;
  float ssq=kk[0]*kk[0]+kk[1]*kk[1]+kk[2]*kk[2]+kk[3]*kk[3];
  #pragma unroll
  for (int mk=1;mk<16;mk<<=1) ssq += __shfl_xor(ssq,mk);
  float scale = 1.0f / fmaxf(sqrtf(ssq), 1e-12f);
  int bh=b*16+h;
  char* cb = ws + OFF_SEQ + (size_t)(bh*64+(t>>4))*24576 + (size_t)(t&15)*896;
  u16x4 rv = *(const u16x4*)(cb + (size_t)i0*2);
  f32x4 rkv = *(const f32x4*)(rkw + h*64 + i0);
  f32x4 kf,vv,av,bv;
  float dpp=0.f;
  #pragma unroll
  for (int j=0;j<4;j++){
    float icc = 1.0f + (ic[j]-1.0f)*kac[j];
    float kkn = kk[j]*scale;
    kf[j]=kq[j]*icc;
    vv[j]=vq[j] + (vf[j]-vq[j])*vm[j];
    av[j]=-kkn;
    bv[j]=kkn*icc;
    dpp += bf2f(rv[j])*kf[j]*rkv[j];
  }
  #pragma unroll
  for (int mk=1;mk<16;mk<<=1) dpp += __shfl_xor(dpp,mk);
  if ((tid&15)==0) DPp[(size_t)bh*1024 + t] = dpp;
  i32x2 o;
  o[0]=pk2(kf[0],kf[1]); o[1]=pk2(kf[2],kf[3]);
  *(i32x2*)(cb + 128 + (size_t)i0*2) = o;
  o[0]=pk2(vv[0],vv[1]); o[1]=pk2(vv[2],vv[3]);
  *(i32x2*)(cb + 256 + (size_t)i0*2) = o;
  *(i32x2*)(VEPI + ((size_t)bh*1024+t)*64 + i0) = o;
  o[0]=pk2(av[0],av[1]); o[1]=pk2(av[2],av[3]);
  *(i32x2*)(cb + 384 + (size_t)i0*2) = o;
  o[0]=pk2(bv[0],bv[1]); o[1]=pk2(bv[2],bv[3]);
  *(i32x2*)(cb + 512 + (size_t)i0*2) = o;
}

#define MFMA32(a,b,c) __builtin_amdgcn_mfma_f32_16x16x32_bf16(a,b,c,0,0,0)

// ---------------- precompute: per-chunk S-independent record (2048-way parallel) ------
__global__ __launch_bounds__(64) void pre_kernel(char* ws){
  int bid=blockIdx.x;
  int l=threadIdx.x, c16=l&15, g=l>>4;
  char* chunk = ws + OFF_SEQ + (size_t)bid*24576;
  char* rec = chunk;

  __shared__ __align__(16) char SH[31776];
  u16* AT =(u16*)(SH+14336);
  u16* RT =(u16*)(SH+16640);
  u16* BT =(u16*)(SH+18944);
  u16* KT =(u16*)(SH+21248);
  u16* vbb=(u16*)(SH+23552);
  u16* BKL=(u16*)(SH+26656);
  // overlay region (valid after column pass)
  float* WN  =(float*)(SH+0);
  u16* WY =(u16*)(SH+1088);
  u16* WB =(u16*)(SH+1888);
  u16* WK =(u16*)(SH+2688);
  u16* pbb=(u16*)(SH+3488);
  u16* zbb=(u16*)(SH+6592);
  float* rhsb=(float*)(SH+9696);
  float* gtmp=(float*)(SH+9696);   // overlays rhsb (disjoint lifetime)
  const s16x8 zero8 = {0,0,0,0,0,0,0,0};
  const f32x4 zf4 = {0.f,0.f,0.f,0.f};

  // ---- stage chunk payload (14336B, linear) ----
  #pragma unroll
  for (int q=0;q<14;q++)
    gload_lds16((const float*)(chunk + (size_t)q*1024) + l*4, (float*)(SH + q*1024));
  asm volatile("s_waitcnt vmcnt(0)" ::: "memory");
  __builtin_amdgcn_sched_barrier(0);

  // ---- column pass: lane = channel l ----
  float ptv[16]; float pp=1.f;
  #pragma unroll
  for (int t=0;t<16;t++){ pp *= *(const float*)(SH + t*896 + 640 + l*4); ptv[t]=pp; }
  float pL = ptv[15];
  *(float*)(rec + 10240 + (size_t)l*4) = pL;
  float rpL = __builtin_amdgcn_rcpf(pL);
  float bs[16], ks[16];
  u16 vcol[16];
  #pragma unroll
  for (int t=0;t<16;t++){
    float sc = pL * __builtin_amdgcn_rcpf(ptv[t]);
    bs[t] = bf2f(*(const u16*)(SH + t*896 + 512 + l*2)) * sc;
    ks[t] = bf2f(*(const u16*)(SH + t*896 + 128 + l*2)) * sc;
    vcol[t] = *(const u16*)(SH + t*896 + 256 + l*2);
  }
  {
    i32x4 o;
    o[0]=(int)((unsigned)vcol[0]|((unsigned)vcol[1]<<16));
    o[1]=(int)((unsigned)vcol[2]|((unsigned)vcol[3]<<16));
    o[2]=(int)((unsigned)vcol[4]|((unsigned)vcol[5]<<16));
    o[3]=(int)((unsigned)vcol[6]|((unsigned)vcol[7]<<16));
    *(i32x4*)(&vbb[l*24]) = o;
    o[0]=(int)((unsigned)vcol[8]|((unsigned)vcol[9]<<16));
    o[1]=(int)((unsigned)vcol[10]|((unsigned)vcol[11]<<16));
    o[2]=(int)((unsigned)vcol[12]|((unsigned)vcol[13]<<16));
    o[3]=(int)((unsigned)vcol[14]|((unsigned)vcol[15]<<16));
    *(i32x4*)(&vbb[l*24+8]) = o;
    o[0]=pk2(bs[0],bs[1]); o[1]=pk2(bs[2],bs[3]); o[2]=pk2(bs[4],bs[5]); o[3]=pk2(bs[6],bs[7]);
    *(i32x4*)(&BKL[l*40]) = o;
    o[0]=pk2(bs[8],bs[9]); o[1]=pk2(bs[10],bs[11]); o[2]=pk2(bs[12],bs[13]); o[3]=pk2(bs[14],bs[15]);
    *(i32x4*)(&BKL[l*40+8]) = o;
    o[0]=pk2(ks[0],ks[1]); o[1]=pk2(ks[2],ks[3]); o[2]=pk2(ks[4],ks[5]); o[3]=pk2(ks[6],ks[7]);
    *(i32x4*)(&BKL[l*40+16]) = o;
    o[0]=pk2(ks[8],ks[9]); o[1]=pk2(ks[10],ks[11]); o[2]=pk2(ks[12],ks[13]); o[3]=pk2(ks[14],ks[15]);
    *(i32x4*)(&BKL[l*40+24]) = o;
  }
  #pragma unroll
  for (int t=0;t<16;t++){
    float at = bf2f(*(const u16*)(SH + t*896 + 384 + l*2));
    float rt = bf2f(*(const u16*)(SH + t*896 +   0 + l*2));
    float pprev = (t==0) ? 1.f : ptv[t-1];
    AT[t*72+l] = f2bf(pprev*at);
    RT[t*72+l] = f2bf(ptv[t]*rt);
    BT[t*72+l] = f2bf(bs[t]*rpL);
    KT[t*72+l] = f2bf(ks[t]*rpL);
  }
  asm volatile("s_waitcnt lgkmcnt(0)" ::: "memory");
  __builtin_amdgcn_sched_barrier(0);

  // ---- W-block: N, Yhat, Tb, Tk ----
  {
    s16x8 afA[2], afR[2], bfB[2], bfK[2];
    #pragma unroll
    for (int Kt=0;Kt<2;Kt++){
      afA[Kt]=*(const s16x8*)(&AT[c16*72 + 32*Kt + 8*g]);
      afR[Kt]=*(const s16x8*)(&RT[c16*72 + 32*Kt + 8*g]);
      bfB[Kt]=*(const s16x8*)(&BT[c16*72 + 32*Kt + 8*g]);
      bfK[Kt]=*(const s16x8*)(&KT[c16*72 + 32*Kt + 8*g]);
    }
    f32x4 dNN=zf4, dNY=zf4, dBB=zf4, dBK=zf4;
    #pragma unroll
    for (int Kt=0;Kt<2;Kt++){
      dNN=MFMA32(afA[Kt],bfB[Kt],dNN);
      dNY=MFMA32(afA[Kt],bfK[Kt],dNY);
      dBB=MFMA32(afR[Kt],bfB[Kt],dBB);
      dBK=MFMA32(afR[Kt],bfK[Kt],dBK);
    }
    #pragma unroll
    for (int e=0;e<4;e++){
      int tR=4*g+e, sC=c16;
      WN[tR*17+sC] = dNN[e];
      WY[tR*24+sC] = (sC<tR)? f2bf(dNY[e]) : (u16)0;
      WB[tR*24+sC] = (sC<=tR)? f2bf(dBB[e]) : (u16)0;
      WK[tR*24+sC] = (sC<=tR)? f2bf(dBK[e]) : (u16)0;
    }
  }

  // ---- YhatV -> rhsb ----
  s16x8 vf[4];
  #pragma unroll
  for (int J=0;J<4;J++){
    vf[J]=zero8;
    if (g<2) vf[J]=*(const s16x8*)(&vbb[(16*J+c16)*24 + 8*g]);
  }
  {
    s16x8 wyf=zero8;
    if (g<2) wyf=*(const s16x8*)(&WY[c16*24 + 8*g]);
    f32x4 dR[4];
    #pragma unroll
    for (int J=0;J<4;J++){
      dR[J]=zf4;
      dR[J]=MFMA32(wyf,vf[J],dR[J]);
      #pragma unroll
      for (int e=0;e<4;e++)
        rhsb[(4*g+e)*68 + 16*J + c16] = dR[J][e];
    }
  }

  // ---- P-solve: (I-N)P = Atil, lane = column j=l ----
  {
    float pv[16];
    #pragma unroll
    for (int t=0;t<16;t++) pv[t]=bf2f(AT[t*72+l]);
    #pragma unroll
    for (int t=1;t<16;t++)
      #pragma unroll
      for (int s=0;s<16;s++){
        if (s<t) pv[t] += WN[t*17+s]*pv[s];
      }
    i32x4 o;
    o[0]=pk2(pv[0],pv[1]); o[1]=pk2(pv[2],pv[3]); o[2]=pk2(pv[4],pv[5]); o[3]=pk2(pv[6],pv[7]);
    *(i32x4*)(&pbb[l*24]) = o;
    o[0]=pk2(pv[8],pv[9]); o[1]=pk2(pv[10],pv[11]); o[2]=pk2(pv[12],pv[13]); o[3]=pk2(pv[14],pv[15]);
    *(i32x4*)(&pbb[l*24+8]) = o;
  }

  // ---- z-solve: (I-N)zloc = YhatV, lane = column i=l ----
  {
    float zz[16];
    #pragma unroll
    for (int t=0;t<16;t++) zz[t]=rhsb[t*68+l];
    #pragma unroll
    for (int t=1;t<16;t++)
      #pragma unroll
      for (int s=0;s<16;s++){
        if (s<t) zz[t] += WN[t*17+s]*zz[s];
      }
    i32x4 o;
    o[0]=pk2(zz[0],zz[1]); o[1]=pk2(zz[2],zz[3]); o[2]=pk2(zz[4],zz[5]); o[3]=pk2(zz[6],zz[7]);
    *(i32x4*)(&zbb[l*24]) = o;
    o[0]=pk2(zz[8],zz[9]); o[1]=pk2(zz[10],zz[11]); o[2]=pk2(zz[12],zz[13]); o[3]=pk2(zz[14],zz[15]);
    *(i32x4*)(&zbb[l*24+8]) = o;
  }
  asm volatile("s_waitcnt lgkmcnt(0)" ::: "memory");
  __builtin_amdgcn_sched_barrier(0);

  // ---- G = Rtil + Tb*P -> gtmp ; Yloc = Tb*zloc + Tk*V -> record strips ----
  {
    s16x8 wbf=zero8, wkf=zero8;
    if (g<2){
      wbf=*(const s16x8*)(&WB[c16*24 + 8*g]);
      wkf=*(const s16x8*)(&WK[c16*24 + 8*g]);
    }
    #pragma unroll
    for (int J=0;J<4;J++){
      s16x8 pfB=zero8, zfB=zero8;
      if (g<2){
        pfB=*(const s16x8*)(&pbb[(16*J+c16)*24 + 8*g]);
        zfB=*(const s16x8*)(&zbb[(16*J+c16)*24 + 8*g]);
      }
      f32x4 dG, dYl=zf4;
      #pragma unroll
      for (int e=0;e<4;e++) dG[e]=bf2f(RT[(4*g+e)*72 + 16*J + c16]);
      dG=MFMA32(wbf,pfB,dG);
      dYl=MFMA32(wbf,zfB,dYl);
      dYl=MFMA32(wkf,vf[J],dYl);
      #pragma unroll
      for (int e=0;e<4;e++) gtmp[(4*g+e)*68 + 16*J + c16]=dG[e];
      i32x2 o2; o2[0]=pk2(dYl[0],dYl[1]); o2[1]=pk2(dYl[2],dYl[3]);
      *(i32x2*)(rec + 10496 + (size_t)J*2560 + 2048 + (size_t)l*8) = o2;
    }
  }

  // ---- Q = P^T [Bbar;Kbar] tiles -> record Q A-frags; c = [Bbar;Kbar]^T [z;V] ----
  {
    s16x8 bk[4], pfr[4], bzv[4];
    #pragma unroll
    for (int nt=0;nt<4;nt++) bk[nt]=*(const s16x8*)(&BKL[(16*nt+c16)*40 + 8*g]);
    #pragma unroll
    for (int mt=0;mt<4;mt++)
      pfr[mt]= (g<2) ? *(const s16x8*)(&pbb[(16*mt+c16)*24 + 8*g]) : zero8;
    #pragma unroll
    for (int it=0;it<4;it++)
      bzv[it]= (g<2) ? *(const s16x8*)(&zbb[(16*it+c16)*24 + 8*g])
                     : *(const s16x8*)(&vbb[(16*it+c16)*24 + 8*(g-2)]);
    #pragma unroll
    for (int mt=0;mt<4;mt++){
      #pragma unroll
      for (int nt=0;nt<4;nt++){
        f32x4 dQ = MFMA32(pfr[mt], bk[nt], zf4);
        int kk = mt>>1, gq = ((mt&1)<<1) | (g>>1), jo = g&1;
        i32x2 o2; o2[0]=pk2(dQ[0],dQ[1]); o2[1]=pk2(dQ[2],dQ[3]);
        *(i32x2*)(rec + ((size_t)(kk*4+nt)*64 + (size_t)(c16 + 16*gq))*16 + 8*jo) = o2;
      }
    }
    #pragma unroll
    for (int jtp=0;jtp<4;jtp++){
      #pragma unroll
      for (int it=0;it<4;it++){
        f32x4 dc = MFMA32(bk[jtp], bzv[it], zf4);
        i32x2 o2; o2[0]=pk2(dc[0],dc[1]); o2[1]=pk2(dc[2],dc[3]);
        *(i32x2*)(rec + 10496 + (size_t)it*2560 + ((size_t)jtp*64 + l)*8) = o2;
      }
    }
  }

  // ---- G A-frags -> record ----
  #pragma unroll
  for (int kk=0;kk<2;kk++){
    f32x4 b0 = *(const f32x4*)(&gtmp[c16*68 + 32*kk + 8*g]);
    f32x4 b1 = *(const f32x4*)(&gtmp[c16*68 + 32*kk + 8*g + 4]);
    i32x4 o;
    o[0]=pk2(b0[0],b0[1]); o[1]=pk2(b0[2],b0[3]); o[2]=pk2(b1[0],b1[1]); o[3]=pk2(b1[2],b1[3]);
    *(i32x4*)(rec + 8192 + (size_t)(kk*64+l)*16) = o;
  }
}

// ---------------- serial scan: register-direct record loads, unroll-2 ----------------
__global__ __launch_bounds__(64) void scan2_kernel(char* ws, const float* S0, float* dout){
  float* YB=(float*)(ws+OFF_YBUF);
  const char* recb = ws + OFF_SEQ;
  int bid=blockIdx.x, bh=bid>>2, w=bid&3;
  int l=threadIdx.x, c16=l&15, g=l>>4;

  __shared__ __align__(16) u16 ST[16*88];

  f32x4 Sreg[4];
  #pragma unroll
  for (int jt=0;jt<4;jt++)
    Sreg[jt] = *(const f32x4*)(S0 + (size_t)bh*4096 + (size_t)(16*w+c16)*64 + 16*jt + 4*g);
  #pragma unroll
  for (int jt=0;jt<4;jt++){
    i32x2 p; p[0]=pk2(Sreg[jt][0],Sreg[jt][1]); p[1]=pk2(Sreg[jt][2],Sreg[jt][3]);
    *(i32x2*)(&ST[c16*88 + 16*jt + 4*g]) = p;
  }

  const char* rb = recb + (size_t)(bh*64)*24576;
  float* yb0 = YB + (size_t)bh*65536;

#define DECLR(S) s16x8 qf##S[8]; s16x8 gf##S[2]; f32x4 pl##S[4]; i32x2 cf##S[4]; i32x2 yl##S;
#define LOADR(S, nc) do{ \
    const char* rp_ = rb + (size_t)(nc)*24576; \
    _Pragma("unroll") \
    for (int q_=0;q_<8;q_++) qf##S[q_] = *(const s16x8*)(rp_ + (size_t)q_*1024 + l*16); \
    gf##S[0] = *(const s16x8*)(rp_ + 8192 + (size_t)l*16); \
    gf##S[1] = *(const s16x8*)(rp_ + 9216 + (size_t)l*16); \
    _Pragma("unroll") \
    for (int jt_=0;jt_<4;jt_++) pl##S[jt_] = *(const f32x4*)(rp_ + 10240 + (size_t)(16*jt_+4*g)*4); \
    _Pragma("unroll") \
    for (int jt_=0;jt_<4;jt_++) cf##S[jt_] = *(const i32x2*)(rp_ + 10496 + (size_t)w*2560 + (size_t)(jt_*64+l)*8); \
    yl##S = *(const i32x2*)(rp_ + 10496 + (size_t)w*2560 + 2048 + (size_t)l*8); \
  }while(0)
#define STEP(S, ch) do{ \
    s16x8 sB0=*(const s16x8*)(&ST[c16*88 + 8*g]); \
    s16x8 sB1=*(const s16x8*)(&ST[c16*88 + 32 + 8*g]); \
    f32x4 dy=cvt4(yl##S); \
    dy=MFMA32(gf##S[0],sB0,dy); dy=MFMA32(gf##S[1],sB1,dy); \
    _Pragma("unroll") \
    for (int jt_=0;jt_<4;jt_++){ \
      f32x4 acc = cvt4(cf##S[jt_]); \
      acc = MFMA32(qf##S[jt_], sB0, acc); \
      acc = MFMA32(qf##S[4+jt_], sB1, acc); \
      _Pragma("unroll") \
      for (int e_=0;e_<4;e_++) acc[e_] = fmaf(pl##S[jt_][e_], Sreg[jt_][e_], acc[e_]); \
      Sreg[jt_]=acc; \
    } \
    _Pragma("unroll") \
    for (int jt_=0;jt_<4;jt_++){ \
      i32x2 p_; p_[0]=cvtpk(Sreg[jt_][0],Sreg[jt_][1]); p_[1]=cvtpk(Sreg[jt_][2],Sreg[jt_][3]); \
      *(i32x2*)(&ST[c16*88 + 16*jt_ + 4*g]) = p_; \
    } \
    { float* yb_ = yb0 + (size_t)(ch)*1024; \
      _Pragma("unroll") \
      for (int e_=0;e_<4;e_++) yb_[(size_t)(4*g+e_)*64 + 16*w + c16] = dy[e_]; } \
  }while(0)

  DECLR(A); DECLR(B);
  LOADR(A, 0);
  LOADR(B, 1);

  #pragma unroll 1
  for (int ch=0; ch<64; ch+=2){
    STEP(A, ch);
    { int nc = ch+2; if (nc>63) nc=63; LOADR(A, nc); }
    STEP(B, ch+1);
    { int nc = ch+3; if (nc>63) nc=63; LOADR(B, nc); }
  }
#undef DECLR
#undef LOADR
#undef STEP

  #pragma unroll
  for (int jt=0;jt<4;jt++)
    *(f32x4*)(dout + 2097152 + (size_t)bh*4096 + (size_t)(16*w+c16)*64 + 16*jt + 4*g) = Sreg[jt];
}

// ---------------- epilogue: groupnorm + bonus + gate -> bf16 ----------------
__global__ __launch_bounds__(256) void epi_kernel(char* ws, const float* lnw, const float* lnb)
{
  const float* YB=(const float*)(ws+OFF_YBUF);
  const u16* VEPI=(const u16*)(ws+OFF_VEPI);
  const float* DPp=(const float*)(ws+OFF_DP);
  const float* GB=(const float*)(ws+OFF_GBUF);
  u16* XGB=(u16*)(ws+OFF_XGB);
  int m=blockIdx.x, b=m>>10, t=m&1023;
  int tid=threadIdx.x, c0=tid*4, h=c0>>6, i0=c0&63;
  f32x4 y=*(const f32x4*)(YB + ((size_t)(b*16+h)*1024+t)*64 + i0);
  float s = y[0]+y[1]+y[2]+y[3];
  float ss= y[0]*y[0]+y[1]*y[1]+y[2]*y[2]+y[3]*y[3];
  #pragma unroll
  for (int mk=1;mk<16;mk<<=1){ s+=__shfl_xor(s,mk); ss+=__shfl_xor(ss,mk); }
  float mu=s*(1.0f/64.0f), var=ss*(1.0f/64.0f)-mu*mu;
  float inv=rsqrtf(var + 6.4e-4f);
  u16x4 v16=*(const u16x4*)(VEPI + ((size_t)(b*16+h)*1024+t)*64 + i0);
  float dp = DPp[(size_t)(b*16+h)*1024 + t];
  f32x4 gg=*(const f32x4*)(GB+(size_t)m*1024+c0);
  u16x4 outv;
  #pragma unroll
  for (int j=0;j<4;j++){
    float xn = (y[j]-mu)*inv*lnw[c0+j] + lnb[c0+j] + dp*bf2f(v16[j]);
    outv[j]=f2bf(xn*gg[j]);
  }
  *(u16x4*)(XGB+(size_t)m*1024+c0)=outv;
}

extern "C" void kernel_launch(void* const* d_in, const int* in_sizes, int n_in,
                              void* d_out, int out_size, void* d_ws, size_t ws_size,
                              hipStream_t stream) {
  const float* x      =(const float*)d_in[0];
  const float* S0     =(const float*)d_in[1];
  const float* vfirst =(const float*)d_in[2];
  const float* w0     =(const float*)d_in[3];
  const float* w1     =(const float*)d_in[4];
  const float* w2     =(const float*)d_in[5];
  const float* a0     =(const float*)d_in[6];
  const float* a1     =(const float*)d_in[7];
  const float* a2     =(const float*)d_in[8];
  const float* v0     =(const float*)d_in[9];
  const float* v1     =(const float*)d_in[10];
  const float* v2     =(const float*)d_in[11];
  const float* g1     =(const float*)d_in[12];
  const float* g2     =(const float*)d_in[13];
  const float* k_k    =(const float*)d_in[14];
  const float* k_a    =(const float*)d_in[15];
  const float* r_k    =(const float*)d_in[16];
  const float* Wq     =(const float*)d_in[17];
  const float* Wk     =(const float*)d_in[18];
  const float* Wv     =(const float*)d_in[19];
  const float* Wo     =(const float*)d_in[20];
  const float* ln_w   =(const float*)d_in[21];
  const float* ln_b   =(const float*)d_in[22];
  char* ws=(char*)d_ws;
  float* dout=(float*)d_out;

  prep_kernel<<<2048,256,0,stream>>>(ws,x,vfirst,w1,w2,a1,a2,v1,v2,g1,g2,Wq,Wk,Wv,Wo,dout);
  gemm_kernel<<<dim3(32,19),256,0,stream>>>(0,ws,w0,a0,v0,dout);
  gemm_kernel<<<dim3(32,32),256,0,stream>>>(1,ws,w0,a0,v0,dout);
  prep2_kernel<<<2048,256,0,stream>>>(ws,vfirst,k_k,k_a,r_k);
  pre_kernel<<<2048,64,0,stream>>>(ws);
  scan2_kernel<<<128,64,0,stream>>>(ws,S0,dout);
  epi_kernel<<<2048,256,0,stream>>>(ws,ln_w,ln_b);
  gemm_kernel<<<dim3(32,8),256,0,stream>>>(2,ws,w0,a0,v0,dout);
}

// Round 14
// 159.305 us; speedup vs baseline: 1.4906x; 1.0014x over previous
//
#include <hip/hip_runtime.h>

typedef unsigned short u16;
typedef __attribute__((ext_vector_type(8))) short s16x8;
typedef __attribute__((ext_vector_type(4))) float f32x4;
typedef __attribute__((ext_vector_type(4))) int   i32x4;
typedef __attribute__((ext_vector_type(2))) int   i32x2;
typedef __attribute__((ext_vector_type(4))) unsigned short u16x4;

// ---------------- workspace layout (bytes) ----------------
constexpr size_t OFF_XB   = 0;                     // bf16 x [2048][1024]; later VEPI
constexpr size_t OFF_WQB  = OFF_XB   + 4194304;    // bf16 Wq         [1024][1024]
constexpr size_t OFF_WKB  = OFF_WQB  + 2097152;    // bf16 Wk         [512][1024]
constexpr size_t OFF_WVB  = OFF_WKB  + 1048576;    // bf16 Wv         [512][1024]
constexpr size_t OFF_WOB  = OFF_WVB  + 1048576;    // bf16 Wo         [1024][1024]
constexpr size_t OFF_W1T  = OFF_WOB  + 2097152;    // bf16 W1T [384][1024]; later DP
constexpr size_t OFF_W2T  = OFF_W1T  + 786432;     // bf16 w2T        [1024][64]
constexpr size_t OFF_A2T  = OFF_W2T  + 131072;     // bf16 a2T        [1024][64]
constexpr size_t OFF_V2T  = OFF_A2T  + 131072;     // bf16 v2T        [1024][32]
constexpr size_t OFF_G2T  = OFF_V2T  + 65536;      // bf16 g2T        [1024][160]
constexpr size_t OFF_KQF  = OFF_G2T  + 327680;     // f32 k-proj      [2048][512]
constexpr size_t OFF_VQF  = OFF_KQF  + 4194304;    // f32 v-proj      [2048][512]
constexpr size_t OFF_URAW = OFF_VQF  + 4194304;    // (dead)
constexpr size_t OFF_UB   = OFF_URAW + 2621440;    // bf16 stage1 act [2048][384]
constexpr size_t OFF_S2A  = OFF_UB   + 1572864;    // f32 iclr        [2048][1024]
constexpr size_t OFF_S2V  = OFF_S2A  + 8388608;    // f32 vmix        [2048][1024]
constexpr size_t OFF_GBUF = OFF_S2V  + 8388608;    // f32 gate        [2048][1024]
constexpr size_t OFF_SEQ  = OFF_GBUF + 8388608;    // chunks [2048][24576B]; later records
constexpr size_t OFF_YBUF = OFF_SEQ  + 50331648;   // f32 y   [2][16][1024][64]
constexpr size_t OFF_XGB  = OFF_YBUF + 8388608;    // bf16 xn*g       [2048][1024]

// SEQ chunk payload (first 14336B of each 24576B slot), per t-row stride 896:
//  +0 r bf16[64] | +128 k | +256 v | +384 a | +512 b | +640 decay f32[64]
// record overlay (pre overwrites its OWN chunk): 0 Q(8192) | 8192 G(2048) |
//  10240 pL f32[64] | 10496 + w*2560 { c[jt4][lane]x8B (2048) | Yloc (512) }
constexpr size_t OFF_VEPI = OFF_XB;                // bf16 v rows (XB dead after gemm0)
constexpr size_t OFF_DP   = OFF_W1T;               // f32 dp (W1T dead after gemm0)

__device__ __forceinline__ u16 f2bf(float f){
  unsigned int u = __builtin_bit_cast(unsigned int, f);
  u = u + 0x7fffu + ((u >> 16) & 1u);
  return (u16)(u >> 16);
}
__device__ __forceinline__ int pk2(float a, float b){
  return (int)((unsigned)f2bf(a) | ((unsigned)f2bf(b) << 16));
}
__device__ __forceinline__ int cvtpk(float a, float b){
  int r;
  asm("v_cvt_pk_bf16_f32 %0, %1, %2" : "=v"(r) : "v"(a), "v"(b));
  return r;
}
__device__ __forceinline__ float bf2f(u16 h){
  return __builtin_bit_cast(float, ((unsigned)h) << 16);
}
__device__ __forceinline__ f32x4 cvt4(i32x2 v){
  unsigned a=(unsigned)v[0], b=(unsigned)v[1];
  f32x4 r;
  r[0]=__builtin_bit_cast(float, a<<16);
  r[1]=__builtin_bit_cast(float, a&0xffff0000u);
  r[2]=__builtin_bit_cast(float, b<<16);
  r[3]=__builtin_bit_cast(float, b&0xffff0000u);
  return r;
}

__device__ __forceinline__ void gload_lds16(const float* g, float* l){
  __builtin_amdgcn_global_load_lds((const __attribute__((address_space(1))) void*)g,
                                   (__attribute__((address_space(3))) void*)l, 16, 0, 0);
}
__device__ __forceinline__ void gload_lds16u(const u16* g, u16* l){
  __builtin_amdgcn_global_load_lds((const __attribute__((address_space(1))) void*)g,
                                   (__attribute__((address_space(3))) void*)l, 16, 0, 0);
}

// ---------------- prep: vectorized convert + transposes + v_first passthrough ----------------
constexpr size_t N_XB=2097152, N_WQ=1048576, N_WK=524288, N_WV=524288, N_WO=1048576,
  N_W1T=393216, N_W2T=65536, N_A2T=65536, N_V2T=32768, N_G2T=163840, N_VF=2097152;
constexpr size_t NV_BULK = (N_XB+N_WQ+N_WK+N_WV+N_WO)/4;   // vectorized bf16 copies
constexpr size_t NV_VF   = N_VF/4;                          // vectorized f32 copy
constexpr size_t N_SCAL  = N_W1T+N_W2T+N_A2T+N_V2T+N_G2T;   // scalar transposes
constexpr size_t PREP_TOT = NV_BULK + NV_VF + N_SCAL;

__global__ __launch_bounds__(256) void prep_kernel(char* ws, const float* x, const float* vfirst,
  const float* w1, const float* w2, const float* a1, const float* a2,
  const float* v1, const float* v2, const float* g1, const float* g2,
  const float* Wq, const float* Wk, const float* Wv, const float* Wo, float* dout)
{
  u16* XB=(u16*)(ws+OFF_XB); u16* WQB=(u16*)(ws+OFF_WQB); u16* WKB=(u16*)(ws+OFF_WKB);
  u16* WVB=(u16*)(ws+OFF_WVB); u16* WOB=(u16*)(ws+OFF_WOB); u16* W1T=(u16*)(ws+OFF_W1T);
  u16* W2T=(u16*)(ws+OFF_W2T); u16* A2T=(u16*)(ws+OFF_A2T); u16* V2T=(u16*)(ws+OFF_V2T);
  u16* G2T=(u16*)(ws+OFF_G2T);
  for (size_t idx=(size_t)blockIdx.x*256+threadIdx.x; idx<PREP_TOT; idx+=(size_t)gridDim.x*256){
    size_t r = idx;
    if (r < NV_BULK){
      size_t e = r*4;
      const float* src; u16* dst;
      if (e < N_XB){ src=x+e; dst=XB+e; }
      else { e-=N_XB;
        if (e < N_WQ){ src=Wq+e; dst=WQB+e; }
        else { e-=N_WQ;
          if (e < N_WK){ src=Wk+e; dst=WKB+e; }
          else { e-=N_WK;
            if (e < N_WV){ src=Wv+e; dst=WVB+e; }
            else { e-=N_WV; src=Wo+e; dst=WOB+e; }
          }
        }
      }
      f32x4 v=*(const f32x4*)src;
      u16x4 o; o[0]=f2bf(v[0]); o[1]=f2bf(v[1]); o[2]=f2bf(v[2]); o[3]=f2bf(v[3]);
      *(u16x4*)dst=o;
      continue;
    }
    r -= NV_BULK;
    if (r < NV_VF){
      size_t e=r*4;
      *(f32x4*)(dout + 2228224 + e) = *(const f32x4*)(vfirst + e);
      continue;
    }
    r -= NV_VF;
    if (r < N_W1T){
      int n=(int)(r>>10), k=(int)(r&1023); float v=0.f;
      if (n<64) v=w1[(size_t)k*64+n];
      else if (n<128) v=a1[(size_t)k*64+(n-64)];
      else if (n<160) v=v1[(size_t)k*32+(n-128)];
      else if (n<320) v=g1[(size_t)k*160+(n-160)];
      W1T[r]=f2bf(v); continue; } r-=N_W1T;
    if (r < N_W2T){ int c=(int)(r>>6), d=(int)(r&63); W2T[r]=f2bf(w2[(size_t)d*1024+c]); continue; } r-=N_W2T;
    if (r < N_A2T){ int c=(int)(r>>6), d=(int)(r&63); A2T[r]=f2bf(a2[(size_t)d*1024+c]); continue; } r-=N_A2T;
    if (r < N_V2T){ int c=(int)(r>>5), d=(int)(r&31); V2T[r]=f2bf(v2[(size_t)d*1024+c]); continue; } r-=N_V2T;
    { int c=(int)(r/160), d=(int)(r%160); G2T[r]=f2bf(g2[(size_t)d*1024+c]); }
  }
}

// ---------------- unified NT bf16 MFMA GEMM: C[m][n] = sum_k A[m][k]*B[n][k] ----------------
// 64x128 tile, 4 waves (2Mx2N), LDS 24KB; global_load_lds staging with XOR chunk swizzle.
__global__ __launch_bounds__(256) void gemm_kernel(int phase, char* ws,
  const float* w0b, const float* a0b, const float* v0b, float* dout)
{
  const u16* A; const u16* Bw;
  float* outF=nullptr; const float* bias=nullptr;
  char* SEQc=(char*)(ws+OFF_SEQ);
  u16* UBp=(u16*)(ws+OFF_UB);
  int lda=0, ldb=0, K=0, ldc=0, Nlim=1024, col0=0, outMode=0;
  int y = blockIdx.y;
  if (phase==0){
    A=(const u16*)(ws+OFF_XB); lda=1024; K=1024;
    if (y<8)      { Bw=(const u16*)(ws+OFF_WQB); ldb=1024; col0=y*128;       outMode=1; }
    else if (y<12){ Bw=(const u16*)(ws+OFF_WKB); ldb=1024; col0=(y-8)*128;   outF=(float*)(ws+OFF_KQF); ldc=512; Nlim=512; }
    else if (y<16){ Bw=(const u16*)(ws+OFF_WVB); ldb=1024; col0=(y-12)*128;  outF=(float*)(ws+OFF_VQF); ldc=512; Nlim=512; }
    else          { Bw=(const u16*)(ws+OFF_W1T); ldb=1024; col0=(y-16)*128;  outMode=4; Nlim=320; }
  } else if (phase==1){
    int seg=y>>3; col0=(y&7)*128;
    const int Ks[4]={64,64,32,160};
    const int Ao[4]={0,64,128,160};
    K=Ks[seg]; lda=384; ldb=K;
    A=(const u16*)(ws+OFF_UB) + Ao[seg];
    if (seg==0)     { Bw=(const u16*)(ws+OFF_W2T); outMode=2; bias=w0b; }
    else if (seg==1){ Bw=(const u16*)(ws+OFF_A2T); outMode=3; bias=a0b; outF=(float*)(ws+OFF_S2A); ldc=1024; }
    else if (seg==2){ Bw=(const u16*)(ws+OFF_V2T); outMode=3; bias=v0b; outF=(float*)(ws+OFF_S2V); ldc=1024; }
    else            { Bw=(const u16*)(ws+OFF_G2T); outF=(float*)(ws+OFF_GBUF); ldc=1024; }
  } else {
    A=(const u16*)(ws+OFF_XGB); lda=1024; K=1024;
    Bw=(const u16*)(ws+OFF_WOB); ldb=1024; col0=y*128; outF=dout; ldc=1024;
  }
  int m0 = blockIdx.x*64;
  __shared__ __align__(16) u16 As[2][2048];   // 64 x 32
  __shared__ __align__(16) u16 Bs[2][4096];   // 128 x 32
  int tid=threadIdx.x, l=tid&63, wv=tid>>6, wm=wv>>1, wn=wv&1;

  int cswz = (l&3) ^ ((l>>3)&3);
  int srA = wv*16 + (l>>2);
  int srB = wv*32 + (l>>2);
  const u16* aP0 = A  + (size_t)(m0+srA)*lda       + cswz*8;
  const u16* bP0 = Bw + (size_t)(col0+srB)*ldb     + cswz*8;
  const u16* bP1 = Bw + (size_t)(col0+srB+16)*ldb  + cswz*8;

  f32x4 acc[2][4];
  #pragma unroll
  for (int i=0;i<2;i++)
    #pragma unroll
    for (int j=0;j<4;j++) acc[i][j]=(f32x4){0.f,0.f,0.f,0.f};

#define GSTAGE(b,k0) do{                                   \
    gload_lds16u(aP0 + (k0), &As[b][wv*512]);              \
    gload_lds16u(bP0 + (k0), &Bs[b][wv*1024]);             \
    gload_lds16u(bP1 + (k0), &Bs[b][wv*1024+512]);         \
  }while(0)

  GSTAGE(0,0);
  asm volatile("s_waitcnt vmcnt(0)" ::: "memory");
  __syncthreads();

  int rrow=l&15, ck=l>>4;
  for (int k0=0;k0<K;k0+=32){
    int cb=(k0>>5)&1;
    if (k0+32<K) GSTAGE(cb^1, k0+32);
    s16x8 af[2], bf[4];
    #pragma unroll
    for (int mt=0;mt<2;mt++){
      int ra = wm*32+mt*16+rrow;
      af[mt]=*(const s16x8*)(&As[cb][ra*32 + ((ck ^ ((ra>>1)&3))<<3)]);
    }
    #pragma unroll
    for (int nt=0;nt<4;nt++){
      int rb = wn*64+nt*16+rrow;
      bf[nt]=*(const s16x8*)(&Bs[cb][rb*32 + ((ck ^ ((rb>>1)&3))<<3)]);
    }
    #pragma unroll
    for (int mt=0;mt<2;mt++)
      #pragma unroll
      for (int nt=0;nt<4;nt++)
        acc[mt][nt]=__builtin_amdgcn_mfma_f32_16x16x32_bf16(af[mt],bf[nt],acc[mt][nt],0,0,0);
    __syncthreads();
  }
#undef GSTAGE
  // epilogue
  #pragma unroll
  for (int mt=0;mt<2;mt++){
    #pragma unroll
    for (int nt=0;nt<4;nt++){
      int nglob = col0 + wn*64 + nt*16 + (l&15);
      if (nglob >= Nlim) continue;
      #pragma unroll
      for (int rg=0;rg<4;rg++){
        int mrow = m0 + wm*32 + mt*16 + ((l>>4)<<2) + rg;
        float val = acc[mt][nt][rg];
        if (outMode==0){
          outF[(size_t)mrow*ldc + nglob] = val;
        } else if (outMode==1){          // r bf16 -> SEQ slot 0
          int b=mrow>>10, t=mrow&1023, h=nglob>>6, i=nglob&63;
          char* cbase = SEQc + (size_t)((b*16+h)*64 + (t>>4))*24576 + (size_t)(t&15)*896;
          *(u16*)(cbase + i*2) = f2bf(val);
        } else if (outMode==2){          // decay f32 -> SEQ slot 5
          float w = bias[nglob] + val;
          float d = expf(-expf(w));
          int b=mrow>>10, t=mrow&1023, h=nglob>>6, i=nglob&63;
          char* cbase = SEQc + (size_t)((b*16+h)*64 + (t>>4))*24576 + (size_t)(t&15)*896;
          *(float*)(cbase + 640 + i*4) = d;
        } else if (outMode==3){          // sigmoid(bias+acc)
          float s = 1.0f/(1.0f+__expf(-(bias[nglob]+val)));
          outF[(size_t)mrow*ldc + nglob] = s;
        } else {                          // fused stage-1 activation -> UB bf16
          float a = (nglob<64) ? tanhf(val)
                  : (nglob<160) ? val
                  : 1.0f/(1.0f+__expf(-val));
          UBp[(size_t)mrow*384 + nglob] = f2bf(a);
        }
      }
    }
  }
}

// ---------------- prep2: build SEQ slots k,v,a,b (bf16) + dp + VEPI ----------------
__global__ __launch_bounds__(256) void prep2_kernel(char* ws, const float* vfirst,
  const float* kk_s, const float* ka_s, const float* rkw)
{
  const float* KQF=(const float*)(ws+OFF_KQF);
  const float* VQF=(const float*)(ws+OFF_VQF);
  const float* ICLR=(const float*)(ws+OFF_S2A);
  const float* VMIX=(const float*)(ws+OFF_S2V);
  u16* VEPI=(u16*)(ws+OFF_VEPI);
  float* DPp=(float*)(ws+OFF_DP);
  int m=blockIdx.x, b=m>>10, t=m&1023;
  int tid=threadIdx.x, c0=tid*4, h=c0>>6, i0=c0&63, hk=h>>1;
  f32x4 kq=*(const f32x4*)(KQF+(size_t)m*512+hk*64+i0);
  f32x4 vq=*(const f32x4*)(VQF+(size_t)m*512+hk*64+i0);
  f32x4 ic=*(const f32x4*)(ICLR+(size_t)m*1024+c0);
  f32x4 vm=*(const f32x4*)(VMIX+(size_t)m*1024+c0);
  f32x4 vf=*(const f32x4*)(vfirst+(size_t)m*1024+c0);
  f32x4 kkc=*(const f32x4*)(kk_s+c0);
  f32x4 kac=*(const f32x4*)(ka_s+c0);
  f32x4 kk=kq*kkc;
  float ssq=kk[0]*kk[0]+kk[1]*kk[1]+kk[2]*kk[2]+kk[3]*kk[3];
  #pragma unroll
  for (int mk=1;mk<16;mk<<=1) ssq += __shfl_xor(ssq,mk);
  float scale = 1.0f / fmaxf(sqrtf(ssq), 1e-12f);
  int bh=b*16+h;
  char* cb = ws + OFF_SEQ + (size_t)(bh*64+(t>>4))*24576 + (size_t)(t&15)*896;
  u16x4 rv = *(const u16x4*)(cb + (size_t)i0*2);
  f32x4 rkv = *(const f32x4*)(rkw + h*64 + i0);
  f32x4 kf,vv,av,bv;
  float dpp=0.f;
  #pragma unroll
  for (int j=0;j<4;j++){
    float icc = 1.0f + (ic[j]-1.0f)*kac[j];
    float kkn = kk[j]*scale;
    kf[j]=kq[j]*icc;
    vv[j]=vq[j] + (vf[j]-vq[j])*vm[j];
    av[j]=-kkn;
    bv[j]=kkn*icc;
    dpp += bf2f(rv[j])*kf[j]*rkv[j];
  }
  #pragma unroll
  for (int mk=1;mk<16;mk<<=1) dpp += __shfl_xor(dpp,mk);
  if ((tid&15)==0) DPp[(size_t)bh*1024 + t] = dpp;
  i32x2 o;
  o[0]=pk2(kf[0],kf[1]); o[1]=pk2(kf[2],kf[3]);
  *(i32x2*)(cb + 128 + (size_t)i0*2) = o;
  o[0]=pk2(vv[0],vv[1]); o[1]=pk2(vv[2],vv[3]);
  *(i32x2*)(cb + 256 + (size_t)i0*2) = o;
  *(i32x2*)(VEPI + ((size_t)bh*1024+t)*64 + i0) = o;
  o[0]=pk2(av[0],av[1]); o[1]=pk2(av[2],av[3]);
  *(i32x2*)(cb + 384 + (size_t)i0*2) = o;
  o[0]=pk2(bv[0],bv[1]); o[1]=pk2(bv[2],bv[3]);
  *(i32x2*)(cb + 512 + (size_t)i0*2) = o;
}

#define MFMA32(a,b,c) __builtin_amdgcn_mfma_f32_16x16x32_bf16(a,b,c,0,0,0)

// ---------------- precompute: per-chunk S-independent record (2048-way parallel) ------
__global__ __launch_bounds__(64) void pre_kernel(char* ws){
  int bid=blockIdx.x;
  int l=threadIdx.x, c16=l&15, g=l>>4;
  char* chunk = ws + OFF_SEQ + (size_t)bid*24576;
  char* rec = chunk;

  __shared__ __align__(16) char SH[31776];
  u16* AT =(u16*)(SH+14336);
  u16* RT =(u16*)(SH+16640);
  u16* BT =(u16*)(SH+18944);
  u16* KT =(u16*)(SH+21248);
  u16* vbb=(u16*)(SH+23552);
  u16* BKL=(u16*)(SH+26656);
  // overlay region (valid after column pass)
  float* WN  =(float*)(SH+0);
  u16* WY =(u16*)(SH+1088);
  u16* WB =(u16*)(SH+1888);
  u16* WK =(u16*)(SH+2688);
  u16* pbb=(u16*)(SH+3488);
  u16* zbb=(u16*)(SH+6592);
  float* rhsb=(float*)(SH+9696);
  float* gtmp=(float*)(SH+9696);   // overlays rhsb (disjoint lifetime)
  const s16x8 zero8 = {0,0,0,0,0,0,0,0};
  const f32x4 zf4 = {0.f,0.f,0.f,0.f};

  // ---- stage chunk payload (14336B, linear) ----
  #pragma unroll
  for (int q=0;q<14;q++)
    gload_lds16((const float*)(chunk + (size_t)q*1024) + l*4, (float*)(SH + q*1024));
  asm volatile("s_waitcnt vmcnt(0)" ::: "memory");
  __builtin_amdgcn_sched_barrier(0);

  // ---- column pass: lane = channel l ----
  float ptv[16]; float pp=1.f;
  #pragma unroll
  for (int t=0;t<16;t++){ pp *= *(const float*)(SH + t*896 + 640 + l*4); ptv[t]=pp; }
  float pL = ptv[15];
  *(float*)(rec + 10240 + (size_t)l*4) = pL;
  float rpL = __builtin_amdgcn_rcpf(pL);
  float bs[16], ks[16];
  u16 vcol[16];
  #pragma unroll
  for (int t=0;t<16;t++){
    float sc = pL * __builtin_amdgcn_rcpf(ptv[t]);
    bs[t] = bf2f(*(const u16*)(SH + t*896 + 512 + l*2)) * sc;
    ks[t] = bf2f(*(const u16*)(SH + t*896 + 128 + l*2)) * sc;
    vcol[t] = *(const u16*)(SH + t*896 + 256 + l*2);
  }
  {
    i32x4 o;
    o[0]=(int)((unsigned)vcol[0]|((unsigned)vcol[1]<<16));
    o[1]=(int)((unsigned)vcol[2]|((unsigned)vcol[3]<<16));
    o[2]=(int)((unsigned)vcol[4]|((unsigned)vcol[5]<<16));
    o[3]=(int)((unsigned)vcol[6]|((unsigned)vcol[7]<<16));
    *(i32x4*)(&vbb[l*24]) = o;
    o[0]=(int)((unsigned)vcol[8]|((unsigned)vcol[9]<<16));
    o[1]=(int)((unsigned)vcol[10]|((unsigned)vcol[11]<<16));
    o[2]=(int)((unsigned)vcol[12]|((unsigned)vcol[13]<<16));
    o[3]=(int)((unsigned)vcol[14]|((unsigned)vcol[15]<<16));
    *(i32x4*)(&vbb[l*24+8]) = o;
    o[0]=pk2(bs[0],bs[1]); o[1]=pk2(bs[2],bs[3]); o[2]=pk2(bs[4],bs[5]); o[3]=pk2(bs[6],bs[7]);
    *(i32x4*)(&BKL[l*40]) = o;
    o[0]=pk2(bs[8],bs[9]); o[1]=pk2(bs[10],bs[11]); o[2]=pk2(bs[12],bs[13]); o[3]=pk2(bs[14],bs[15]);
    *(i32x4*)(&BKL[l*40+8]) = o;
    o[0]=pk2(ks[0],ks[1]); o[1]=pk2(ks[2],ks[3]); o[2]=pk2(ks[4],ks[5]); o[3]=pk2(ks[6],ks[7]);
    *(i32x4*)(&BKL[l*40+16]) = o;
    o[0]=pk2(ks[8],ks[9]); o[1]=pk2(ks[10],ks[11]); o[2]=pk2(ks[12],ks[13]); o[3]=pk2(ks[14],ks[15]);
    *(i32x4*)(&BKL[l*40+24]) = o;
  }
  #pragma unroll
  for (int t=0;t<16;t++){
    float at = bf2f(*(const u16*)(SH + t*896 + 384 + l*2));
    float rt = bf2f(*(const u16*)(SH + t*896 +   0 + l*2));
    float pprev = (t==0) ? 1.f : ptv[t-1];
    AT[t*72+l] = f2bf(pprev*at);
    RT[t*72+l] = f2bf(ptv[t]*rt);
    BT[t*72+l] = f2bf(bs[t]*rpL);
    KT[t*72+l] = f2bf(ks[t]*rpL);
  }
  asm volatile("s_waitcnt lgkmcnt(0)" ::: "memory");
  __builtin_amdgcn_sched_barrier(0);

  // ---- W-block: N, Yhat, Tb, Tk ----
  {
    s16x8 afA[2], afR[2], bfB[2], bfK[2];
    #pragma unroll
    for (int Kt=0;Kt<2;Kt++){
      afA[Kt]=*(const s16x8*)(&AT[c16*72 + 32*Kt + 8*g]);
      afR[Kt]=*(const s16x8*)(&RT[c16*72 + 32*Kt + 8*g]);
      bfB[Kt]=*(const s16x8*)(&BT[c16*72 + 32*Kt + 8*g]);
      bfK[Kt]=*(const s16x8*)(&KT[c16*72 + 32*Kt + 8*g]);
    }
    f32x4 dNN=zf4, dNY=zf4, dBB=zf4, dBK=zf4;
    #pragma unroll
    for (int Kt=0;Kt<2;Kt++){
      dNN=MFMA32(afA[Kt],bfB[Kt],dNN);
      dNY=MFMA32(afA[Kt],bfK[Kt],dNY);
      dBB=MFMA32(afR[Kt],bfB[Kt],dBB);
      dBK=MFMA32(afR[Kt],bfK[Kt],dBK);
    }
    #pragma unroll
    for (int e=0;e<4;e++){
      int tR=4*g+e, sC=c16;
      WN[tR*17+sC] = dNN[e];
      WY[tR*24+sC] = (sC<tR)? f2bf(dNY[e]) : (u16)0;
      WB[tR*24+sC] = (sC<=tR)? f2bf(dBB[e]) : (u16)0;
      WK[tR*24+sC] = (sC<=tR)? f2bf(dBK[e]) : (u16)0;
    }
  }

  // ---- YhatV -> rhsb ----
  s16x8 vf[4];
  #pragma unroll
  for (int J=0;J<4;J++){
    vf[J]=zero8;
    if (g<2) vf[J]=*(const s16x8*)(&vbb[(16*J+c16)*24 + 8*g]);
  }
  {
    s16x8 wyf=zero8;
    if (g<2) wyf=*(const s16x8*)(&WY[c16*24 + 8*g]);
    f32x4 dR[4];
    #pragma unroll
    for (int J=0;J<4;J++){
      dR[J]=zf4;
      dR[J]=MFMA32(wyf,vf[J],dR[J]);
      #pragma unroll
      for (int e=0;e<4;e++)
        rhsb[(4*g+e)*68 + 16*J + c16] = dR[J][e];
    }
  }

  // ---- P-solve: (I-N)P = Atil, lane = column j=l ----
  {
    float pv[16];
    #pragma unroll
    for (int t=0;t<16;t++) pv[t]=bf2f(AT[t*72+l]);
    #pragma unroll
    for (int t=1;t<16;t++)
      #pragma unroll
      for (int s=0;s<16;s++){
        if (s<t) pv[t] += WN[t*17+s]*pv[s];
      }
    i32x4 o;
    o[0]=pk2(pv[0],pv[1]); o[1]=pk2(pv[2],pv[3]); o[2]=pk2(pv[4],pv[5]); o[3]=pk2(pv[6],pv[7]);
    *(i32x4*)(&pbb[l*24]) = o;
    o[0]=pk2(pv[8],pv[9]); o[1]=pk2(pv[10],pv[11]); o[2]=pk2(pv[12],pv[13]); o[3]=pk2(pv[14],pv[15]);
    *(i32x4*)(&pbb[l*24+8]) = o;
  }

  // ---- z-solve: (I-N)zloc = YhatV, lane = column i=l ----
  {
    float zz[16];
    #pragma unroll
    for (int t=0;t<16;t++) zz[t]=rhsb[t*68+l];
    #pragma unroll
    for (int t=1;t<16;t++)
      #pragma unroll
      for (int s=0;s<16;s++){
        if (s<t) zz[t] += WN[t*17+s]*zz[s];
      }
    i32x4 o;
    o[0]=pk2(zz[0],zz[1]); o[1]=pk2(zz[2],zz[3]); o[2]=pk2(zz[4],zz[5]); o[3]=pk2(zz[6],zz[7]);
    *(i32x4*)(&zbb[l*24]) = o;
    o[0]=pk2(zz[8],zz[9]); o[1]=pk2(zz[10],zz[11]); o[2]=pk2(zz[12],zz[13]); o[3]=pk2(zz[14],zz[15]);
    *(i32x4*)(&zbb[l*24+8]) = o;
  }
  asm volatile("s_waitcnt lgkmcnt(0)" ::: "memory");
  __builtin_amdgcn_sched_barrier(0);

  // ---- G = Rtil + Tb*P -> gtmp ; Yloc = Tb*zloc + Tk*V -> record strips ----
  {
    s16x8 wbf=zero8, wkf=zero8;
    if (g<2){
      wbf=*(const s16x8*)(&WB[c16*24 + 8*g]);
      wkf=*(const s16x8*)(&WK[c16*24 + 8*g]);
    }
    #pragma unroll
    for (int J=0;J<4;J++){
      s16x8 pfB=zero8, zfB=zero8;
      if (g<2){
        pfB=*(const s16x8*)(&pbb[(16*J+c16)*24 + 8*g]);
        zfB=*(const s16x8*)(&zbb[(16*J+c16)*24 + 8*g]);
      }
      f32x4 dG, dYl=zf4;
      #pragma unroll
      for (int e=0;e<4;e++) dG[e]=bf2f(RT[(4*g+e)*72 + 16*J + c16]);
      dG=MFMA32(wbf,pfB,dG);
      dYl=MFMA32(wbf,zfB,dYl);
      dYl=MFMA32(wkf,vf[J],dYl);
      #pragma unroll
      for (int e=0;e<4;e++) gtmp[(4*g+e)*68 + 16*J + c16]=dG[e];
      i32x2 o2; o2[0]=pk2(dYl[0],dYl[1]); o2[1]=pk2(dYl[2],dYl[3]);
      *(i32x2*)(rec + 10496 + (size_t)J*2560 + 2048 + (size_t)l*8) = o2;
    }
  }

  // ---- Q = P^T [Bbar;Kbar] tiles -> record Q A-frags; c = [Bbar;Kbar]^T [z;V] ----
  {
    s16x8 bk[4], pfr[4], bzv[4];
    #pragma unroll
    for (int nt=0;nt<4;nt++) bk[nt]=*(const s16x8*)(&BKL[(16*nt+c16)*40 + 8*g]);
    #pragma unroll
    for (int mt=0;mt<4;mt++)
      pfr[mt]= (g<2) ? *(const s16x8*)(&pbb[(16*mt+c16)*24 + 8*g]) : zero8;
    #pragma unroll
    for (int it=0;it<4;it++)
      bzv[it]= (g<2) ? *(const s16x8*)(&zbb[(16*it+c16)*24 + 8*g])
                     : *(const s16x8*)(&vbb[(16*it+c16)*24 + 8*(g-2)]);
    #pragma unroll
    for (int mt=0;mt<4;mt++){
      #pragma unroll
      for (int nt=0;nt<4;nt++){
        f32x4 dQ = MFMA32(pfr[mt], bk[nt], zf4);
        int kk = mt>>1, gq = ((mt&1)<<1) | (g>>1), jo = g&1;
        i32x2 o2; o2[0]=pk2(dQ[0],dQ[1]); o2[1]=pk2(dQ[2],dQ[3]);
        *(i32x2*)(rec + ((size_t)(kk*4+nt)*64 + (size_t)(c16 + 16*gq))*16 + 8*jo) = o2;
      }
    }
    #pragma unroll
    for (int jtp=0;jtp<4;jtp++){
      #pragma unroll
      for (int it=0;it<4;it++){
        f32x4 dc = MFMA32(bk[jtp], bzv[it], zf4);
        i32x2 o2; o2[0]=pk2(dc[0],dc[1]); o2[1]=pk2(dc[2],dc[3]);
        *(i32x2*)(rec + 10496 + (size_t)it*2560 + ((size_t)jtp*64 + l)*8) = o2;
      }
    }
  }

  // ---- G A-frags -> record ----
  #pragma unroll
  for (int kk=0;kk<2;kk++){
    f32x4 b0 = *(const f32x4*)(&gtmp[c16*68 + 32*kk + 8*g]);
    f32x4 b1 = *(const f32x4*)(&gtmp[c16*68 + 32*kk + 8*g + 4]);
    i32x4 o;
    o[0]=pk2(b0[0],b0[1]); o[1]=pk2(b0[2],b0[3]); o[2]=pk2(b1[0],b1[1]); o[3]=pk2(b1[2],b1[3]);
    *(i32x4*)(rec + 8192 + (size_t)(kk*64+l)*16) = o;
  }
}

// ---------------- serial scan: register-direct loads, 4 waves/block (1 per i-strip) ----
__global__ __launch_bounds__(256) void scan2_kernel(char* ws, const float* S0, float* dout){
  float* YB=(float*)(ws+OFF_YBUF);
  const char* recb = ws + OFF_SEQ;
  int bh=blockIdx.x;
  int tid=threadIdx.x, w=tid>>6, l=tid&63, c16=l&15, g=l>>4;

  __shared__ __align__(16) u16 ST[4][16*88];
  u16* STw = &ST[w][0];

  f32x4 Sreg[4];
  #pragma unroll
  for (int jt=0;jt<4;jt++)
    Sreg[jt] = *(const f32x4*)(S0 + (size_t)bh*4096 + (size_t)(16*w+c16)*64 + 16*jt + 4*g);
  #pragma unroll
  for (int jt=0;jt<4;jt++){
    i32x2 p; p[0]=pk2(Sreg[jt][0],Sreg[jt][1]); p[1]=pk2(Sreg[jt][2],Sreg[jt][3]);
    *(i32x2*)(&STw[c16*88 + 16*jt + 4*g]) = p;
  }

  const char* rb = recb + (size_t)(bh*64)*24576;
  float* yb0 = YB + (size_t)bh*65536;

#define DECLR(S) s16x8 qf##S[8]; s16x8 gf##S[2]; f32x4 pl##S[4]; i32x2 cf##S[4]; i32x2 yl##S;
#define LOADR(S, nc) do{ \
    const char* rp_ = rb + (size_t)(nc)*24576; \
    _Pragma("unroll") \
    for (int q_=0;q_<8;q_++) qf##S[q_] = *(const s16x8*)(rp_ + (size_t)q_*1024 + l*16); \
    gf##S[0] = *(const s16x8*)(rp_ + 8192 + (size_t)l*16); \
    gf##S[1] = *(const s16x8*)(rp_ + 9216 + (size_t)l*16); \
    _Pragma("unroll") \
    for (int jt_=0;jt_<4;jt_++) pl##S[jt_] = *(const f32x4*)(rp_ + 10240 + (size_t)(16*jt_+4*g)*4); \
    _Pragma("unroll") \
    for (int jt_=0;jt_<4;jt_++) cf##S[jt_] = *(const i32x2*)(rp_ + 10496 + (size_t)w*2560 + (size_t)(jt_*64+l)*8); \
    yl##S = *(const i32x2*)(rp_ + 10496 + (size_t)w*2560 + 2048 + (size_t)l*8); \
  }while(0)
#define STEP(S, ch) do{ \
    s16x8 sB0=*(const s16x8*)(&STw[c16*88 + 8*g]); \
    s16x8 sB1=*(const s16x8*)(&STw[c16*88 + 32 + 8*g]); \
    f32x4 dy=cvt4(yl##S); \
    dy=MFMA32(gf##S[0],sB0,dy); dy=MFMA32(gf##S[1],sB1,dy); \
    _Pragma("unroll") \
    for (int jt_=0;jt_<4;jt_++){ \
      f32x4 acc = cvt4(cf##S[jt_]); \
      acc = MFMA32(qf##S[jt_], sB0, acc); \
      acc = MFMA32(qf##S[4+jt_], sB1, acc); \
      _Pragma("unroll") \
      for (int e_=0;e_<4;e_++) acc[e_] = fmaf(pl##S[jt_][e_], Sreg[jt_][e_], acc[e_]); \
      Sreg[jt_]=acc; \
    } \
    _Pragma("unroll") \
    for (int jt_=0;jt_<4;jt_++){ \
      i32x2 p_; p_[0]=cvtpk(Sreg[jt_][0],Sreg[jt_][1]); p_[1]=cvtpk(Sreg[jt_][2],Sreg[jt_][3]); \
      *(i32x2*)(&STw[c16*88 + 16*jt_ + 4*g]) = p_; \
    } \
    { float* yb_ = yb0 + (size_t)(ch)*1024; \
      _Pragma("unroll") \
      for (int e_=0;e_<4;e_++) yb_[(size_t)(4*g+e_)*64 + 16*w + c16] = dy[e_]; } \
  }while(0)

  DECLR(A); DECLR(B);
  LOADR(A, 0);
  LOADR(B, 1);

  #pragma unroll 1
  for (int ch=0; ch<64; ch+=2){
    STEP(A, ch);
    { int nc = ch+2; if (nc>63) nc=63; LOADR(A, nc); }
    STEP(B, ch+1);
    { int nc = ch+3; if (nc>63) nc=63; LOADR(B, nc); }
  }
#undef DECLR
#undef LOADR
#undef STEP

  #pragma unroll
  for (int jt=0;jt<4;jt++)
    *(f32x4*)(dout + 2097152 + (size_t)bh*4096 + (size_t)(16*w+c16)*64 + 16*jt + 4*g) = Sreg[jt];
}

// ---------------- epilogue: groupnorm + bonus + gate -> bf16 ----------------
__global__ __launch_bounds__(256) void epi_kernel(char* ws, const float* lnw, const float* lnb)
{
  const float* YB=(const float*)(ws+OFF_YBUF);
  const u16* VEPI=(const u16*)(ws+OFF_VEPI);
  const float* DPp=(const float*)(ws+OFF_DP);
  const float* GB=(const float*)(ws+OFF_GBUF);
  u16* XGB=(u16*)(ws+OFF_XGB);
  int m=blockIdx.x, b=m>>10, t=m&1023;
  int tid=threadIdx.x, c0=tid*4, h=c0>>6, i0=c0&63;
  f32x4 y=*(const f32x4*)(YB + ((size_t)(b*16+h)*1024+t)*64 + i0);
  float s = y[0]+y[1]+y[2]+y[3];
  float ss= y[0]*y[0]+y[1]*y[1]+y[2]*y[2]+y[3]*y[3];
  #pragma unroll
  for (int mk=1;mk<16;mk<<=1){ s+=__shfl_xor(s,mk); ss+=__shfl_xor(ss,mk); }
  float mu=s*(1.0f/64.0f), var=ss*(1.0f/64.0f)-mu*mu;
  float inv=rsqrtf(var + 6.4e-4f);
  u16x4 v16=*(const u16x4*)(VEPI + ((size_t)(b*16+h)*1024+t)*64 + i0);
  float dp = DPp[(size_t)(b*16+h)*1024 + t];
  f32x4 gg=*(const f32x4*)(GB+(size_t)m*1024+c0);
  u16x4 outv;
  #pragma unroll
  for (int j=0;j<4;j++){
    float xn = (y[j]-mu)*inv*lnw[c0+j] + lnb[c0+j] + dp*bf2f(v16[j]);
    outv[j]=f2bf(xn*gg[j]);
  }
  *(u16x4*)(XGB+(size_t)m*1024+c0)=outv;
}

extern "C" void kernel_launch(void* const* d_in, const int* in_sizes, int n_in,
                              void* d_out, int out_size, void* d_ws, size_t ws_size,
                              hipStream_t stream) {
  const float* x      =(const float*)d_in[0];
  const float* S0     =(const float*)d_in[1];
  const float* vfirst =(const float*)d_in[2];
  const float* w0     =(const float*)d_in[3];
  const float* w1     =(const float*)d_in[4];
  const float* w2     =(const float*)d_in[5];
  const float* a0     =(const float*)d_in[6];
  const float* a1     =(const float*)d_in[7];
  const float* a2     =(const float*)d_in[8];
  const float* v0     =(const float*)d_in[9];
  const float* v1     =(const float*)d_in[10];
  const float* v2     =(const float*)d_in[11];
  const float* g1     =(const float*)d_in[12];
  const float* g2     =(const float*)d_in[13];
  const float* k_k    =(const float*)d_in[14];
  const float* k_a    =(const float*)d_in[15];
  const float* r_k    =(const float*)d_in[16];
  const float* Wq     =(const float*)d_in[17];
  const float* Wk     =(const float*)d_in[18];
  const float* Wv     =(const float*)d_in[19];
  const float* Wo     =(const float*)d_in[20];
  const float* ln_w   =(const float*)d_in[21];
  const float* ln_b   =(const float*)d_in[22];
  char* ws=(char*)d_ws;
  float* dout=(float*)d_out;

  prep_kernel<<<2048,256,0,stream>>>(ws,x,vfirst,w1,w2,a1,a2,v1,v2,g1,g2,Wq,Wk,Wv,Wo,dout);
  gemm_kernel<<<dim3(32,19),256,0,stream>>>(0,ws,w0,a0,v0,dout);
  gemm_kernel<<<dim3(32,32),256,0,stream>>>(1,ws,w0,a0,v0,dout);
  prep2_kernel<<<2048,256,0,stream>>>(ws,vfirst,k_k,k_a,r_k);
  pre_kernel<<<2048,64,0,stream>>>(ws);
  scan2_kernel<<<32,256,0,stream>>>(ws,S0,dout);
  epi_kernel<<<2048,256,0,stream>>>(ws,ln_w,ln_b);
  gemm_kernel<<<dim3(32,8),256,0,stream>>>(2,ws,w0,a0,v0,dout);
}

// Round 15
// 158.723 us; speedup vs baseline: 1.4961x; 1.0037x over previous
//
#include <hip/hip_runtime.h>

typedef unsigned short u16;
typedef __attribute__((ext_vector_type(8))) short s16x8;
typedef __attribute__((ext_vector_type(4))) float f32x4;
typedef __attribute__((ext_vector_type(4))) int   i32x4;
typedef __attribute__((ext_vector_type(2))) int   i32x2;
typedef __attribute__((ext_vector_type(4))) unsigned short u16x4;

// ---------------- workspace layout (bytes) ----------------
constexpr size_t OFF_XB   = 0;                     // bf16 x [2048][1024]; later VEPI
constexpr size_t OFF_WQB  = OFF_XB   + 4194304;    // bf16 Wq         [1024][1024]
constexpr size_t OFF_WKB  = OFF_WQB  + 2097152;    // bf16 Wk         [512][1024]
constexpr size_t OFF_WVB  = OFF_WKB  + 1048576;    // bf16 Wv         [512][1024]
constexpr size_t OFF_WOB  = OFF_WVB  + 1048576;    // bf16 Wo         [1024][1024]
constexpr size_t OFF_W1T  = OFF_WOB  + 2097152;    // bf16 W1T [384][1024]; later DP
constexpr size_t OFF_W2T  = OFF_W1T  + 786432;     // bf16 w2T        [1024][64]
constexpr size_t OFF_A2T  = OFF_W2T  + 131072;     // bf16 a2T        [1024][64]
constexpr size_t OFF_V2T  = OFF_A2T  + 131072;     // bf16 v2T        [1024][32]
constexpr size_t OFF_G2T  = OFF_V2T  + 65536;      // bf16 g2T        [1024][160]
constexpr size_t OFF_KQF  = OFF_G2T  + 327680;     // f32 k-proj      [2048][512]
constexpr size_t OFF_VQF  = OFF_KQF  + 4194304;    // f32 v-proj      [2048][512]
constexpr size_t OFF_URAW = OFF_VQF  + 4194304;    // (dead)
constexpr size_t OFF_UB   = OFF_URAW + 2621440;    // bf16 stage1 act [2048][384]
constexpr size_t OFF_S2A  = OFF_UB   + 1572864;    // f32 iclr        [2048][1024]
constexpr size_t OFF_S2V  = OFF_S2A  + 8388608;    // f32 vmix        [2048][1024]
constexpr size_t OFF_GBUF = OFF_S2V  + 8388608;    // f32 gate        [2048][1024]
constexpr size_t OFF_SEQ  = OFF_GBUF + 8388608;    // chunks [2048][24576B]; later records
constexpr size_t OFF_YBUF = OFF_SEQ  + 50331648;   // f32 y   [2][16][1024][64]
constexpr size_t OFF_XGB  = OFF_YBUF + 8388608;    // bf16 xn*g       [2048][1024]

// SEQ chunk payload (first 14336B of each 24576B slot), per t-row stride 896:
//  +0 r bf16[64] | +128 k | +256 v | +384 a | +512 b | +640 decay f32[64]
// record overlay (pre overwrites its OWN chunk): 0 Q(8192) | 8192 G(2048) |
//  10240 pL f32[64] | 10496 + w*2560 { c[jt4][lane]x8B (2048) | Yloc (512) }
constexpr size_t OFF_VEPI = OFF_XB;                // bf16 v rows (XB dead after gemm0)
constexpr size_t OFF_DP   = OFF_W1T;               // f32 dp (W1T dead after gemm0)

__device__ __forceinline__ u16 f2bf(float f){
  unsigned int u = __builtin_bit_cast(unsigned int, f);
  u = u + 0x7fffu + ((u >> 16) & 1u);
  return (u16)(u >> 16);
}
__device__ __forceinline__ int pk2(float a, float b){
  return (int)((unsigned)f2bf(a) | ((unsigned)f2bf(b) << 16));
}
__device__ __forceinline__ int cvtpk(float a, float b){
  int r;
  asm("v_cvt_pk_bf16_f32 %0, %1, %2" : "=v"(r) : "v"(a), "v"(b));
  return r;
}
__device__ __forceinline__ float bf2f(u16 h){
  return __builtin_bit_cast(float, ((unsigned)h) << 16);
}
__device__ __forceinline__ f32x4 cvt4(i32x2 v){
  unsigned a=(unsigned)v[0], b=(unsigned)v[1];
  f32x4 r;
  r[0]=__builtin_bit_cast(float, a<<16);
  r[1]=__builtin_bit_cast(float, a&0xffff0000u);
  r[2]=__builtin_bit_cast(float, b<<16);
  r[3]=__builtin_bit_cast(float, b&0xffff0000u);
  return r;
}

__device__ __forceinline__ void gload_lds16(const float* g, float* l){
  __builtin_amdgcn_global_load_lds((const __attribute__((address_space(1))) void*)g,
                                   (__attribute__((address_space(3))) void*)l, 16, 0, 0);
}
__device__ __forceinline__ void gload_lds16u(const u16* g, u16* l){
  __builtin_amdgcn_global_load_lds((const __attribute__((address_space(1))) void*)g,
                                   (__attribute__((address_space(3))) void*)l, 16, 0, 0);
}

// ---------------- prep: vectorized convert + transposes + v_first passthrough ----------------
constexpr size_t N_XB=2097152, N_WQ=1048576, N_WK=524288, N_WV=524288, N_WO=1048576,
  N_W1T=393216, N_W2T=65536, N_A2T=65536, N_V2T=32768, N_G2T=163840, N_VF=2097152;
constexpr size_t NV_BULK = (N_XB+N_WQ+N_WK+N_WV+N_WO)/4;   // vectorized bf16 copies
constexpr size_t NV_VF   = N_VF/4;                          // vectorized f32 copy
constexpr size_t N_SCAL  = N_W1T+N_W2T+N_A2T+N_V2T+N_G2T;   // scalar transposes
constexpr size_t PREP_TOT = NV_BULK + NV_VF + N_SCAL;

__global__ __launch_bounds__(256) void prep_kernel(char* ws, const float* x, const float* vfirst,
  const float* w1, const float* w2, const float* a1, const float* a2,
  const float* v1, const float* v2, const float* g1, const float* g2,
  const float* Wq, const float* Wk, const float* Wv, const float* Wo, float* dout)
{
  u16* XB=(u16*)(ws+OFF_XB); u16* WQB=(u16*)(ws+OFF_WQB); u16* WKB=(u16*)(ws+OFF_WKB);
  u16* WVB=(u16*)(ws+OFF_WVB); u16* WOB=(u16*)(ws+OFF_WOB); u16* W1T=(u16*)(ws+OFF_W1T);
  u16* W2T=(u16*)(ws+OFF_W2T); u16* A2T=(u16*)(ws+OFF_A2T); u16* V2T=(u16*)(ws+OFF_V2T);
  u16* G2T=(u16*)(ws+OFF_G2T);
  for (size_t idx=(size_t)blockIdx.x*256+threadIdx.x; idx<PREP_TOT; idx+=(size_t)gridDim.x*256){
    size_t r = idx;
    if (r < NV_BULK){
      size_t e = r*4;
      const float* src; u16* dst;
      if (e < N_XB){ src=x+e; dst=XB+e; }
      else { e-=N_XB;
        if (e < N_WQ){ src=Wq+e; dst=WQB+e; }
        else { e-=N_WQ;
          if (e < N_WK){ src=Wk+e; dst=WKB+e; }
          else { e-=N_WK;
            if (e < N_WV){ src=Wv+e; dst=WVB+e; }
            else { e-=N_WV; src=Wo+e; dst=WOB+e; }
          }
        }
      }
      f32x4 v=*(const f32x4*)src;
      u16x4 o; o[0]=f2bf(v[0]); o[1]=f2bf(v[1]); o[2]=f2bf(v[2]); o[3]=f2bf(v[3]);
      *(u16x4*)dst=o;
      continue;
    }
    r -= NV_BULK;
    if (r < NV_VF){
      size_t e=r*4;
      *(f32x4*)(dout + 2228224 + e) = *(const f32x4*)(vfirst + e);
      continue;
    }
    r -= NV_VF;
    if (r < N_W1T){
      int n=(int)(r>>10), k=(int)(r&1023); float v=0.f;
      if (n<64) v=w1[(size_t)k*64+n];
      else if (n<128) v=a1[(size_t)k*64+(n-64)];
      else if (n<160) v=v1[(size_t)k*32+(n-128)];
      else if (n<320) v=g1[(size_t)k*160+(n-160)];
      W1T[r]=f2bf(v); continue; } r-=N_W1T;
    if (r < N_W2T){ int c=(int)(r>>6), d=(int)(r&63); W2T[r]=f2bf(w2[(size_t)d*1024+c]); continue; } r-=N_W2T;
    if (r < N_A2T){ int c=(int)(r>>6), d=(int)(r&63); A2T[r]=f2bf(a2[(size_t)d*1024+c]); continue; } r-=N_A2T;
    if (r < N_V2T){ int c=(int)(r>>5), d=(int)(r&31); V2T[r]=f2bf(v2[(size_t)d*1024+c]); continue; } r-=N_V2T;
    { int c=(int)(r/160), d=(int)(r%160); G2T[r]=f2bf(g2[(size_t)d*1024+c]); }
  }
}

// ---------------- unified NT bf16 MFMA GEMM: C[m][n] = sum_k A[m][k]*B[n][k] ----------------
// 64x128 tile, 4 waves (2Mx2N), LDS 24KB; global_load_lds staging with XOR chunk swizzle.
__global__ __launch_bounds__(256) void gemm_kernel(int phase, char* ws,
  const float* w0b, const float* a0b, const float* v0b, float* dout)
{
  const u16* A; const u16* Bw;
  float* outF=nullptr; const float* bias=nullptr;
  char* SEQc=(char*)(ws+OFF_SEQ);
  u16* UBp=(u16*)(ws+OFF_UB);
  int lda=0, ldb=0, K=0, ldc=0, Nlim=1024, col0=0, outMode=0;
  int y = blockIdx.y;
  if (phase==0){
    A=(const u16*)(ws+OFF_XB); lda=1024; K=1024;
    if (y<8)      { Bw=(const u16*)(ws+OFF_WQB); ldb=1024; col0=y*128;       outMode=1; }
    else if (y<12){ Bw=(const u16*)(ws+OFF_WKB); ldb=1024; col0=(y-8)*128;   outF=(float*)(ws+OFF_KQF); ldc=512; Nlim=512; }
    else if (y<16){ Bw=(const u16*)(ws+OFF_WVB); ldb=1024; col0=(y-12)*128;  outF=(float*)(ws+OFF_VQF); ldc=512; Nlim=512; }
    else          { Bw=(const u16*)(ws+OFF_W1T); ldb=1024; col0=(y-16)*128;  outMode=4; Nlim=320; }
  } else if (phase==1){
    int seg=y>>3; col0=(y&7)*128;
    const int Ks[4]={64,64,32,160};
    const int Ao[4]={0,64,128,160};
    K=Ks[seg]; lda=384; ldb=K;
    A=(const u16*)(ws+OFF_UB) + Ao[seg];
    if (seg==0)     { Bw=(const u16*)(ws+OFF_W2T); outMode=2; bias=w0b; }
    else if (seg==1){ Bw=(const u16*)(ws+OFF_A2T); outMode=3; bias=a0b; outF=(float*)(ws+OFF_S2A); ldc=1024; }
    else if (seg==2){ Bw=(const u16*)(ws+OFF_V2T); outMode=3; bias=v0b; outF=(float*)(ws+OFF_S2V); ldc=1024; }
    else            { Bw=(const u16*)(ws+OFF_G2T); outF=(float*)(ws+OFF_GBUF); ldc=1024; }
  } else {
    A=(const u16*)(ws+OFF_XGB); lda=1024; K=1024;
    Bw=(const u16*)(ws+OFF_WOB); ldb=1024; col0=y*128; outF=dout; ldc=1024;
  }
  int m0 = blockIdx.x*64;
  __shared__ __align__(16) u16 As[2][2048];   // 64 x 32
  __shared__ __align__(16) u16 Bs[2][4096];   // 128 x 32
  int tid=threadIdx.x, l=tid&63, wv=tid>>6, wm=wv>>1, wn=wv&1;

  int cswz = (l&3) ^ ((l>>3)&3);
  int srA = wv*16 + (l>>2);
  int srB = wv*32 + (l>>2);
  const u16* aP0 = A  + (size_t)(m0+srA)*lda       + cswz*8;
  const u16* bP0 = Bw + (size_t)(col0+srB)*ldb     + cswz*8;
  const u16* bP1 = Bw + (size_t)(col0+srB+16)*ldb  + cswz*8;

  f32x4 acc[2][4];
  #pragma unroll
  for (int i=0;i<2;i++)
    #pragma unroll
    for (int j=0;j<4;j++) acc[i][j]=(f32x4){0.f,0.f,0.f,0.f};

#define GSTAGE(b,k0) do{                                   \
    gload_lds16u(aP0 + (k0), &As[b][wv*512]);              \
    gload_lds16u(bP0 + (k0), &Bs[b][wv*1024]);             \
    gload_lds16u(bP1 + (k0), &Bs[b][wv*1024+512]);         \
  }while(0)

  GSTAGE(0,0);
  asm volatile("s_waitcnt vmcnt(0)" ::: "memory");
  __syncthreads();

  int rrow=l&15, ck=l>>4;
  for (int k0=0;k0<K;k0+=32){
    int cb=(k0>>5)&1;
    if (k0+32<K) GSTAGE(cb^1, k0+32);
    s16x8 af[2], bf[4];
    #pragma unroll
    for (int mt=0;mt<2;mt++){
      int ra = wm*32+mt*16+rrow;
      af[mt]=*(const s16x8*)(&As[cb][ra*32 + ((ck ^ ((ra>>1)&3))<<3)]);
    }
    #pragma unroll
    for (int nt=0;nt<4;nt++){
      int rb = wn*64+nt*16+rrow;
      bf[nt]=*(const s16x8*)(&Bs[cb][rb*32 + ((ck ^ ((rb>>1)&3))<<3)]);
    }
    #pragma unroll
    for (int mt=0;mt<2;mt++)
      #pragma unroll
      for (int nt=0;nt<4;nt++)
        acc[mt][nt]=__builtin_amdgcn_mfma_f32_16x16x32_bf16(af[mt],bf[nt],acc[mt][nt],0,0,0);
    __syncthreads();
  }
#undef GSTAGE
  // epilogue
  #pragma unroll
  for (int mt=0;mt<2;mt++){
    #pragma unroll
    for (int nt=0;nt<4;nt++){
      int nglob = col0 + wn*64 + nt*16 + (l&15);
      if (nglob >= Nlim) continue;
      #pragma unroll
      for (int rg=0;rg<4;rg++){
        int mrow = m0 + wm*32 + mt*16 + ((l>>4)<<2) + rg;
        float val = acc[mt][nt][rg];
        if (outMode==0){
          outF[(size_t)mrow*ldc + nglob] = val;
        } else if (outMode==1){          // r bf16 -> SEQ slot 0
          int b=mrow>>10, t=mrow&1023, h=nglob>>6, i=nglob&63;
          char* cbase = SEQc + (size_t)((b*16+h)*64 + (t>>4))*24576 + (size_t)(t&15)*896;
          *(u16*)(cbase + i*2) = f2bf(val);
        } else if (outMode==2){          // decay f32 -> SEQ slot 5
          float w = bias[nglob] + val;
          float d = expf(-expf(w));
          int b=mrow>>10, t=mrow&1023, h=nglob>>6, i=nglob&63;
          char* cbase = SEQc + (size_t)((b*16+h)*64 + (t>>4))*24576 + (size_t)(t&15)*896;
          *(float*)(cbase + 640 + i*4) = d;
        } else if (outMode==3){          // sigmoid(bias+acc)
          float s = 1.0f/(1.0f+__expf(-(bias[nglob]+val)));
          outF[(size_t)mrow*ldc + nglob] = s;
        } else {                          // fused stage-1 activation -> UB bf16
          float a = (nglob<64) ? tanhf(val)
                  : (nglob<160) ? val
                  : 1.0f/(1.0f+__expf(-val));
          UBp[(size_t)mrow*384 + nglob] = f2bf(a);
        }
      }
    }
  }
}

// ---------------- prep2: build SEQ slots k,v,a,b (bf16) + dp + VEPI ----------------
__global__ __launch_bounds__(256) void prep2_kernel(char* ws, const float* vfirst,
  const float* kk_s, const float* ka_s, const float* rkw)
{
  const float* KQF=(const float*)(ws+OFF_KQF);
  const float* VQF=(const float*)(ws+OFF_VQF);
  const float* ICLR=(const float*)(ws+OFF_S2A);
  const float* VMIX=(const float*)(ws+OFF_S2V);
  u16* VEPI=(u16*)(ws+OFF_VEPI);
  float* DPp=(float*)(ws+OFF_DP);
  int m=blockIdx.x, b=m>>10, t=m&1023;
  int tid=threadIdx.x, c0=tid*4, h=c0>>6, i0=c0&63, hk=h>>1;
  f32x4 kq=*(const f32x4*)(KQF+(size_t)m*512+hk*64+i0);
  f32x4 vq=*(const f32x4*)(VQF+(size_t)m*512+hk*64+i0);
  f32x4 ic=*(const f32x4*)(ICLR+(size_t)m*1024+c0);
  f32x4 vm=*(const f32x4*)(VMIX+(size_t)m*1024+c0);
  f32x4 vf=*(const f32x4*)(vfirst+(size_t)m*1024+c0);
  f32x4 kkc=*(const f32x4*)(kk_s+c0);
  f32x4 kac=*(const f32x4*)(ka_s+c0);
  f32x4 kk=kq*kkc;
  float ssq=kk[0]*kk[0]+kk[1]*kk[1]+kk[2]*kk[2]+kk[3]*kk[3];
  #pragma unroll
  for (int mk=1;mk<16;mk<<=1) ssq += __shfl_xor(ssq,mk);
  float scale = 1.0f / fmaxf(sqrtf(ssq), 1e-12f);
  int bh=b*16+h;
  char* cb = ws + OFF_SEQ + (size_t)(bh*64+(t>>4))*24576 + (size_t)(t&15)*896;
  u16x4 rv = *(const u16x4*)(cb + (size_t)i0*2);
  f32x4 rkv = *(const f32x4*)(rkw + h*64 + i0);
  f32x4 kf,vv,av,bv;
  float dpp=0.f;
  #pragma unroll
  for (int j=0;j<4;j++){
    float icc = 1.0f + (ic[j]-1.0f)*kac[j];
    float kkn = kk[j]*scale;
    kf[j]=kq[j]*icc;
    vv[j]=vq[j] + (vf[j]-vq[j])*vm[j];
    av[j]=-kkn;
    bv[j]=kkn*icc;
    dpp += bf2f(rv[j])*kf[j]*rkv[j];
  }
  #pragma unroll
  for (int mk=1;mk<16;mk<<=1) dpp += __shfl_xor(dpp,mk);
  if ((tid&15)==0) DPp[(size_t)bh*1024 + t] = dpp;
  i32x2 o;
  o[0]=pk2(kf[0],kf[1]); o[1]=pk2(kf[2],kf[3]);
  *(i32x2*)(cb + 128 + (size_t)i0*2) = o;
  o[0]=pk2(vv[0],vv[1]); o[1]=pk2(vv[2],vv[3]);
  *(i32x2*)(cb + 256 + (size_t)i0*2) = o;
  *(i32x2*)(VEPI + ((size_t)bh*1024+t)*64 + i0) = o;
  o[0]=pk2(av[0],av[1]); o[1]=pk2(av[2],av[3]);
  *(i32x2*)(cb + 384 + (size_t)i0*2) = o;
  o[0]=pk2(bv[0],bv[1]); o[1]=pk2(bv[2],bv[3]);
  *(i32x2*)(cb + 512 + (size_t)i0*2) = o;
}

#define MFMA32(a,b,c) __builtin_amdgcn_mfma_f32_16x16x32_bf16(a,b,c,0,0,0)

// ---------------- precompute: per-chunk S-independent record (2048-way parallel) ------
__global__ __launch_bounds__(64) void pre_kernel(char* ws){
  int bid=blockIdx.x;
  int l=threadIdx.x, c16=l&15, g=l>>4;
  char* chunk = ws + OFF_SEQ + (size_t)bid*24576;
  char* rec = chunk;

  __shared__ __align__(16) char SH[31776];
  u16* AT =(u16*)(SH+14336);
  u16* RT =(u16*)(SH+16640);
  u16* BT =(u16*)(SH+18944);
  u16* KT =(u16*)(SH+21248);
  u16* vbb=(u16*)(SH+23552);
  u16* BKL=(u16*)(SH+26656);
  // overlay region (valid after column pass)
  float* WN  =(float*)(SH+0);
  u16* WY =(u16*)(SH+1088);
  u16* WB =(u16*)(SH+1888);
  u16* WK =(u16*)(SH+2688);
  u16* pbb=(u16*)(SH+3488);
  u16* zbb=(u16*)(SH+6592);
  float* rhsb=(float*)(SH+9696);
  float* gtmp=(float*)(SH+9696);   // overlays rhsb (disjoint lifetime)
  const s16x8 zero8 = {0,0,0,0,0,0,0,0};
  const f32x4 zf4 = {0.f,0.f,0.f,0.f};

  // ---- stage chunk payload (14336B, linear) ----
  #pragma unroll
  for (int q=0;q<14;q++)
    gload_lds16((const float*)(chunk + (size_t)q*1024) + l*4, (float*)(SH + q*1024));
  asm volatile("s_waitcnt vmcnt(0)" ::: "memory");
  __builtin_amdgcn_sched_barrier(0);

  // ---- column pass: lane = channel l ----
  float ptv[16]; float pp=1.f;
  #pragma unroll
  for (int t=0;t<16;t++){ pp *= *(const float*)(SH + t*896 + 640 + l*4); ptv[t]=pp; }
  float pL = ptv[15];
  *(float*)(rec + 10240 + (size_t)l*4) = pL;
  float rpL = __builtin_amdgcn_rcpf(pL);
  float bs[16], ks[16];
  u16 vcol[16];
  #pragma unroll
  for (int t=0;t<16;t++){
    float sc = pL * __builtin_amdgcn_rcpf(ptv[t]);
    bs[t] = bf2f(*(const u16*)(SH + t*896 + 512 + l*2)) * sc;
    ks[t] = bf2f(*(const u16*)(SH + t*896 + 128 + l*2)) * sc;
    vcol[t] = *(const u16*)(SH + t*896 + 256 + l*2);
  }
  {
    i32x4 o;
    o[0]=(int)((unsigned)vcol[0]|((unsigned)vcol[1]<<16));
    o[1]=(int)((unsigned)vcol[2]|((unsigned)vcol[3]<<16));
    o[2]=(int)((unsigned)vcol[4]|((unsigned)vcol[5]<<16));
    o[3]=(int)((unsigned)vcol[6]|((unsigned)vcol[7]<<16));
    *(i32x4*)(&vbb[l*24]) = o;
    o[0]=(int)((unsigned)vcol[8]|((unsigned)vcol[9]<<16));
    o[1]=(int)((unsigned)vcol[10]|((unsigned)vcol[11]<<16));
    o[2]=(int)((unsigned)vcol[12]|((unsigned)vcol[13]<<16));
    o[3]=(int)((unsigned)vcol[14]|((unsigned)vcol[15]<<16));
    *(i32x4*)(&vbb[l*24+8]) = o;
    o[0]=pk2(bs[0],bs[1]); o[1]=pk2(bs[2],bs[3]); o[2]=pk2(bs[4],bs[5]); o[3]=pk2(bs[6],bs[7]);
    *(i32x4*)(&BKL[l*40]) = o;
    o[0]=pk2(bs[8],bs[9]); o[1]=pk2(bs[10],bs[11]); o[2]=pk2(bs[12],bs[13]); o[3]=pk2(bs[14],bs[15]);
    *(i32x4*)(&BKL[l*40+8]) = o;
    o[0]=pk2(ks[0],ks[1]); o[1]=pk2(ks[2],ks[3]); o[2]=pk2(ks[4],ks[5]); o[3]=pk2(ks[6],ks[7]);
    *(i32x4*)(&BKL[l*40+16]) = o;
    o[0]=pk2(ks[8],ks[9]); o[1]=pk2(ks[10],ks[11]); o[2]=pk2(ks[12],ks[13]); o[3]=pk2(ks[14],ks[15]);
    *(i32x4*)(&BKL[l*40+24]) = o;
  }
  #pragma unroll
  for (int t=0;t<16;t++){
    float at = bf2f(*(const u16*)(SH + t*896 + 384 + l*2));
    float rt = bf2f(*(const u16*)(SH + t*896 +   0 + l*2));
    float pprev = (t==0) ? 1.f : ptv[t-1];
    AT[t*72+l] = f2bf(pprev*at);
    RT[t*72+l] = f2bf(ptv[t]*rt);
    BT[t*72+l] = f2bf(bs[t]*rpL);
    KT[t*72+l] = f2bf(ks[t]*rpL);
  }
  asm volatile("s_waitcnt lgkmcnt(0)" ::: "memory");
  __builtin_amdgcn_sched_barrier(0);

  // ---- W-block: N, Yhat, Tb, Tk ----
  {
    s16x8 afA[2], afR[2], bfB[2], bfK[2];
    #pragma unroll
    for (int Kt=0;Kt<2;Kt++){
      afA[Kt]=*(const s16x8*)(&AT[c16*72 + 32*Kt + 8*g]);
      afR[Kt]=*(const s16x8*)(&RT[c16*72 + 32*Kt + 8*g]);
      bfB[Kt]=*(const s16x8*)(&BT[c16*72 + 32*Kt + 8*g]);
      bfK[Kt]=*(const s16x8*)(&KT[c16*72 + 32*Kt + 8*g]);
    }
    f32x4 dNN=zf4, dNY=zf4, dBB=zf4, dBK=zf4;
    #pragma unroll
    for (int Kt=0;Kt<2;Kt++){
      dNN=MFMA32(afA[Kt],bfB[Kt],dNN);
      dNY=MFMA32(afA[Kt],bfK[Kt],dNY);
      dBB=MFMA32(afR[Kt],bfB[Kt],dBB);
      dBK=MFMA32(afR[Kt],bfK[Kt],dBK);
    }
    #pragma unroll
    for (int e=0;e<4;e++){
      int tR=4*g+e, sC=c16;
      WN[tR*17+sC] = dNN[e];
      WY[tR*24+sC] = (sC<tR)? f2bf(dNY[e]) : (u16)0;
      WB[tR*24+sC] = (sC<=tR)? f2bf(dBB[e]) : (u16)0;
      WK[tR*24+sC] = (sC<=tR)? f2bf(dBK[e]) : (u16)0;
    }
  }

  // ---- YhatV -> rhsb ----
  s16x8 vf[4];
  #pragma unroll
  for (int J=0;J<4;J++){
    vf[J]=zero8;
    if (g<2) vf[J]=*(const s16x8*)(&vbb[(16*J+c16)*24 + 8*g]);
  }
  {
    s16x8 wyf=zero8;
    if (g<2) wyf=*(const s16x8*)(&WY[c16*24 + 8*g]);
    f32x4 dR[4];
    #pragma unroll
    for (int J=0;J<4;J++){
      dR[J]=zf4;
      dR[J]=MFMA32(wyf,vf[J],dR[J]);
      #pragma unroll
      for (int e=0;e<4;e++)
        rhsb[(4*g+e)*68 + 16*J + c16] = dR[J][e];
    }
  }

  // ---- P-solve: (I-N)P = Atil, lane = column j=l ----
  {
    float pv[16];
    #pragma unroll
    for (int t=0;t<16;t++) pv[t]=bf2f(AT[t*72+l]);
    #pragma unroll
    for (int t=1;t<16;t++)
      #pragma unroll
      for (int s=0;s<16;s++){
        if (s<t) pv[t] += WN[t*17+s]*pv[s];
      }
    i32x4 o;
    o[0]=pk2(pv[0],pv[1]); o[1]=pk2(pv[2],pv[3]); o[2]=pk2(pv[4],pv[5]); o[3]=pk2(pv[6],pv[7]);
    *(i32x4*)(&pbb[l*24]) = o;
    o[0]=pk2(pv[8],pv[9]); o[1]=pk2(pv[10],pv[11]); o[2]=pk2(pv[12],pv[13]); o[3]=pk2(pv[14],pv[15]);
    *(i32x4*)(&pbb[l*24+8]) = o;
  }

  // ---- z-solve: (I-N)zloc = YhatV, lane = column i=l ----
  {
    float zz[16];
    #pragma unroll
    for (int t=0;t<16;t++) zz[t]=rhsb[t*68+l];
    #pragma unroll
    for (int t=1;t<16;t++)
      #pragma unroll
      for (int s=0;s<16;s++){
        if (s<t) zz[t] += WN[t*17+s]*zz[s];
      }
    i32x4 o;
    o[0]=pk2(zz[0],zz[1]); o[1]=pk2(zz[2],zz[3]); o[2]=pk2(zz[4],zz[5]); o[3]=pk2(zz[6],zz[7]);
    *(i32x4*)(&zbb[l*24]) = o;
    o[0]=pk2(zz[8],zz[9]); o[1]=pk2(zz[10],zz[11]); o[2]=pk2(zz[12],zz[13]); o[3]=pk2(zz[14],zz[15]);
    *(i32x4*)(&zbb[l*24+8]) = o;
  }
  asm volatile("s_waitcnt lgkmcnt(0)" ::: "memory");
  __builtin_amdgcn_sched_barrier(0);

  // ---- G = Rtil + Tb*P -> gtmp ; Yloc = Tb*zloc + Tk*V -> record strips ----
  {
    s16x8 wbf=zero8, wkf=zero8;
    if (g<2){
      wbf=*(const s16x8*)(&WB[c16*24 + 8*g]);
      wkf=*(const s16x8*)(&WK[c16*24 + 8*g]);
    }
    #pragma unroll
    for (int J=0;J<4;J++){
      s16x8 pfB=zero8, zfB=zero8;
      if (g<2){
        pfB=*(const s16x8*)(&pbb[(16*J+c16)*24 + 8*g]);
        zfB=*(const s16x8*)(&zbb[(16*J+c16)*24 + 8*g]);
      }
      f32x4 dG, dYl=zf4;
      #pragma unroll
      for (int e=0;e<4;e++) dG[e]=bf2f(RT[(4*g+e)*72 + 16*J + c16]);
      dG=MFMA32(wbf,pfB,dG);
      dYl=MFMA32(wbf,zfB,dYl);
      dYl=MFMA32(wkf,vf[J],dYl);
      #pragma unroll
      for (int e=0;e<4;e++) gtmp[(4*g+e)*68 + 16*J + c16]=dG[e];
      i32x2 o2; o2[0]=pk2(dYl[0],dYl[1]); o2[1]=pk2(dYl[2],dYl[3]);
      *(i32x2*)(rec + 10496 + (size_t)J*2560 + 2048 + (size_t)l*8) = o2;
    }
  }

  // ---- Q = P^T [Bbar;Kbar] tiles -> record Q A-frags; c = [Bbar;Kbar]^T [z;V] ----
  {
    s16x8 bk[4], pfr[4], bzv[4];
    #pragma unroll
    for (int nt=0;nt<4;nt++) bk[nt]=*(const s16x8*)(&BKL[(16*nt+c16)*40 + 8*g]);
    #pragma unroll
    for (int mt=0;mt<4;mt++)
      pfr[mt]= (g<2) ? *(const s16x8*)(&pbb[(16*mt+c16)*24 + 8*g]) : zero8;
    #pragma unroll
    for (int it=0;it<4;it++)
      bzv[it]= (g<2) ? *(const s16x8*)(&zbb[(16*it+c16)*24 + 8*g])
                     : *(const s16x8*)(&vbb[(16*it+c16)*24 + 8*(g-2)]);
    #pragma unroll
    for (int mt=0;mt<4;mt++){
      #pragma unroll
      for (int nt=0;nt<4;nt++){
        f32x4 dQ = MFMA32(pfr[mt], bk[nt], zf4);
        int kk = mt>>1, gq = ((mt&1)<<1) | (g>>1), jo = g&1;
        i32x2 o2; o2[0]=pk2(dQ[0],dQ[1]); o2[1]=pk2(dQ[2],dQ[3]);
        *(i32x2*)(rec + ((size_t)(kk*4+nt)*64 + (size_t)(c16 + 16*gq))*16 + 8*jo) = o2;
      }
    }
    #pragma unroll
    for (int jtp=0;jtp<4;jtp++){
      #pragma unroll
      for (int it=0;it<4;it++){
        f32x4 dc = MFMA32(bk[jtp], bzv[it], zf4);
        i32x2 o2; o2[0]=pk2(dc[0],dc[1]); o2[1]=pk2(dc[2],dc[3]);
        *(i32x2*)(rec + 10496 + (size_t)it*2560 + ((size_t)jtp*64 + l)*8) = o2;
      }
    }
  }

  // ---- G A-frags -> record ----
  #pragma unroll
  for (int kk=0;kk<2;kk++){
    f32x4 b0 = *(const f32x4*)(&gtmp[c16*68 + 32*kk + 8*g]);
    f32x4 b1 = *(const f32x4*)(&gtmp[c16*68 + 32*kk + 8*g + 4]);
    i32x4 o;
    o[0]=pk2(b0[0],b0[1]); o[1]=pk2(b0[2],b0[3]); o[2]=pk2(b1[0],b1[1]); o[3]=pk2(b1[2],b1[3]);
    *(i32x4*)(rec + 8192 + (size_t)(kk*64+l)*16) = o;
  }
}

// ---------------- serial scan: register-direct loads, 4 waves/block, depth-3 prefetch ----
__global__ __launch_bounds__(256) void scan2_kernel(char* ws, const float* S0, float* dout){
  float* YB=(float*)(ws+OFF_YBUF);
  const char* recb = ws + OFF_SEQ;
  int bh=blockIdx.x;
  int tid=threadIdx.x, w=tid>>6, l=tid&63, c16=l&15, g=l>>4;

  __shared__ __align__(16) u16 ST[4][16*88];
  u16* STw = &ST[w][0];

  f32x4 Sreg[4];
  #pragma unroll
  for (int jt=0;jt<4;jt++)
    Sreg[jt] = *(const f32x4*)(S0 + (size_t)bh*4096 + (size_t)(16*w+c16)*64 + 16*jt + 4*g);
  #pragma unroll
  for (int jt=0;jt<4;jt++){
    i32x2 p; p[0]=pk2(Sreg[jt][0],Sreg[jt][1]); p[1]=pk2(Sreg[jt][2],Sreg[jt][3]);
    *(i32x2*)(&STw[c16*88 + 16*jt + 4*g]) = p;
  }

  const char* rb = recb + (size_t)(bh*64)*24576;
  float* yb0 = YB + (size_t)bh*65536;

#define DECLR(S) s16x8 qf##S[8]; s16x8 gf##S[2]; f32x4 pl##S[4]; i32x2 cf##S[4]; i32x2 yl##S;
#define LOADR(S, nc) do{ \
    const char* rp_ = rb + (size_t)(nc)*24576; \
    _Pragma("unroll") \
    for (int q_=0;q_<8;q_++) qf##S[q_] = *(const s16x8*)(rp_ + (size_t)q_*1024 + l*16); \
    gf##S[0] = *(const s16x8*)(rp_ + 8192 + (size_t)l*16); \
    gf##S[1] = *(const s16x8*)(rp_ + 9216 + (size_t)l*16); \
    _Pragma("unroll") \
    for (int jt_=0;jt_<4;jt_++) pl##S[jt_] = *(const f32x4*)(rp_ + 10240 + (size_t)(16*jt_+4*g)*4); \
    _Pragma("unroll") \
    for (int jt_=0;jt_<4;jt_++) cf##S[jt_] = *(const i32x2*)(rp_ + 10496 + (size_t)w*2560 + (size_t)(jt_*64+l)*8); \
    yl##S = *(const i32x2*)(rp_ + 10496 + (size_t)w*2560 + 2048 + (size_t)l*8); \
  }while(0)
#define STEP(S, ch) do{ \
    s16x8 sB0=*(const s16x8*)(&STw[c16*88 + 8*g]); \
    s16x8 sB1=*(const s16x8*)(&STw[c16*88 + 32 + 8*g]); \
    f32x4 dy=cvt4(yl##S); \
    dy=MFMA32(gf##S[0],sB0,dy); dy=MFMA32(gf##S[1],sB1,dy); \
    _Pragma("unroll") \
    for (int jt_=0;jt_<4;jt_++){ \
      f32x4 acc = cvt4(cf##S[jt_]); \
      acc = MFMA32(qf##S[jt_], sB0, acc); \
      acc = MFMA32(qf##S[4+jt_], sB1, acc); \
      _Pragma("unroll") \
      for (int e_=0;e_<4;e_++) acc[e_] = fmaf(pl##S[jt_][e_], Sreg[jt_][e_], acc[e_]); \
      Sreg[jt_]=acc; \
    } \
    _Pragma("unroll") \
    for (int jt_=0;jt_<4;jt_++){ \
      i32x2 p_; p_[0]=cvtpk(Sreg[jt_][0],Sreg[jt_][1]); p_[1]=cvtpk(Sreg[jt_][2],Sreg[jt_][3]); \
      *(i32x2*)(&STw[c16*88 + 16*jt_ + 4*g]) = p_; \
    } \
    { float* yb_ = yb0 + (size_t)(ch)*1024; \
      _Pragma("unroll") \
      for (int e_=0;e_<4;e_++) yb_[(size_t)(4*g+e_)*64 + 16*w + c16] = dy[e_]; } \
  }while(0)

  DECLR(A); DECLR(B); DECLR(C);
  LOADR(A, 0);
  LOADR(B, 1);
  LOADR(C, 2);

  // 64 chunks = 21 iterations x 3 + 1 epilogue
  #pragma unroll 1
  for (int ch=0; ch<63; ch+=3){
    STEP(A, ch);
    { int nc = ch+3; if (nc>63) nc=63; LOADR(A, nc); }
    STEP(B, ch+1);
    { int nc = ch+4; if (nc>63) nc=63; LOADR(B, nc); }
    STEP(C, ch+2);
    { int nc = ch+5; if (nc>63) nc=63; LOADR(C, nc); }
  }
  STEP(A, 63);
#undef DECLR
#undef LOADR
#undef STEP

  #pragma unroll
  for (int jt=0;jt<4;jt++)
    *(f32x4*)(dout + 2097152 + (size_t)bh*4096 + (size_t)(16*w+c16)*64 + 16*jt + 4*g) = Sreg[jt];
}

// ---------------- epilogue: groupnorm + bonus + gate -> bf16 ----------------
__global__ __launch_bounds__(256) void epi_kernel(char* ws, const float* lnw, const float* lnb)
{
  const float* YB=(const float*)(ws+OFF_YBUF);
  const u16* VEPI=(const u16*)(ws+OFF_VEPI);
  const float* DPp=(const float*)(ws+OFF_DP);
  const float* GB=(const float*)(ws+OFF_GBUF);
  u16* XGB=(u16*)(ws+OFF_XGB);
  int m=blockIdx.x, b=m>>10, t=m&1023;
  int tid=threadIdx.x, c0=tid*4, h=c0>>6, i0=c0&63;
  f32x4 y=*(const f32x4*)(YB + ((size_t)(b*16+h)*1024+t)*64 + i0);
  float s = y[0]+y[1]+y[2]+y[3];
  float ss= y[0]*y[0]+y[1]*y[1]+y[2]*y[2]+y[3]*y[3];
  #pragma unroll
  for (int mk=1;mk<16;mk<<=1){ s+=__shfl_xor(s,mk); ss+=__shfl_xor(ss,mk); }
  float mu=s*(1.0f/64.0f), var=ss*(1.0f/64.0f)-mu*mu;
  float inv=rsqrtf(var + 6.4e-4f);
  u16x4 v16=*(const u16x4*)(VEPI + ((size_t)(b*16+h)*1024+t)*64 + i0);
  float dp = DPp[(size_t)(b*16+h)*1024 + t];
  f32x4 gg=*(const f32x4*)(GB+(size_t)m*1024+c0);
  u16x4 outv;
  #pragma unroll
  for (int j=0;j<4;j++){
    float xn = (y[j]-mu)*inv*lnw[c0+j] + lnb[c0+j] + dp*bf2f(v16[j]);
    outv[j]=f2bf(xn*gg[j]);
  }
  *(u16x4*)(XGB+(size_t)m*1024+c0)=outv;
}

extern "C" void kernel_launch(void* const* d_in, const int* in_sizes, int n_in,
                              void* d_out, int out_size, void* d_ws, size_t ws_size,
                              hipStream_t stream) {
  const float* x      =(const float*)d_in[0];
  const float* S0     =(const float*)d_in[1];
  const float* vfirst =(const float*)d_in[2];
  const float* w0     =(const float*)d_in[3];
  const float* w1     =(const float*)d_in[4];
  const float* w2     =(const float*)d_in[5];
  const float* a0     =(const float*)d_in[6];
  const float* a1     =(const float*)d_in[7];
  const float* a2     =(const float*)d_in[8];
  const float* v0     =(const float*)d_in[9];
  const float* v1     =(const float*)d_in[10];
  const float* v2     =(const float*)d_in[11];
  const float* g1     =(const float*)d_in[12];
  const float* g2     =(const float*)d_in[13];
  const float* k_k    =(const float*)d_in[14];
  const float* k_a    =(const float*)d_in[15];
  const float* r_k    =(const float*)d_in[16];
  const float* Wq     =(const float*)d_in[17];
  const float* Wk     =(const float*)d_in[18];
  const float* Wv     =(const float*)d_in[19];
  const float* Wo     =(const float*)d_in[20];
  const float* ln_w   =(const float*)d_in[21];
  const float* ln_b   =(const float*)d_in[22];
  char* ws=(char*)d_ws;
  float* dout=(float*)d_out;

  prep_kernel<<<2048,256,0,stream>>>(ws,x,vfirst,w1,w2,a1,a2,v1,v2,g1,g2,Wq,Wk,Wv,Wo,dout);
  gemm_kernel<<<dim3(32,19),256,0,stream>>>(0,ws,w0,a0,v0,dout);
  gemm_kernel<<<dim3(32,32),256,0,stream>>>(1,ws,w0,a0,v0,dout);
  prep2_kernel<<<2048,256,0,stream>>>(ws,vfirst,k_k,k_a,r_k);
  pre_kernel<<<2048,64,0,stream>>>(ws);
  scan2_kernel<<<32,256,0,stream>>>(ws,S0,dout);
  epi_kernel<<<2048,256,0,stream>>>(ws,ln_w,ln_b);
  gemm_kernel<<<dim3(32,8),256,0,stream>>>(2,ws,w0,a0,v0,dout);
}